// Round 6
// baseline (588.921 us; speedup 1.0000x reference)
//
#include <hip/hip_runtime.h>

typedef float f32x4 __attribute__((ext_vector_type(4)));
typedef __bf16 bf16x8 __attribute__((ext_vector_type(8)));
typedef unsigned short ushort;
typedef ushort ushort8 __attribute__((ext_vector_type(8)));
typedef ushort ushort4v __attribute__((ext_vector_type(4)));

#define DM 1024
#define DI 2048
#define DSTATE 128
#define NH 32
#define HD 64
#define CONVDIM 2304
#define DPROJ 4384
#define ROWS 8192

__device__ __forceinline__ float bf2f(ushort u){
  union { unsigned int i; float f; } v; v.i = ((unsigned int)u)<<16; return v.f;
}
__device__ __forceinline__ ushort f2bf(float f){
  union { float f; unsigned int i; } v; v.f = f;
  unsigned int r = v.i + 0x7FFFu + ((v.i>>16)&1u);
  return (ushort)(r>>16);
}
__device__ __forceinline__ float siluf(float x){ return x / (1.f + __expf(-x)); }

__device__ __forceinline__ void gload16(const ushort* g, ushort* l){
  __builtin_amdgcn_global_load_lds(
      (const __attribute__((address_space(1))) void*)g,
      (__attribute__((address_space(3))) void*)l, 16, 0, 0);
}

// ---------------- elementwise: Ya = bf16(silu(y)) ----------------
__global__ __launch_bounds__(256) void k_silu_cast(const float* __restrict__ in,
                                                   ushort* __restrict__ out, int n){
  int i = (blockIdx.x*256 + threadIdx.x)*4;
  if (i >= n) return;
  float4 v = *(const float4*)(in + i);
  ushort4v o;
  o.x = f2bf(siluf(v.x)); o.y = f2bf(siluf(v.y));
  o.z = f2bf(siluf(v.z)); o.w = f2bf(siluf(v.w));
  *(ushort4v*)(out + i) = o;
}

// ---------------- weight transpose+cast: in[K][N] f32 -> out[N][K] bf16 ----------------
__global__ __launch_bounds__(256) void k_transpose_cast(const float* __restrict__ in,
                                                        ushort* __restrict__ out,
                                                        int K, int N){
  __shared__ float tile[32][33];
  int n0 = blockIdx.x*32, k0 = blockIdx.y*32;
  int tx = threadIdx.x & 31, ty = threadIdx.x >> 5; // 32x8
  for (int r = ty; r < 32; r += 8) tile[r][tx] = in[(size_t)(k0+r)*N + n0+tx];
  __syncthreads();
  for (int r = ty; r < 32; r += 8) out[(size_t)(n0+r)*K + k0+tx] = f2bf(tile[tx][r]);
}

// ---------------- at[b][n] = silu(t[b]) @ w_ada + b_ada ----------------
__global__ __launch_bounds__(256) void k_at(const float* __restrict__ t,
                                            const float* __restrict__ w_ada,
                                            const float* __restrict__ b_ada,
                                            float* __restrict__ at){
  __shared__ float st[1024];
  int b = blockIdx.y;
  int col = blockIdx.x*256 + threadIdx.x;
  for (int i = threadIdx.x; i < 1024; i += 256) st[i] = siluf(t[b*1024 + i]);
  __syncthreads();
  float acc = 0.f;
  for (int k = 0; k < 1024; ++k) acc += st[k] * w_ada[(size_t)k*3072 + col];
  at[b*3072 + col] = acc + b_ada[col];
}

// ================= 8-wave 256x256 GEMM, BK=64, safe double-buffer =================
// Tile T: 4 phases read buf[T&1]; each phase stages ONE half-tile of tile T+1
// into buf[~T&1] (never the read buffer). One vmcnt(0)+barrier per tile.
// Swizzle: element (row, chunk8) at row*64 + ((chunk ^ (row&7))*8).
#define LOADFRAGS(RBUF, MH, NH) \
  _Pragma("unroll") \
  for (int mf=0; mf<4; ++mf){ \
    const int row = wm*128 + ((MH)*4+mf)*16 + l16; \
    _Pragma("unroll") \
    for (int ks=0; ks<2; ++ks){ \
      const int ch = ks*4 + l4; \
      af[mf][ks] = *(const bf16x8*)&sm[(RBUF)*32768 + row*64 + ((ch ^ (row&7))*8)]; \
    } \
  } \
  _Pragma("unroll") \
  for (int nf=0; nf<2; ++nf){ \
    const int row = wn*64 + ((NH)*2+nf)*16 + l16; \
    _Pragma("unroll") \
    for (int ks=0; ks<2; ++ks){ \
      const int ch = ks*4 + l4; \
      bv[nf][ks] = *(const bf16x8*)&sm[(RBUF)*32768 + 16384 + row*64 + ((ch ^ (row&7))*8)]; \
    } \
  }

#define STAGE(SBUF, ISB, HALF, KT) \
  { const ushort* Gp = (ISB) ? Bt : Ag; \
    const int bb = (ISB) ? bn : bm; \
    gload16(Gp + (size_t)(bb*256 + (HALF)*128 + r0)*K + (size_t)(KT)*64 + c0v*8, \
            sm + (SBUF)*32768 + (ISB)*16384 + (HALF)*8192 + (wave*2+0)*512); \
    gload16(Gp + (size_t)(bb*256 + (HALF)*128 + r1)*K + (size_t)(KT)*64 + c1v*8, \
            sm + (SBUF)*32768 + (ISB)*16384 + (HALF)*8192 + (wave*2+1)*512); }

#define MFMAQUAD(MH, NH) \
  _Pragma("unroll") \
  for (int ks=0; ks<2; ++ks) \
    _Pragma("unroll") \
    for (int mf=0; mf<4; ++mf) \
      _Pragma("unroll") \
      for (int nf=0; nf<2; ++nf) \
        acc[(MH)*4+mf][(NH)*2+nf] = __builtin_amdgcn_mfma_f32_16x16x32_bf16( \
            af[mf][ks], bv[nf][ks], acc[(MH)*4+mf][(NH)*2+nf], 0, 0, 0);

#define PHASE(RBUF, MH, NH, SBUF, ISB, HALF, KT, DS) \
  { bf16x8 af[4][2], bv[2][2]; \
    LOADFRAGS(RBUF, MH, NH); \
    if (DS) { STAGE(SBUF, ISB, HALF, KT); } \
    __builtin_amdgcn_s_barrier(); \
    __builtin_amdgcn_sched_barrier(0); \
    __builtin_amdgcn_s_setprio(1); \
    MFMAQUAD(MH, NH); \
    __builtin_amdgcn_s_setprio(0); \
    __builtin_amdgcn_sched_barrier(0); \
  }

template<int EPI>
__global__ __launch_bounds__(512)
void k_gemm8(const ushort* __restrict__ Ag, const ushort* __restrict__ Bt,
             ushort* __restrict__ Cb, ushort* __restrict__ Cb2, ushort* __restrict__ Cb3,
             float* __restrict__ Cf,
             int M, int N, int K, int nbn,
             const float* __restrict__ bias, const float* __restrict__ at,
             const ushort* __restrict__ gateM, const float* __restrict__ xres){
  extern __shared__ ushort sm[];   // 2 bufs x (A 16384 + B 16384) ushorts = 128KB
  const int tid = threadIdx.x, wave = tid >> 6, lane = tid & 63;
  const int l16 = lane & 15, l4 = lane >> 4;
  const int wm = wave >> 2, wn = wave & 3;
  // XCD-bijective swizzle (gridDim.x % 8 == 0 guaranteed by caller)
  const int nwg = gridDim.x, bid = blockIdx.x;
  const int wg = (bid & 7)*(nwg >> 3) + (bid >> 3);
  const int bm = wg / nbn, bn = wg % nbn;
  const int NT = K >> 6;
  // staging geometry: 2 gload16/wave per half-tile; rows wave*16..wave*16+16
  const int r0 = wave*16 + (lane>>3);
  const int r1 = wave*16 + 8 + (lane>>3);
  const int c0v = (lane&7) ^ (r0&7);
  const int c1v = (lane&7) ^ (r1&7);

  f32x4 acc[8][4];
#pragma unroll
  for (int mi=0; mi<8; ++mi)
#pragma unroll
    for (int ni=0; ni<4; ++ni) acc[mi][ni] = (f32x4){0.f,0.f,0.f,0.f};

  // prologue: tile 0 (all 4 half-tiles) -> buf0; drain; barrier
  STAGE(0,0,0,0); STAGE(0,1,0,0); STAGE(0,0,1,0); STAGE(0,1,1,0);
  asm volatile("s_waitcnt vmcnt(0)" ::: "memory");
  __builtin_amdgcn_s_barrier();
  __builtin_amdgcn_sched_barrier(0);

  for (int T = 0; T < NT; ++T){
    const int cur = T & 1, nx = cur ^ 1;
    const int tn = T + 1;
    const bool ds = (tn < NT);
    PHASE(cur, 0,0, nx, 0,0, tn, ds);   // stage A-h0 of T+1
    PHASE(cur, 0,1, nx, 1,0, tn, ds);   // stage B-h0
    PHASE(cur, 1,0, nx, 0,1, tn, ds);   // stage A-h1
    PHASE(cur, 1,1, nx, 1,1, tn, ds);   // stage B-h1
    asm volatile("s_waitcnt vmcnt(0)" ::: "memory");
    __builtin_amdgcn_s_barrier();
    __builtin_amdgcn_sched_barrier(0);
  }

  // epilogue
#pragma unroll
  for (int mi=0; mi<8; ++mi){
    int grow_base = bm*256 + wm*128 + mi*16 + l4*4;
#pragma unroll
    for (int ni=0; ni<4; ++ni){
      int gcol = bn*256 + wn*64 + ni*16 + l16;
      if (EPI == 0){
#pragma unroll
        for (int r=0;r<4;r++){
          int row = grow_base + r;
          float v = acc[mi][ni][r];
          if (gcol < 2048)      Cb [(size_t)row*2048 + gcol] = f2bf(v);
          else if (gcol < 4352) Cb2[(size_t)row*2304 + (gcol-2048)] = f2bf(v);
          else if (gcol < 4384) Cb3[(size_t)row*32   + (gcol-4352)] = f2bf(v);
        }
      } else if (EPI == 1){
        float bvv = bias[gcol];
#pragma unroll
        for (int r=0;r<4;r++){
          int row = grow_base + r;
          float v = acc[mi][ni][r] + bvv + at[(row>>10)*3072 + gcol];
          if (gcol < 2048) Cb [(size_t)row*2048 + gcol] = f2bf(v);
          else             Cb2[(size_t)row*1024 + (gcol-2048)] = f2bf(v);
        }
      } else {
#pragma unroll
        for (int r=0;r<4;r++){
          int row = grow_base + r;
          float g = bf2f(gateM[(size_t)row*1024 + gcol]);
          Cf[(size_t)row*1024 + gcol] = g*acc[mi][ni][r] + xres[(size_t)row*1024 + gcol];
        }
      }
    }
  }
}

// ---------------- LN + modulation: mod = LN(x)*(1+scale)+shift (bf16) ----------------
__global__ __launch_bounds__(256) void k_lnmod(const float* __restrict__ x,
                                               const ushort* __restrict__ Mss,
                                               ushort* __restrict__ mod){
  int row = blockIdx.x;
  const float* xr = x + (size_t)row*1024;
  float v[4]; float s = 0.f, s2 = 0.f;
#pragma unroll
  for (int j=0;j<4;j++){ v[j] = xr[threadIdx.x + j*256]; s += v[j]; s2 += v[j]*v[j]; }
#pragma unroll
  for (int o=32;o>0;o>>=1){ s += __shfl_down(s,o); s2 += __shfl_down(s2,o); }
  __shared__ float ls[4], ls2[4];
  int wv = threadIdx.x >> 6;
  if ((threadIdx.x & 63) == 0){ ls[wv] = s; ls2[wv] = s2; }
  __syncthreads();
  s  = ls[0]+ls[1]+ls[2]+ls[3];
  s2 = ls2[0]+ls2[1]+ls2[2]+ls2[3];
  float mu = s * (1.f/1024.f);
  float var = s2 * (1.f/1024.f) - mu*mu;
  float rstd = rsqrtf(var + 1e-6f);
  const ushort* Mr = Mss + (size_t)row*2048;
#pragma unroll
  for (int j=0;j<4;j++){
    int d = threadIdx.x + j*256;
    float sc = bf2f(Mr[1024 + d]);
    float sh = bf2f(Mr[d]);
    mod[(size_t)row*1024 + d] = f2bf((v[j]-mu)*rstd*(1.f+sc) + sh);
  }
}

// ---------------- causal conv4 + silu over xbc ----------------
__global__ __launch_bounds__(256) void k_conv(const ushort* __restrict__ xbc,
                                              const float* __restrict__ conv_w,
                                              const float* __restrict__ conv_b,
                                              ushort* __restrict__ co){
  int ch  = blockIdx.x*256 + threadIdx.x;   // < 2304
  int row = blockIdx.y;                      // < 8192
  int l = row & 1023, b = row >> 10;
  float acc = conv_b[ch];
#pragma unroll
  for (int k=0;k<4;k++){
    int ll = l - 3 + k;
    if (ll >= 0) acc += conv_w[ch*4 + k] * bf2f(xbc[(size_t)(b*1024 + ll)*CONVDIM + ch]);
  }
  co[(size_t)row*CONVDIM + ch] = f2bf(siluf(acc));
}

// ---------------- transpose co cols [0,2176) -> xhT [b*2048+c][l], BTg [b*128+n][l] ----------------
__global__ __launch_bounds__(256) void k_transT(const ushort* __restrict__ co,
                                                ushort* __restrict__ xhT,
                                                ushort* __restrict__ BTg){
  __shared__ ushort tile[64*72];
  const int c0 = blockIdx.x*64, l0 = blockIdx.y*64, b = blockIdx.z;
  const int tid = threadIdx.x;
  for (int q = tid; q < 512; q += 256){
    int r = q >> 3, cc = q & 7;
    ushort8 v = *(const ushort8*)(co + (size_t)(b*1024 + l0 + r)*CONVDIM + c0 + cc*8);
    *(ushort8*)&tile[r*72 + cc*8] = v;
  }
  __syncthreads();
  for (int q = tid; q < 1024; q += 256){
    int oc = q >> 4, lc = (q & 15)*4;
    ushort4v o;
#pragma unroll
    for (int j = 0; j < 4; ++j) o[j] = tile[(lc + j)*72 + oc];
    int ccol = c0 + oc;
    ushort* out = (ccol < 2048) ? (xhT + (size_t)(b*2048 + ccol)*1024)
                                : (BTg + (size_t)(b*128 + (ccol - 2048))*1024);
    *(ushort4v*)(out + l0 + lc) = o;
  }
}

// ---------------- chunk state contribution: Sc[p][n] = sum_s G[s]*x[s,p]*B[s,n] ----------------
__global__ __launch_bounds__(256) void k_chunkstate(
    const ushort* __restrict__ xhT, const ushort* __restrict__ BTg,
    const ushort* __restrict__ dtc,
    const float* __restrict__ dt_bias, const float* __restrict__ A_log,
    ushort* __restrict__ Sc, float* __restrict__ Dcb){
  __shared__ __align__(16) ushort sXG[64*128];   // 16KB (swizzled)
  __shared__ __align__(16) ushort sBT[128*128];  // 32KB (swizzled)
  __shared__ float sG[128];
  const int bid = blockIdx.x;
  const int h = bid & 31, bc = bid >> 5, b = bc >> 3, c = bc & 7;
  const int tid = threadIdx.x, wave = tid >> 6, lane = tid & 63;
  const int l16 = lane & 15, l4 = lane >> 4;
  const int sci = (b*32 + h)*8 + c;
  {
    const ushort* src = BTg + (size_t)(b*128)*1024 + c*128;
    for (int i2 = 0; i2 < 8; ++i2){
      int itg = wave*8 + i2;
      int r = itg*4 + l4;
      int cc = l16 ^ (r & 7);
      gload16(src + (size_t)r*1024 + cc*8, &sBT[itg*512]);
    }
  }
  const float Ah = -__expf(A_log[h]);
  if (wave == 0){
    const int row0 = b*1024 + c*128;
    float bi = dt_bias[h];
    float d0 = bf2f(dtc[(size_t)(row0 + 2*lane    )*32 + h]) + bi;
    float d1 = bf2f(dtc[(size_t)(row0 + 2*lane + 1)*32 + h]) + bi;
    d0 = (d0 > 20.f) ? d0 : log1pf(__expf(d0));
    d1 = (d1 > 20.f) ? d1 : log1pf(__expf(d1));
    float p = d0 + d1;
#pragma unroll
    for (int o = 1; o < 64; o <<= 1){
      float tp = __shfl_up(p, o);
      if (lane >= o) p += tp;
    }
    float cs127 = __shfl(p, 63);
    sG[2*lane    ] = __expf(Ah*(cs127 - (p - d1))) * d0;
    sG[2*lane + 1] = __expf(Ah*(cs127 - p)) * d1;
    if (lane == 0) Dcb[sci] = __expf(Ah*cs127);
  }
  __syncthreads();
  {
    const ushort* xsrc = xhT + (size_t)(b*2048 + h*64)*1024 + c*128;
    for (int q = tid; q < 1024; q += 256){
      int r = q >> 4, cc = q & 15;
      ushort8 v = *(const ushort8*)(xsrc + (size_t)r*1024 + cc*8);
      ushort8 o;
#pragma unroll
      for (int j = 0; j < 8; ++j) o[j] = f2bf(bf2f(v[j]) * sG[cc*8 + j]);
      *(ushort8*)&sXG[r*128 + ((cc ^ (r & 7))*8)] = o;
    }
  }
  __syncthreads();
  f32x4 acc[4][2];
#pragma unroll
  for (int m=0;m<4;m++)
#pragma unroll
    for (int nf=0;nf<2;nf++) acc[m][nf] = (f32x4){0.f,0.f,0.f,0.f};
  for (int ks = 0; ks < 4; ++ks){
    bf16x8 av[4], bv[2];
#pragma unroll
    for (int m = 0; m < 4; ++m){
      int rp = m*16 + l16;
      av[m] = *(const bf16x8*)&sXG[rp*128 + (((ks*4 + l4) ^ (rp & 7))*8)];
    }
#pragma unroll
    for (int nf = 0; nf < 2; ++nf){
      int rn = wave*32 + nf*16 + l16;
      bv[nf] = *(const bf16x8*)&sBT[rn*128 + (((ks*4 + l4) ^ (rn & 7))*8)];
    }
#pragma unroll
    for (int m = 0; m < 4; ++m)
#pragma unroll
      for (int nf = 0; nf < 2; ++nf)
        acc[m][nf] = __builtin_amdgcn_mfma_f32_16x16x32_bf16(av[m], bv[nf], acc[m][nf], 0, 0, 0);
  }
  const size_t base = (size_t)sci * 8192;
#pragma unroll
  for (int m = 0; m < 4; ++m)
#pragma unroll
    for (int nf = 0; nf < 2; ++nf)
#pragma unroll
      for (int r = 0; r < 4; ++r){
        int p = m*16 + l4*4 + r;
        int n = wave*32 + nf*16 + l16;
        Sc[base + p*128 + n] = f2bf(acc[m][nf][r]);
      }
}

// ---------------- chunk recurrence: h <- h*Dc + Sc ; writes h_in over Sc in place ----------------
__global__ __launch_bounds__(256) void k_chunkscan(ushort* __restrict__ Sc,
                                                   const float* __restrict__ Dcb){
  size_t idx = (size_t)blockIdx.x*256 + threadIdx.x;   // 2,097,152 total
  int bh = (int)(idx >> 13);
  int pn = (int)(idx & 8191);
  float hv = 0.f;
  for (int c = 0; c < 8; ++c){
    size_t o = (size_t)(bh*8 + c)*8192 + pn;
    float s = bf2f(Sc[o]);
    float dc = Dcb[bh*8 + c];
    Sc[o] = f2bf(hv);
    hv = hv*dc + s;
  }
}

// ---------------- main SSD chunk kernel: y = (mask.(C@B^T))@X + decay*(C@h^T), gated ----------------
__global__ __launch_bounds__(256) void k_ssd(
    const ushort* __restrict__ co, const ushort* __restrict__ zz,
    const ushort* __restrict__ dtc, const ushort* __restrict__ xhT,
    const ushort* __restrict__ Hin,
    const float* __restrict__ dt_bias, const float* __restrict__ A_log,
    const float* __restrict__ D_param,
    ushort* __restrict__ yv){
  __shared__ __align__(16) ushort sC [128*128];  // 32KB C tile (swizzled)
  __shared__ __align__(16) ushort sBP[128*128];  // 32KB B tile, then P (swizzled)
  __shared__ __align__(16) ushort sXT[64*128];   // 16KB x^T tile (swizzled)
  __shared__ __align__(16) ushort sH [64*128];   // 16KB h_in (swizzled)
  __shared__ float csv[128], dtv[128];
  const int bid = blockIdx.x;
  const int h = bid & 31, bc = bid >> 5, b = bc >> 3, c = bc & 7;
  const int tid = threadIdx.x, wave = tid >> 6, lane = tid & 63;
  const int l16 = lane & 15, l4 = lane >> 4;
  const int row0 = b*1024 + c*128;
  const ushort* cbase = co + (size_t)row0*CONVDIM;
  for (int i2 = 0; i2 < 8; ++i2){
    int itg = wave*8 + i2;
    int r = itg*4 + l4;
    int cc = l16 ^ (r & 7);
    gload16(cbase + (size_t)r*CONVDIM + 2176 + cc*8, &sC [itg*512]);
    gload16(cbase + (size_t)r*CONVDIM + 2048 + cc*8, &sBP[itg*512]);
  }
  {
    const ushort* xsrc = xhT + (size_t)(b*2048 + h*64)*1024 + c*128;
    const size_t hbase = (size_t)((b*32 + h)*8 + c)*8192;
    for (int i2 = 0; i2 < 4; ++i2){
      int itg = wave*4 + i2;
      int r = itg*4 + l4;
      int cc = l16 ^ (r & 7);
      gload16(xsrc + (size_t)r*1024 + cc*8, &sXT[itg*512]);
      gload16(Hin + hbase + r*128 + cc*8, &sH[itg*512]);
    }
  }
  const float Ah = -__expf(A_log[h]);
  if (wave == 0){
    float bi = dt_bias[h];
    float d0 = bf2f(dtc[(size_t)(row0 + 2*lane    )*32 + h]) + bi;
    float d1 = bf2f(dtc[(size_t)(row0 + 2*lane + 1)*32 + h]) + bi;
    d0 = (d0 > 20.f) ? d0 : log1pf(__expf(d0));
    d1 = (d1 > 20.f) ? d1 : log1pf(__expf(d1));
    float p = d0 + d1;
#pragma unroll
    for (int o = 1; o < 64; o <<= 1){
      float tp = __shfl_up(p, o);
      if (lane >= o) p += tp;
    }
    csv[2*lane    ] = p - d1;
    csv[2*lane + 1] = p;
    dtv[2*lane    ] = d0;
    dtv[2*lane + 1] = d1;
  }
  __syncthreads();
  const int wr = wave >> 1, wc = wave & 1;
  // GEMM1: S[i][s] = C[i].B[s]
  f32x4 acc[4][4];
#pragma unroll
  for (int m=0;m<4;m++)
#pragma unroll
    for (int n=0;n<4;n++) acc[m][n] = (f32x4){0.f,0.f,0.f,0.f};
  for (int ks = 0; ks < 4; ++ks){
    bf16x8 av[4], bv[4];
#pragma unroll
    for (int m = 0; m < 4; ++m){
      int ri = wr*64 + m*16 + l16;
      av[m] = *(const bf16x8*)&sC[ri*128 + (((ks*4 + l4) ^ (ri & 7))*8)];
    }
#pragma unroll
    for (int n = 0; n < 4; ++n){
      int rs = wc*64 + n*16 + l16;
      bv[n] = *(const bf16x8*)&sBP[rs*128 + (((ks*4 + l4) ^ (rs & 7))*8)];
    }
#pragma unroll
    for (int m = 0; m < 4; ++m)
#pragma unroll
      for (int n = 0; n < 4; ++n)
        acc[m][n] = __builtin_amdgcn_mfma_f32_16x16x32_bf16(av[m], bv[n], acc[m][n], 0, 0, 0);
  }
  __syncthreads();
  // mask + dt + D-diagonal -> P (bf16, over B tile)
  const float Dp = D_param[h];
#pragma unroll
  for (int m = 0; m < 4; ++m){
#pragma unroll
    for (int r = 0; r < 4; ++r){
      int i = wr*64 + m*16 + l4*4 + r;
      float ci = csv[i];
#pragma unroll
      for (int n = 0; n < 4; ++n){
        int s = wc*64 + n*16 + l16;
        float e = __expf(Ah*(ci - csv[s]));
        float v = (i >= s) ? acc[m][n][r]*e*dtv[s] : 0.f;
        if (i == s) v += Dp;
        sBP[i*128 + (s ^ ((i & 7)<<3))] = f2bf(v);
      }
    }
  }
  __syncthreads();
  // GEMM2: Y[i][p] = P@X^T + Ei*(C@h^T)
  f32x4 accY[4][2], accI[4][2];
#pragma unroll
  for (int m=0;m<4;m++)
#pragma unroll
    for (int n=0;n<2;n++){ accY[m][n] = (f32x4){0.f,0.f,0.f,0.f}; accI[m][n] = (f32x4){0.f,0.f,0.f,0.f}; }
  for (int ks = 0; ks < 4; ++ks){
    bf16x8 pa[4], ca[4], xb[2], hb[2];
#pragma unroll
    for (int m = 0; m < 4; ++m){
      int ri = wr*64 + m*16 + l16;
      int off = ((ks*4 + l4) ^ (ri & 7))*8;
      pa[m] = *(const bf16x8*)&sBP[ri*128 + off];
      ca[m] = *(const bf16x8*)&sC [ri*128 + off];
    }
#pragma unroll
    for (int n = 0; n < 2; ++n){
      int rp = wc*32 + n*16 + l16;
      int off = ((ks*4 + l4) ^ (rp & 7))*8;
      xb[n] = *(const bf16x8*)&sXT[rp*128 + off];
      hb[n] = *(const bf16x8*)&sH [rp*128 + off];
    }
#pragma unroll
    for (int m = 0; m < 4; ++m)
#pragma unroll
      for (int n = 0; n < 2; ++n){
        accY[m][n] = __builtin_amdgcn_mfma_f32_16x16x32_bf16(pa[m], xb[n], accY[m][n], 0, 0, 0);
        accI[m][n] = __builtin_amdgcn_mfma_f32_16x16x32_bf16(ca[m], hb[n], accI[m][n], 0, 0, 0);
      }
  }
#pragma unroll
  for (int m = 0; m < 4; ++m){
#pragma unroll
    for (int r = 0; r < 4; ++r){
      int i = wr*64 + m*16 + l4*4 + r;
      float Ei = __expf(Ah*csv[i]);
      int grow = row0 + i;
#pragma unroll
      for (int n = 0; n < 2; ++n){
        int p = wc*32 + n*16 + l16;
        float yvl = accY[m][n][r] + Ei*accI[m][n][r];
        float z = bf2f(zz[(size_t)grow*2048 + h*64 + p]);
        yv[(size_t)grow*DI + h*64 + p] = f2bf(yvl * siluf(z));
      }
    }
  }
}

extern "C" void kernel_launch(void* const* d_in, const int* in_sizes, int n_in,
                              void* d_out, int out_size, void* d_ws, size_t ws_size,
                              hipStream_t stream){
  const float* x       = (const float*)d_in[0];
  const float* t       = (const float*)d_in[1];
  const float* y       = (const float*)d_in[2];
  const float* w_ada   = (const float*)d_in[3];
  const float* b_ada   = (const float*)d_in[4];
  const float* w_in    = (const float*)d_in[5];
  const float* conv_w  = (const float*)d_in[6];
  const float* conv_b  = (const float*)d_in[7];
  const float* dt_bias = (const float*)d_in[8];
  const float* A_log   = (const float*)d_in[9];
  const float* D_param = (const float*)d_in[10];
  const float* w_out   = (const float*)d_in[11];

  char* w = (char*)d_ws;
  size_t off = 0;
  auto alloc = [&](size_t bytes)->char*{
    char* p = w + off; off += (bytes + 255) & ~(size_t)255; return p;
  };
  ushort* zz    = (ushort*)alloc((size_t)ROWS*2048*2);   // z part of in_proj
  ushort* xbc   = (ushort*)alloc((size_t)ROWS*CONVDIM*2);// conv input; xhT alias (33.6<=37.7MB)
  ushort* dtc   = (ushort*)alloc((size_t)ROWS*32*2);     // dt logits
  ushort* co    = (ushort*)alloc((size_t)ROWS*CONVDIM*2);
  ushort* Mss   = (ushort*)alloc((size_t)ROWS*2048*2);   // shift|scale -> Sc alias
  ushort* Mg    = (ushort*)alloc((size_t)ROWS*1024*2);   // gate
  ushort* yv    = (ushort*)alloc((size_t)ROWS*DI*2);
  ushort* woutT = (ushort*)alloc(1024ull*2048*2);
  ushort* waT   = (ushort*)alloc(3072ull*1024*2);
  ushort* winT  = (ushort*)alloc(4608ull*1024*2);        // padded 4384 -> 4608 (18*256)
  float*  atb   = (float*) alloc(8ull*3072*4);
  ushort* Ya    = (ushort*)alloc((size_t)ROWS*1024*2);   // silu(y) -> mod
  ushort* BTg   = (ushort*)alloc((size_t)8*128*1024*2);
  float*  Dcb   = (float*) alloc(2048ull*4);
  ushort* xhT   = xbc;   // alias: xbc dead after k_conv; xhT needs 33.6MB <= 37.7MB
  ushort* Sc    = Mss;   // alias: Mss dead after k_lnmod; same size (33.6MB)

  // 1. Ya = bf16(silu(y))
  k_silu_cast<<<dim3(ROWS*1024/(256*4)), 256, 0, stream>>>(y, Ya, ROWS*1024);
  // 2. weight transposes (f32 -> bf16 [N][K])
  k_transpose_cast<<<dim3(96,32),  256, 0, stream>>>(w_ada, waT,  1024, 3072);
  k_transpose_cast<<<dim3(137,32), 256, 0, stream>>>(w_in,  winT, 1024, 4384);
  k_transpose_cast<<<dim3(32,64),  256, 0, stream>>>(w_out, woutT, 2048, 1024);
  // 3. at = silu(t)@w_ada + b_ada  (f32)
  k_at<<<dim3(12,8), 256, 0, stream>>>(t, w_ada, b_ada, atb);
  // 4. [shift|scale] -> Mss, gate -> Mg   (grid 32x12=384)
  k_gemm8<1><<<dim3(384), 512, 131072, stream>>>(Ya, waT, Mss, Mg, nullptr, nullptr,
                                                 ROWS, 3072, 1024, 12, b_ada, atb, nullptr, nullptr);
  // 5. mod = LN(x)*(1+scale)+shift  (into Ya)
  k_lnmod<<<dim3(ROWS), 256, 0, stream>>>(x, Mss, Ya);
  // 6. in_proj: zz | xbc | dtc   (grid 32x18=576, N padded to 4608)
  k_gemm8<0><<<dim3(576), 512, 131072, stream>>>(Ya, winT, zz, xbc, dtc, nullptr,
                                                 ROWS, 4384, 1024, 18, nullptr, nullptr, nullptr, nullptr);
  // 7. conv4 + silu
  k_conv<<<dim3(9,ROWS), 256, 0, stream>>>(xbc, conv_w, conv_b, co);
  // 8. transpose xh+B -> xhT (over xbc), BTg
  k_transT<<<dim3(34,16,8), 256, 0, stream>>>(co, xhT, BTg);
  // 9. per-chunk state contributions (Sc over Mss)
  k_chunkstate<<<dim3(2048), 256, 0, stream>>>(xhT, BTg, dtc, dt_bias, A_log, Sc, Dcb);
  // 10. chunk-state recurrence (in place: Sc -> h_in)
  k_chunkscan<<<dim3(8192), 256, 0, stream>>>(Sc, Dcb);
  // 11. SSD main: intra + inter + D + silu(z) gate -> yv
  k_ssd<<<dim3(2048), 256, 0, stream>>>(co, zz, dtc, xhT, Sc, dt_bias, A_log, D_param, yv);
  // 12. out = gate * (yv @ w_out) + x   (grid 32x4=128)
  k_gemm8<2><<<dim3(128), 512, 131072, stream>>>(yv, woutT, nullptr, nullptr, nullptr, (float*)d_out,
                                                 ROWS, 1024, 2048, 4, nullptr, nullptr, Mg, x);
}

// Round 7
// 541.880 us; speedup vs baseline: 1.0868x; 1.0868x over previous
//
#include <hip/hip_runtime.h>

typedef float f32x4 __attribute__((ext_vector_type(4)));
typedef __bf16 bf16x8 __attribute__((ext_vector_type(8)));
typedef unsigned short ushort;
typedef ushort ushort8 __attribute__((ext_vector_type(8)));
typedef ushort ushort4v __attribute__((ext_vector_type(4)));

#define DM 1024
#define DI 2048
#define DSTATE 128
#define NH 32
#define HD 64
#define CONVDIM 2304
#define DPROJ 4384
#define ROWS 8192

__device__ __forceinline__ float bf2f(ushort u){
  union { unsigned int i; float f; } v; v.i = ((unsigned int)u)<<16; return v.f;
}
__device__ __forceinline__ ushort f2bf(float f){
  union { float f; unsigned int i; } v; v.f = f;
  unsigned int r = v.i + 0x7FFFu + ((v.i>>16)&1u);
  return (ushort)(r>>16);
}
__device__ __forceinline__ float siluf(float x){ return x / (1.f + __expf(-x)); }

__device__ __forceinline__ void gload16(const ushort* g, ushort* l){
  __builtin_amdgcn_global_load_lds(
      (const __attribute__((address_space(1))) void*)g,
      (__attribute__((address_space(3))) void*)l, 16, 0, 0);
}

// ---------------- elementwise: Ya = bf16(silu(y)) ----------------
__global__ __launch_bounds__(256) void k_silu_cast(const float* __restrict__ in,
                                                   ushort* __restrict__ out, int n){
  int i = (blockIdx.x*256 + threadIdx.x)*4;
  if (i >= n) return;
  float4 v = *(const float4*)(in + i);
  ushort4v o;
  o.x = f2bf(siluf(v.x)); o.y = f2bf(siluf(v.y));
  o.z = f2bf(siluf(v.z)); o.w = f2bf(siluf(v.w));
  *(ushort4v*)(out + i) = o;
}

// ---------------- weight transpose+cast: in[K][N] f32 -> out[N][K] bf16 ----------------
__global__ __launch_bounds__(256) void k_transpose_cast(const float* __restrict__ in,
                                                        ushort* __restrict__ out,
                                                        int K, int N){
  __shared__ float tile[32][33];
  int n0 = blockIdx.x*32, k0 = blockIdx.y*32;
  int tx = threadIdx.x & 31, ty = threadIdx.x >> 5; // 32x8
  for (int r = ty; r < 32; r += 8) tile[r][tx] = in[(size_t)(k0+r)*N + n0+tx];
  __syncthreads();
  for (int r = ty; r < 32; r += 8) out[(size_t)(n0+r)*K + k0+tx] = f2bf(tile[tx][r]);
}

// ---------------- at[b][n] = silu(t[b]) @ w_ada + b_ada ----------------
__global__ __launch_bounds__(256) void k_at(const float* __restrict__ t,
                                            const float* __restrict__ w_ada,
                                            const float* __restrict__ b_ada,
                                            float* __restrict__ at){
  __shared__ float st[1024];
  int b = blockIdx.y;
  int col = blockIdx.x*256 + threadIdx.x;
  for (int i = threadIdx.x; i < 1024; i += 256) st[i] = siluf(t[b*1024 + i]);
  __syncthreads();
  float acc = 0.f;
  for (int k = 0; k < 1024; ++k) acc += st[k] * w_ada[(size_t)k*3072 + col];
  at[b*3072 + col] = acc + b_ada[col];
}

// ---------------- GEMM: 128x128 tile, BK=32, 4 waves, TRIPLE-buffer counted-vmcnt ----------------
// Tile T: compute from buf[T%3]; stage tile T+2 into buf[(T+2)%3]; vmcnt(4)+s_barrier.
// Read/in-flight/stage buffers always distinct mod 3 -> no WAR hazard.
// LDS swizzle (verified r4): stage col kcs=(lane&3)^((lane>>3)&3); read chunk kbs=(kb^((l16>>1)&3))*8.
#define STG(Q, KT) do{ \
  gload16(pA0 + (size_t)(KT)*32, &sm[(Q)*8192 + (wave*2+0)*512]); \
  gload16(pA1 + (size_t)(KT)*32, &sm[(Q)*8192 + (wave*2+1)*512]); \
  gload16(pB0 + (size_t)(KT)*32, &sm[(Q)*8192 + 4096 + (wave*2+0)*512]); \
  gload16(pB1 + (size_t)(KT)*32, &sm[(Q)*8192 + 4096 + (wave*2+1)*512]); }while(0)

#define CMP(BOFF) do{ \
  bf16x8 af[4], bfr[4]; \
  _Pragma("unroll") \
  for (int m=0;m<4;m++) af[m]  = *(const bf16x8*)&sm[(BOFF) + (wr*64 + m*16 + l16)*32 + kbs]; \
  _Pragma("unroll") \
  for (int n=0;n<4;n++) bfr[n] = *(const bf16x8*)&sm[(BOFF) + 4096 + (wc*64 + n*16 + l16)*32 + kbs]; \
  __builtin_amdgcn_s_setprio(1); \
  _Pragma("unroll") \
  for (int m=0;m<4;m++) \
    _Pragma("unroll") \
    for (int n=0;n<4;n++) \
      acc[m][n] = __builtin_amdgcn_mfma_f32_16x16x32_bf16(af[m], bfr[n], acc[m][n], 0, 0, 0); \
  __builtin_amdgcn_s_setprio(0); }while(0)

#define BODY(Q, T) do{ \
  STG(((Q)+2)%3, (T)+2); \
  CMP((Q)*8192); \
  asm volatile("s_waitcnt vmcnt(4)" ::: "memory"); \
  __builtin_amdgcn_s_barrier(); \
  __builtin_amdgcn_sched_barrier(0); }while(0)

template<int EPI>
__global__ __launch_bounds__(256)
void k_gemm(const ushort* __restrict__ Ag, const ushort* __restrict__ Bt,
            ushort* __restrict__ Cb, ushort* __restrict__ Cb2, ushort* __restrict__ Cb3,
            float* __restrict__ Cf,
            int M, int N, int K,
            const float* __restrict__ bias, const float* __restrict__ at,
            const ushort* __restrict__ gateM, const float* __restrict__ xres){
  __shared__ __align__(16) ushort sm[3*8192];   // 3 bufs x (A 8KB + B 8KB) = 48KB
  const int tid  = threadIdx.x;
  const int wave = tid >> 6, lane = tid & 63;
  const int bn = blockIdx.x, bm = blockIdx.y;
  const int wr = wave >> 1, wc = wave & 1;
  const int l16 = lane & 15, kb = lane >> 4;
  const int arow0 = (wave*2+0)*16 + (lane>>2);
  const int arow1 = (wave*2+1)*16 + (lane>>2);
  const int kcs = (lane & 3) ^ ((lane>>3)&3);
  const int kbs = (kb ^ ((l16>>1)&3))*8;

  const ushort* pA0 = Ag + (size_t)(bm*128 + arow0)*K + kcs*8;
  const ushort* pA1 = Ag + (size_t)(bm*128 + arow1)*K + kcs*8;
  int br0 = bn*128 + arow0; if (br0 > N-1) br0 = N-1;
  int br1 = bn*128 + arow1; if (br1 > N-1) br1 = N-1;
  const ushort* pB0 = Bt + (size_t)br0*K + kcs*8;
  const ushort* pB1 = Bt + (size_t)br1*K + kcs*8;

  f32x4 acc[4][4];
#pragma unroll
  for (int m=0;m<4;m++)
#pragma unroll
    for (int n=0;n<4;n++) acc[m][n] = (f32x4){0.f,0.f,0.f,0.f};

  const int NT = K >> 5;
  const int NB = NT - 2;

  // prologue: stage tiles 0,1; wait tile0 landed
  STG(0, 0); STG(1, 1);
  asm volatile("s_waitcnt vmcnt(4)" ::: "memory");
  __builtin_amdgcn_s_barrier();
  __builtin_amdgcn_sched_barrier(0);

  int T = 0;
  for (; T + 3 <= NB; T += 3){
    BODY(0, T); BODY(1, T+1); BODY(2, T+2);
  }
  if (NB - T >= 1) BODY(0, T);
  if (NB - T >= 2) BODY(1, T+1);

  // tail: tiles NB, NB+1 already staged
  {
    const int qa = NB % 3, qb = (NB + 1) % 3;
    CMP(qa*8192);
    asm volatile("s_waitcnt vmcnt(0)" ::: "memory");
    __builtin_amdgcn_s_barrier();
    __builtin_amdgcn_sched_barrier(0);
    CMP(qb*8192);
  }

#pragma unroll
  for (int m=0;m<4;m++){
    int grow_base = bm*128 + wr*64 + m*16 + (lane>>4)*4;
#pragma unroll
    for (int n=0;n<4;n++){
      int gcol = bn*128 + wc*64 + n*16 + l16;
      if (EPI == 0){
        if (gcol < N){
#pragma unroll
          for (int r=0;r<4;r++){
            int row = grow_base + r;
            float v = acc[m][n][r];
            if (gcol < 2048)      Cb [(size_t)row*2048 + gcol] = f2bf(v);
            else if (gcol < 4352) Cb2[(size_t)row*2304 + (gcol-2048)] = f2bf(v);
            else                  Cb3[(size_t)row*32   + (gcol-4352)] = f2bf(v);
          }
        }
      } else if (EPI == 1){
        float bv = bias[gcol];
#pragma unroll
        for (int r=0;r<4;r++){
          int row = grow_base + r;
          float v = acc[m][n][r] + bv + at[(row>>10)*3072 + gcol];
          if (gcol < 2048) Cb [(size_t)row*2048 + gcol] = f2bf(v);
          else             Cb2[(size_t)row*1024 + (gcol - 2048)] = f2bf(v);
        }
      } else {
#pragma unroll
        for (int r=0;r<4;r++){
          int row = grow_base + r;
          float g = bf2f(gateM[(size_t)row*1024 + gcol]);
          Cf[(size_t)row*1024 + gcol] = g*acc[m][n][r] + xres[(size_t)row*1024 + gcol];
        }
      }
    }
  }
}

// ---------------- LN + modulation: mod = LN(x)*(1+scale)+shift (bf16) ----------------
__global__ __launch_bounds__(256) void k_lnmod(const float* __restrict__ x,
                                               const ushort* __restrict__ Mss,
                                               ushort* __restrict__ mod){
  int row = blockIdx.x;
  const float* xr = x + (size_t)row*1024;
  float v[4]; float s = 0.f, s2 = 0.f;
#pragma unroll
  for (int j=0;j<4;j++){ v[j] = xr[threadIdx.x + j*256]; s += v[j]; s2 += v[j]*v[j]; }
#pragma unroll
  for (int o=32;o>0;o>>=1){ s += __shfl_down(s,o); s2 += __shfl_down(s2,o); }
  __shared__ float ls[4], ls2[4];
  int wv = threadIdx.x >> 6;
  if ((threadIdx.x & 63) == 0){ ls[wv] = s; ls2[wv] = s2; }
  __syncthreads();
  s  = ls[0]+ls[1]+ls[2]+ls[3];
  s2 = ls2[0]+ls2[1]+ls2[2]+ls2[3];
  float mu = s * (1.f/1024.f);
  float var = s2 * (1.f/1024.f) - mu*mu;
  float rstd = rsqrtf(var + 1e-6f);
  const ushort* Mr = Mss + (size_t)row*2048;
#pragma unroll
  for (int j=0;j<4;j++){
    int d = threadIdx.x + j*256;
    float sc = bf2f(Mr[1024 + d]);
    float sh = bf2f(Mr[d]);
    mod[(size_t)row*1024 + d] = f2bf((v[j]-mu)*rstd*(1.f+sc) + sh);
  }
}

// ---------------- causal conv4 + silu over xbc ----------------
__global__ __launch_bounds__(256) void k_conv(const ushort* __restrict__ xbc,
                                              const float* __restrict__ conv_w,
                                              const float* __restrict__ conv_b,
                                              ushort* __restrict__ co){
  int ch  = blockIdx.x*256 + threadIdx.x;   // < 2304
  int row = blockIdx.y;                      // < 8192
  int l = row & 1023, b = row >> 10;
  float acc = conv_b[ch];
#pragma unroll
  for (int k=0;k<4;k++){
    int ll = l - 3 + k;
    if (ll >= 0) acc += conv_w[ch*4 + k] * bf2f(xbc[(size_t)(b*1024 + ll)*CONVDIM + ch]);
  }
  co[(size_t)row*CONVDIM + ch] = f2bf(siluf(acc));
}

// ---------------- transpose co cols [0,2176) -> xhT [b*2048+c][l], BTg [b*128+n][l] ----------------
__global__ __launch_bounds__(256) void k_transT(const ushort* __restrict__ co,
                                                ushort* __restrict__ xhT,
                                                ushort* __restrict__ BTg){
  __shared__ ushort tile[64*72];
  const int c0 = blockIdx.x*64, l0 = blockIdx.y*64, b = blockIdx.z;
  const int tid = threadIdx.x;
  for (int q = tid; q < 512; q += 256){
    int r = q >> 3, cc = q & 7;
    ushort8 v = *(const ushort8*)(co + (size_t)(b*1024 + l0 + r)*CONVDIM + c0 + cc*8);
    *(ushort8*)&tile[r*72 + cc*8] = v;
  }
  __syncthreads();
  for (int q = tid; q < 1024; q += 256){
    int oc = q >> 4, lc = (q & 15)*4;
    ushort4v o;
#pragma unroll
    for (int j = 0; j < 4; ++j) o[j] = tile[(lc + j)*72 + oc];
    int ccol = c0 + oc;
    ushort* out = (ccol < 2048) ? (xhT + (size_t)(b*2048 + ccol)*1024)
                                : (BTg + (size_t)(b*128 + (ccol - 2048))*1024);
    *(ushort4v*)(out + l0 + lc) = o;
  }
}

// ---------------- chunk state contribution: Sc[p][n] = sum_s G[s]*x[s,p]*B[s,n] ----------------
__global__ __launch_bounds__(256) void k_chunkstate(
    const ushort* __restrict__ xhT, const ushort* __restrict__ BTg,
    const ushort* __restrict__ dtc,
    const float* __restrict__ dt_bias, const float* __restrict__ A_log,
    ushort* __restrict__ Sc, float* __restrict__ Dcb){
  __shared__ __align__(16) ushort sXG[64*128];   // 16KB (swizzled)
  __shared__ __align__(16) ushort sBT[128*128];  // 32KB (swizzled)
  __shared__ float sG[128];
  const int bid = blockIdx.x;
  const int h = bid & 31, bc = bid >> 5, b = bc >> 3, c = bc & 7;
  const int tid = threadIdx.x, wave = tid >> 6, lane = tid & 63;
  const int l16 = lane & 15, l4 = lane >> 4;
  const int sci = (b*32 + h)*8 + c;
  {
    const ushort* src = BTg + (size_t)(b*128)*1024 + c*128;
    for (int i2 = 0; i2 < 8; ++i2){
      int itg = wave*8 + i2;
      int r = itg*4 + l4;
      int cc = l16 ^ (r & 7);
      gload16(src + (size_t)r*1024 + cc*8, &sBT[itg*512]);
    }
  }
  const float Ah = -__expf(A_log[h]);
  if (wave == 0){
    const int row0 = b*1024 + c*128;
    float bi = dt_bias[h];
    float d0 = bf2f(dtc[(size_t)(row0 + 2*lane    )*32 + h]) + bi;
    float d1 = bf2f(dtc[(size_t)(row0 + 2*lane + 1)*32 + h]) + bi;
    d0 = (d0 > 20.f) ? d0 : log1pf(__expf(d0));
    d1 = (d1 > 20.f) ? d1 : log1pf(__expf(d1));
    float p = d0 + d1;
#pragma unroll
    for (int o = 1; o < 64; o <<= 1){
      float tp = __shfl_up(p, o);
      if (lane >= o) p += tp;
    }
    float cs127 = __shfl(p, 63);
    sG[2*lane    ] = __expf(Ah*(cs127 - (p - d1))) * d0;
    sG[2*lane + 1] = __expf(Ah*(cs127 - p)) * d1;
    if (lane == 0) Dcb[sci] = __expf(Ah*cs127);
  }
  __syncthreads();
  {
    const ushort* xsrc = xhT + (size_t)(b*2048 + h*64)*1024 + c*128;
    for (int q = tid; q < 1024; q += 256){
      int r = q >> 4, cc = q & 15;
      ushort8 v = *(const ushort8*)(xsrc + (size_t)r*1024 + cc*8);
      ushort8 o;
#pragma unroll
      for (int j = 0; j < 8; ++j) o[j] = f2bf(bf2f(v[j]) * sG[cc*8 + j]);
      *(ushort8*)&sXG[r*128 + ((cc ^ (r & 7))*8)] = o;
    }
  }
  __syncthreads();
  f32x4 acc[4][2];
#pragma unroll
  for (int m=0;m<4;m++)
#pragma unroll
    for (int nf=0;nf<2;nf++) acc[m][nf] = (f32x4){0.f,0.f,0.f,0.f};
  for (int ks = 0; ks < 4; ++ks){
    bf16x8 av[4], bv[2];
#pragma unroll
    for (int m = 0; m < 4; ++m){
      int rp = m*16 + l16;
      av[m] = *(const bf16x8*)&sXG[rp*128 + (((ks*4 + l4) ^ (rp & 7))*8)];
    }
#pragma unroll
    for (int nf = 0; nf < 2; ++nf){
      int rn = wave*32 + nf*16 + l16;
      bv[nf] = *(const bf16x8*)&sBT[rn*128 + (((ks*4 + l4) ^ (rn & 7))*8)];
    }
#pragma unroll
    for (int m = 0; m < 4; ++m)
#pragma unroll
      for (int nf = 0; nf < 2; ++nf)
        acc[m][nf] = __builtin_amdgcn_mfma_f32_16x16x32_bf16(av[m], bv[nf], acc[m][nf], 0, 0, 0);
  }
  const size_t base = (size_t)sci * 8192;
#pragma unroll
  for (int m = 0; m < 4; ++m)
#pragma unroll
    for (int nf = 0; nf < 2; ++nf)
#pragma unroll
      for (int r = 0; r < 4; ++r){
        int p = m*16 + l4*4 + r;
        int n = wave*32 + nf*16 + l16;
        Sc[base + p*128 + n] = f2bf(acc[m][nf][r]);
      }
}

// ---------------- chunk recurrence: h <- h*Dc + Sc ; writes h_in over Sc in place ----------------
__global__ __launch_bounds__(256) void k_chunkscan(ushort* __restrict__ Sc,
                                                   const float* __restrict__ Dcb){
  size_t idx = (size_t)blockIdx.x*256 + threadIdx.x;   // 2,097,152 total
  int bh = (int)(idx >> 13);
  int pn = (int)(idx & 8191);
  float hv = 0.f;
  for (int c = 0; c < 8; ++c){
    size_t o = (size_t)(bh*8 + c)*8192 + pn;
    float s = bf2f(Sc[o]);
    float dc = Dcb[bh*8 + c];
    Sc[o] = f2bf(hv);
    hv = hv*dc + s;
  }
}

// ---------------- main SSD chunk kernel: y = (mask.(C@B^T))@X + decay*(C@h^T), gated ----------------
__global__ __launch_bounds__(256) void k_ssd(
    const ushort* __restrict__ co, const ushort* __restrict__ zz,
    const ushort* __restrict__ dtc, const ushort* __restrict__ xhT,
    const ushort* __restrict__ Hin,
    const float* __restrict__ dt_bias, const float* __restrict__ A_log,
    const float* __restrict__ D_param,
    ushort* __restrict__ yv){
  __shared__ __align__(16) ushort sC [128*128];  // 32KB C tile (swizzled)
  __shared__ __align__(16) ushort sBP[128*128];  // 32KB B tile, then P (swizzled)
  __shared__ __align__(16) ushort sXT[64*128];   // 16KB x^T tile (swizzled)
  __shared__ __align__(16) ushort sH [64*128];   // 16KB h_in (swizzled)
  __shared__ float csv[128], dtv[128];
  const int bid = blockIdx.x;
  const int h = bid & 31, bc = bid >> 5, b = bc >> 3, c = bc & 7;
  const int tid = threadIdx.x, wave = tid >> 6, lane = tid & 63;
  const int l16 = lane & 15, l4 = lane >> 4;
  const int row0 = b*1024 + c*128;
  const ushort* cbase = co + (size_t)row0*CONVDIM;
  for (int i2 = 0; i2 < 8; ++i2){
    int itg = wave*8 + i2;
    int r = itg*4 + l4;
    int cc = l16 ^ (r & 7);
    gload16(cbase + (size_t)r*CONVDIM + 2176 + cc*8, &sC [itg*512]);
    gload16(cbase + (size_t)r*CONVDIM + 2048 + cc*8, &sBP[itg*512]);
  }
  {
    const ushort* xsrc = xhT + (size_t)(b*2048 + h*64)*1024 + c*128;
    const size_t hbase = (size_t)((b*32 + h)*8 + c)*8192;
    for (int i2 = 0; i2 < 4; ++i2){
      int itg = wave*4 + i2;
      int r = itg*4 + l4;
      int cc = l16 ^ (r & 7);
      gload16(xsrc + (size_t)r*1024 + cc*8, &sXT[itg*512]);
      gload16(Hin + hbase + r*128 + cc*8, &sH[itg*512]);
    }
  }
  const float Ah = -__expf(A_log[h]);
  if (wave == 0){
    float bi = dt_bias[h];
    float d0 = bf2f(dtc[(size_t)(row0 + 2*lane    )*32 + h]) + bi;
    float d1 = bf2f(dtc[(size_t)(row0 + 2*lane + 1)*32 + h]) + bi;
    d0 = (d0 > 20.f) ? d0 : log1pf(__expf(d0));
    d1 = (d1 > 20.f) ? d1 : log1pf(__expf(d1));
    float p = d0 + d1;
#pragma unroll
    for (int o = 1; o < 64; o <<= 1){
      float tp = __shfl_up(p, o);
      if (lane >= o) p += tp;
    }
    csv[2*lane    ] = p - d1;
    csv[2*lane + 1] = p;
    dtv[2*lane    ] = d0;
    dtv[2*lane + 1] = d1;
  }
  __syncthreads();
  const int wr = wave >> 1, wc = wave & 1;
  // GEMM1: S[i][s] = C[i].B[s]
  f32x4 acc[4][4];
#pragma unroll
  for (int m=0;m<4;m++)
#pragma unroll
    for (int n=0;n<4;n++) acc[m][n] = (f32x4){0.f,0.f,0.f,0.f};
  for (int ks = 0; ks < 4; ++ks){
    bf16x8 av[4], bv[4];
#pragma unroll
    for (int m = 0; m < 4; ++m){
      int ri = wr*64 + m*16 + l16;
      av[m] = *(const bf16x8*)&sC[ri*128 + (((ks*4 + l4) ^ (ri & 7))*8)];
    }
#pragma unroll
    for (int n = 0; n < 4; ++n){
      int rs = wc*64 + n*16 + l16;
      bv[n] = *(const bf16x8*)&sBP[rs*128 + (((ks*4 + l4) ^ (rs & 7))*8)];
    }
#pragma unroll
    for (int m = 0; m < 4; ++m)
#pragma unroll
      for (int n = 0; n < 4; ++n)
        acc[m][n] = __builtin_amdgcn_mfma_f32_16x16x32_bf16(av[m], bv[n], acc[m][n], 0, 0, 0);
  }
  __syncthreads();
  // mask + dt + D-diagonal -> P (bf16, over B tile)
  const float Dp = D_param[h];
#pragma unroll
  for (int m = 0; m < 4; ++m){
#pragma unroll
    for (int r = 0; r < 4; ++r){
      int i = wr*64 + m*16 + l4*4 + r;
      float ci = csv[i];
#pragma unroll
      for (int n = 0; n < 4; ++n){
        int s = wc*64 + n*16 + l16;
        float e = __expf(Ah*(ci - csv[s]));
        float v = (i >= s) ? acc[m][n][r]*e*dtv[s] : 0.f;
        if (i == s) v += Dp;
        sBP[i*128 + (s ^ ((i & 7)<<3))] = f2bf(v);
      }
    }
  }
  __syncthreads();
  // GEMM2: Y[i][p] = P@X^T + Ei*(C@h^T)
  f32x4 accY[4][2], accI[4][2];
#pragma unroll
  for (int m=0;m<4;m++)
#pragma unroll
    for (int n=0;n<2;n++){ accY[m][n] = (f32x4){0.f,0.f,0.f,0.f}; accI[m][n] = (f32x4){0.f,0.f,0.f,0.f}; }
  for (int ks = 0; ks < 4; ++ks){
    bf16x8 pa[4], ca[4], xb[2], hb[2];
#pragma unroll
    for (int m = 0; m < 4; ++m){
      int ri = wr*64 + m*16 + l16;
      int off = ((ks*4 + l4) ^ (ri & 7))*8;
      pa[m] = *(const bf16x8*)&sBP[ri*128 + off];
      ca[m] = *(const bf16x8*)&sC [ri*128 + off];
    }
#pragma unroll
    for (int n = 0; n < 2; ++n){
      int rp = wc*32 + n*16 + l16;
      int off = ((ks*4 + l4) ^ (rp & 7))*8;
      xb[n] = *(const bf16x8*)&sXT[rp*128 + off];
      hb[n] = *(const bf16x8*)&sH [rp*128 + off];
    }
#pragma unroll
    for (int m = 0; m < 4; ++m)
#pragma unroll
      for (int n = 0; n < 2; ++n){
        accY[m][n] = __builtin_amdgcn_mfma_f32_16x16x32_bf16(pa[m], xb[n], accY[m][n], 0, 0, 0);
        accI[m][n] = __builtin_amdgcn_mfma_f32_16x16x32_bf16(ca[m], hb[n], accI[m][n], 0, 0, 0);
      }
  }
#pragma unroll
  for (int m = 0; m < 4; ++m){
#pragma unroll
    for (int r = 0; r < 4; ++r){
      int i = wr*64 + m*16 + l4*4 + r;
      float Ei = __expf(Ah*csv[i]);
      int grow = row0 + i;
#pragma unroll
      for (int n = 0; n < 2; ++n){
        int p = wc*32 + n*16 + l16;
        float yvl = accY[m][n][r] + Ei*accI[m][n][r];
        float z = bf2f(zz[(size_t)grow*2048 + h*64 + p]);
        yv[(size_t)grow*DI + h*64 + p] = f2bf(yvl * siluf(z));
      }
    }
  }
}

extern "C" void kernel_launch(void* const* d_in, const int* in_sizes, int n_in,
                              void* d_out, int out_size, void* d_ws, size_t ws_size,
                              hipStream_t stream){
  const float* x       = (const float*)d_in[0];
  const float* t       = (const float*)d_in[1];
  const float* y       = (const float*)d_in[2];
  const float* w_ada   = (const float*)d_in[3];
  const float* b_ada   = (const float*)d_in[4];
  const float* w_in    = (const float*)d_in[5];
  const float* conv_w  = (const float*)d_in[6];
  const float* conv_b  = (const float*)d_in[7];
  const float* dt_bias = (const float*)d_in[8];
  const float* A_log   = (const float*)d_in[9];
  const float* D_param = (const float*)d_in[10];
  const float* w_out   = (const float*)d_in[11];

  char* w = (char*)d_ws;
  size_t off = 0;
  auto alloc = [&](size_t bytes)->char*{
    char* p = w + off; off += (bytes + 255) & ~(size_t)255; return p;
  };
  ushort* zz    = (ushort*)alloc((size_t)ROWS*2048*2);   // z part of in_proj
  ushort* xbc   = (ushort*)alloc((size_t)ROWS*CONVDIM*2);// conv input; xhT alias (33.6<=37.7MB)
  ushort* dtc   = (ushort*)alloc((size_t)ROWS*32*2);     // dt logits
  ushort* co    = (ushort*)alloc((size_t)ROWS*CONVDIM*2);
  ushort* Mss   = (ushort*)alloc((size_t)ROWS*2048*2);   // shift|scale -> Sc alias
  ushort* Mg    = (ushort*)alloc((size_t)ROWS*1024*2);   // gate
  ushort* yv    = (ushort*)alloc((size_t)ROWS*DI*2);
  ushort* woutT = (ushort*)alloc(1024ull*2048*2);
  ushort* waT   = (ushort*)alloc(3072ull*1024*2);
  ushort* winT  = (ushort*)alloc(4608ull*1024*2);
  float*  atb   = (float*) alloc(8ull*3072*4);
  ushort* Ya    = (ushort*)alloc((size_t)ROWS*1024*2);   // silu(y) -> mod
  ushort* BTg   = (ushort*)alloc((size_t)8*128*1024*2);
  float*  Dcb   = (float*) alloc(2048ull*4);
  ushort* xhT   = xbc;   // alias: xbc dead after k_conv; xhT needs 33.6MB <= 37.7MB
  ushort* Sc    = Mss;   // alias: Mss dead after k_lnmod; same size (33.6MB)

  // 1. Ya = bf16(silu(y))
  k_silu_cast<<<dim3(ROWS*1024/(256*4)), 256, 0, stream>>>(y, Ya, ROWS*1024);
  // 2. weight transposes (f32 -> bf16 [N][K])
  k_transpose_cast<<<dim3(96,32),  256, 0, stream>>>(w_ada, waT,  1024, 3072);
  k_transpose_cast<<<dim3(137,32), 256, 0, stream>>>(w_in,  winT, 1024, 4384);
  k_transpose_cast<<<dim3(32,64),  256, 0, stream>>>(w_out, woutT, 2048, 1024);
  // 3. at = silu(t)@w_ada + b_ada  (f32)
  k_at<<<dim3(12,8), 256, 0, stream>>>(t, w_ada, b_ada, atb);
  // 4. [shift|scale] -> Mss, gate -> Mg
  k_gemm<1><<<dim3(24,64), 256, 0, stream>>>(Ya, waT, Mss, Mg, nullptr, nullptr, ROWS, 3072, 1024,
                                             b_ada, atb, nullptr, nullptr);
  // 5. mod = LN(x)*(1+scale)+shift  (into Ya)
  k_lnmod<<<dim3(ROWS), 256, 0, stream>>>(x, Mss, Ya);
  // 6. in_proj: zz | xbc | dtc
  k_gemm<0><<<dim3(35,64), 256, 0, stream>>>(Ya, winT, zz, xbc, dtc, nullptr, ROWS, DPROJ, 1024,
                                             nullptr, nullptr, nullptr, nullptr);
  // 7. conv4 + silu
  k_conv<<<dim3(9,ROWS), 256, 0, stream>>>(xbc, conv_w, conv_b, co);
  // 8. transpose xh+B -> xhT (over xbc), BTg
  k_transT<<<dim3(34,16,8), 256, 0, stream>>>(co, xhT, BTg);
  // 9. per-chunk state contributions (Sc over Mss)
  k_chunkstate<<<dim3(2048), 256, 0, stream>>>(xhT, BTg, dtc, dt_bias, A_log, Sc, Dcb);
  // 10. chunk-state recurrence (in place: Sc -> h_in)
  k_chunkscan<<<dim3(8192), 256, 0, stream>>>(Sc, Dcb);
  // 11. SSD main: intra + inter + D + silu(z) gate -> yv
  k_ssd<<<dim3(2048), 256, 0, stream>>>(co, zz, dtc, xhT, Sc, dt_bias, A_log, D_param, yv);
  // 12. out = gate * (yv @ w_out) + x
  k_gemm<2><<<dim3(8,64), 256, 0, stream>>>(yv, woutT, nullptr, nullptr, nullptr, (float*)d_out,
                                            ROWS, 1024, 2048, nullptr, nullptr, Mg, x);
}

// Round 8
// 525.426 us; speedup vs baseline: 1.1208x; 1.0313x over previous
//
#include <hip/hip_runtime.h>

typedef float f32x4 __attribute__((ext_vector_type(4)));
typedef __bf16 bf16x8 __attribute__((ext_vector_type(8)));
typedef unsigned short ushort;
typedef ushort ushort8 __attribute__((ext_vector_type(8)));
typedef ushort ushort4v __attribute__((ext_vector_type(4)));

#define DM 1024
#define DI 2048
#define DSTATE 128
#define NH 32
#define HD 64
#define CONVDIM 2304
#define DPROJ 4384
#define ROWS 8192

__device__ __forceinline__ float bf2f(ushort u){
  union { unsigned int i; float f; } v; v.i = ((unsigned int)u)<<16; return v.f;
}
__device__ __forceinline__ ushort f2bf(float f){
  union { float f; unsigned int i; } v; v.f = f;
  unsigned int r = v.i + 0x7FFFu + ((v.i>>16)&1u);
  return (ushort)(r>>16);
}
__device__ __forceinline__ float siluf(float x){ return x / (1.f + __expf(-x)); }

__device__ __forceinline__ void gload16(const ushort* g, ushort* l){
  __builtin_amdgcn_global_load_lds(
      (const __attribute__((address_space(1))) void*)g,
      (__attribute__((address_space(3))) void*)l, 16, 0, 0);
}

// ---------------- elementwise: Ya = bf16(silu(y)) ----------------
__global__ __launch_bounds__(256) void k_silu_cast(const float* __restrict__ in,
                                                   ushort* __restrict__ out, int n){
  int i = (blockIdx.x*256 + threadIdx.x)*4;
  if (i >= n) return;
  float4 v = *(const float4*)(in + i);
  ushort4v o;
  o.x = f2bf(siluf(v.x)); o.y = f2bf(siluf(v.y));
  o.z = f2bf(siluf(v.z)); o.w = f2bf(siluf(v.w));
  *(ushort4v*)(out + i) = o;
}

// ---------------- weight transpose+cast: in[K][N] f32 -> out[N][K] bf16 ----------------
__global__ __launch_bounds__(256) void k_transpose_cast(const float* __restrict__ in,
                                                        ushort* __restrict__ out,
                                                        int K, int N){
  __shared__ float tile[32][33];
  int n0 = blockIdx.x*32, k0 = blockIdx.y*32;
  int tx = threadIdx.x & 31, ty = threadIdx.x >> 5; // 32x8
  for (int r = ty; r < 32; r += 8) tile[r][tx] = in[(size_t)(k0+r)*N + n0+tx];
  __syncthreads();
  for (int r = ty; r < 32; r += 8) out[(size_t)(n0+r)*K + k0+tx] = f2bf(tile[tx][r]);
}

// ---------------- at[b][n] = silu(t[b]) @ w_ada + b_ada ----------------
__global__ __launch_bounds__(256) void k_at(const float* __restrict__ t,
                                            const float* __restrict__ w_ada,
                                            const float* __restrict__ b_ada,
                                            float* __restrict__ at){
  __shared__ float st[1024];
  int b = blockIdx.y;
  int col = blockIdx.x*256 + threadIdx.x;
  for (int i = threadIdx.x; i < 1024; i += 256) st[i] = siluf(t[b*1024 + i]);
  __syncthreads();
  float acc = 0.f;
  for (int k = 0; k < 1024; ++k) acc += st[k] * w_ada[(size_t)k*3072 + col];
  at[b*3072 + col] = acc + b_ada[col];
}

// ---------------- GEMM: 128x128 tile, BK=32, 4 waves, TRIPLE-buffer counted-vmcnt ----------------
// + XCD-chunked bijective swizzle composed with GROUP_M=8 supertiling:
//   each XCD gets a contiguous wg range covering 8 bm-stripes x all bn.
// Tile T: compute from buf[T%3]; stage tile T+2 into buf[(T+2)%3]; vmcnt(4)+s_barrier.
#define STG(Q, KT) do{ \
  gload16(pA0 + (size_t)(KT)*32, &sm[(Q)*8192 + (wave*2+0)*512]); \
  gload16(pA1 + (size_t)(KT)*32, &sm[(Q)*8192 + (wave*2+1)*512]); \
  gload16(pB0 + (size_t)(KT)*32, &sm[(Q)*8192 + 4096 + (wave*2+0)*512]); \
  gload16(pB1 + (size_t)(KT)*32, &sm[(Q)*8192 + 4096 + (wave*2+1)*512]); }while(0)

#define CMP(BOFF) do{ \
  bf16x8 af[4], bfr[4]; \
  _Pragma("unroll") \
  for (int m=0;m<4;m++) af[m]  = *(const bf16x8*)&sm[(BOFF) + (wr*64 + m*16 + l16)*32 + kbs]; \
  _Pragma("unroll") \
  for (int n=0;n<4;n++) bfr[n] = *(const bf16x8*)&sm[(BOFF) + 4096 + (wc*64 + n*16 + l16)*32 + kbs]; \
  __builtin_amdgcn_s_setprio(1); \
  _Pragma("unroll") \
  for (int m=0;m<4;m++) \
    _Pragma("unroll") \
    for (int n=0;n<4;n++) \
      acc[m][n] = __builtin_amdgcn_mfma_f32_16x16x32_bf16(af[m], bfr[n], acc[m][n], 0, 0, 0); \
  __builtin_amdgcn_s_setprio(0); }while(0)

#define BODY(Q, T) do{ \
  STG(((Q)+2)%3, (T)+2); \
  CMP((Q)*8192); \
  asm volatile("s_waitcnt vmcnt(4)" ::: "memory"); \
  __builtin_amdgcn_s_barrier(); \
  __builtin_amdgcn_sched_barrier(0); }while(0)

template<int EPI>
__global__ __launch_bounds__(256)
void k_gemm(const ushort* __restrict__ Ag, const ushort* __restrict__ Bt,
            ushort* __restrict__ Cb, ushort* __restrict__ Cb2, ushort* __restrict__ Cb3,
            float* __restrict__ Cf,
            int M, int N, int K, int nbn,
            const float* __restrict__ bias, const float* __restrict__ at,
            const ushort* __restrict__ gateM, const float* __restrict__ xres){
  __shared__ __align__(16) ushort sm[3*8192];   // 3 bufs x (A 8KB + B 8KB) = 48KB
  const int tid  = threadIdx.x;
  const int wave = tid >> 6, lane = tid & 63;
  // XCD-chunked swizzle (nwg % 8 == 0 guaranteed) + GROUP_M=8 supertiling
  const int nwg = gridDim.x, bid0 = blockIdx.x;
  const int wg = (bid0 & 7)*(nwg >> 3) + (bid0 >> 3);
  const int pg = nbn << 3;
  const int g  = wg / pg;
  const int rem = wg - g*pg;
  const int bm = (g << 3) + (rem & 7);
  const int bn = rem >> 3;
  const int wr = wave >> 1, wc = wave & 1;
  const int l16 = lane & 15, kb = lane >> 4;
  const int arow0 = (wave*2+0)*16 + (lane>>2);
  const int arow1 = (wave*2+1)*16 + (lane>>2);
  const int kcs = (lane & 3) ^ ((lane>>3)&3);
  const int kbs = (kb ^ ((l16>>1)&3))*8;

  const ushort* pA0 = Ag + (size_t)(bm*128 + arow0)*K + kcs*8;
  const ushort* pA1 = Ag + (size_t)(bm*128 + arow1)*K + kcs*8;
  int br0 = bn*128 + arow0; if (br0 > N-1) br0 = N-1;
  int br1 = bn*128 + arow1; if (br1 > N-1) br1 = N-1;
  const ushort* pB0 = Bt + (size_t)br0*K + kcs*8;
  const ushort* pB1 = Bt + (size_t)br1*K + kcs*8;

  f32x4 acc[4][4];
#pragma unroll
  for (int m=0;m<4;m++)
#pragma unroll
    for (int n=0;n<4;n++) acc[m][n] = (f32x4){0.f,0.f,0.f,0.f};

  const int NT = K >> 5;
  const int NB = NT - 2;

  // prologue: stage tiles 0,1; wait tile0 landed
  STG(0, 0); STG(1, 1);
  asm volatile("s_waitcnt vmcnt(4)" ::: "memory");
  __builtin_amdgcn_s_barrier();
  __builtin_amdgcn_sched_barrier(0);

  int T = 0;
  for (; T + 3 <= NB; T += 3){
    BODY(0, T); BODY(1, T+1); BODY(2, T+2);
  }
  if (NB - T >= 1) BODY(0, T);
  if (NB - T >= 2) BODY(1, T+1);

  // tail: tiles NB, NB+1 already staged
  {
    const int qa = NB % 3, qb = (NB + 1) % 3;
    CMP(qa*8192);
    asm volatile("s_waitcnt vmcnt(0)" ::: "memory");
    __builtin_amdgcn_s_barrier();
    __builtin_amdgcn_sched_barrier(0);
    CMP(qb*8192);
  }

#pragma unroll
  for (int m=0;m<4;m++){
    int grow_base = bm*128 + wr*64 + m*16 + (lane>>4)*4;
#pragma unroll
    for (int n=0;n<4;n++){
      int gcol = bn*128 + wc*64 + n*16 + l16;
      if (EPI == 0){
        if (gcol < N){
#pragma unroll
          for (int r=0;r<4;r++){
            int row = grow_base + r;
            float v = acc[m][n][r];
            if (gcol < 2048)      Cb [(size_t)row*2048 + gcol] = f2bf(v);
            else if (gcol < 4352) Cb2[(size_t)row*2304 + (gcol-2048)] = f2bf(v);
            else                  Cb3[(size_t)row*32   + (gcol-4352)] = f2bf(v);
          }
        }
      } else if (EPI == 1){
        float bv = bias[gcol];
#pragma unroll
        for (int r=0;r<4;r++){
          int row = grow_base + r;
          float v = acc[m][n][r] + bv + at[(row>>10)*3072 + gcol];
          if (gcol < 2048) Cb [(size_t)row*2048 + gcol] = f2bf(v);
          else             Cb2[(size_t)row*1024 + (gcol - 2048)] = f2bf(v);
        }
      } else {
#pragma unroll
        for (int r=0;r<4;r++){
          int row = grow_base + r;
          float g2 = bf2f(gateM[(size_t)row*1024 + gcol]);
          Cf[(size_t)row*1024 + gcol] = g2*acc[m][n][r] + xres[(size_t)row*1024 + gcol];
        }
      }
    }
  }
}

// ---------------- LN + modulation: mod = LN(x)*(1+scale)+shift (bf16) ----------------
__global__ __launch_bounds__(256) void k_lnmod(const float* __restrict__ x,
                                               const ushort* __restrict__ Mss,
                                               ushort* __restrict__ mod){
  int row = blockIdx.x;
  const float* xr = x + (size_t)row*1024;
  float v[4]; float s = 0.f, s2 = 0.f;
#pragma unroll
  for (int j=0;j<4;j++){ v[j] = xr[threadIdx.x + j*256]; s += v[j]; s2 += v[j]*v[j]; }
#pragma unroll
  for (int o=32;o>0;o>>=1){ s += __shfl_down(s,o); s2 += __shfl_down(s2,o); }
  __shared__ float ls[4], ls2[4];
  int wv = threadIdx.x >> 6;
  if ((threadIdx.x & 63) == 0){ ls[wv] = s; ls2[wv] = s2; }
  __syncthreads();
  s  = ls[0]+ls[1]+ls[2]+ls[3];
  s2 = ls2[0]+ls2[1]+ls2[2]+ls2[3];
  float mu = s * (1.f/1024.f);
  float var = s2 * (1.f/1024.f) - mu*mu;
  float rstd = rsqrtf(var + 1e-6f);
  const ushort* Mr = Mss + (size_t)row*2048;
#pragma unroll
  for (int j=0;j<4;j++){
    int d = threadIdx.x + j*256;
    float sc = bf2f(Mr[1024 + d]);
    float sh = bf2f(Mr[d]);
    mod[(size_t)row*1024 + d] = f2bf((v[j]-mu)*rstd*(1.f+sc) + sh);
  }
}

// ---------------- causal conv4 + silu over xbc ----------------
__global__ __launch_bounds__(256) void k_conv(const ushort* __restrict__ xbc,
                                              const float* __restrict__ conv_w,
                                              const float* __restrict__ conv_b,
                                              ushort* __restrict__ co){
  int ch  = blockIdx.x*256 + threadIdx.x;   // < 2304
  int row = blockIdx.y;                      // < 8192
  int l = row & 1023, b = row >> 10;
  float acc = conv_b[ch];
#pragma unroll
  for (int k=0;k<4;k++){
    int ll = l - 3 + k;
    if (ll >= 0) acc += conv_w[ch*4 + k] * bf2f(xbc[(size_t)(b*1024 + ll)*CONVDIM + ch]);
  }
  co[(size_t)row*CONVDIM + ch] = f2bf(siluf(acc));
}

// ---------------- transpose co cols [0,2176) -> xhT [b*2048+c][l], BTg [b*128+n][l] ----------------
__global__ __launch_bounds__(256) void k_transT(const ushort* __restrict__ co,
                                                ushort* __restrict__ xhT,
                                                ushort* __restrict__ BTg){
  __shared__ ushort tile[64*72];
  const int c0 = blockIdx.x*64, l0 = blockIdx.y*64, b = blockIdx.z;
  const int tid = threadIdx.x;
  for (int q = tid; q < 512; q += 256){
    int r = q >> 3, cc = q & 7;
    ushort8 v = *(const ushort8*)(co + (size_t)(b*1024 + l0 + r)*CONVDIM + c0 + cc*8);
    *(ushort8*)&tile[r*72 + cc*8] = v;
  }
  __syncthreads();
  for (int q = tid; q < 1024; q += 256){
    int oc = q >> 4, lc = (q & 15)*4;
    ushort4v o;
#pragma unroll
    for (int j = 0; j < 4; ++j) o[j] = tile[(lc + j)*72 + oc];
    int ccol = c0 + oc;
    ushort* out = (ccol < 2048) ? (xhT + (size_t)(b*2048 + ccol)*1024)
                                : (BTg + (size_t)(b*128 + (ccol - 2048))*1024);
    *(ushort4v*)(out + l0 + lc) = o;
  }
}

// ---------------- chunk state contribution: Sc[p][n] = sum_s G[s]*x[s,p]*B[s,n] ----------------
__global__ __launch_bounds__(256) void k_chunkstate(
    const ushort* __restrict__ xhT, const ushort* __restrict__ BTg,
    const ushort* __restrict__ dtc,
    const float* __restrict__ dt_bias, const float* __restrict__ A_log,
    ushort* __restrict__ Sc, float* __restrict__ Dcb){
  __shared__ __align__(16) ushort sXG[64*128];   // 16KB (swizzled)
  __shared__ __align__(16) ushort sBT[128*128];  // 32KB (swizzled)
  __shared__ float sG[128];
  const int bid = blockIdx.x;
  const int h = bid & 31, bc = bid >> 5, b = bc >> 3, c = bc & 7;
  const int tid = threadIdx.x, wave = tid >> 6, lane = tid & 63;
  const int l16 = lane & 15, l4 = lane >> 4;
  const int sci = (b*32 + h)*8 + c;
  {
    const ushort* src = BTg + (size_t)(b*128)*1024 + c*128;
    for (int i2 = 0; i2 < 8; ++i2){
      int itg = wave*8 + i2;
      int r = itg*4 + l4;
      int cc = l16 ^ (r & 7);
      gload16(src + (size_t)r*1024 + cc*8, &sBT[itg*512]);
    }
  }
  const float Ah = -__expf(A_log[h]);
  if (wave == 0){
    const int row0 = b*1024 + c*128;
    float bi = dt_bias[h];
    float d0 = bf2f(dtc[(size_t)(row0 + 2*lane    )*32 + h]) + bi;
    float d1 = bf2f(dtc[(size_t)(row0 + 2*lane + 1)*32 + h]) + bi;
    d0 = (d0 > 20.f) ? d0 : log1pf(__expf(d0));
    d1 = (d1 > 20.f) ? d1 : log1pf(__expf(d1));
    float p = d0 + d1;
#pragma unroll
    for (int o = 1; o < 64; o <<= 1){
      float tp = __shfl_up(p, o);
      if (lane >= o) p += tp;
    }
    float cs127 = __shfl(p, 63);
    sG[2*lane    ] = __expf(Ah*(cs127 - (p - d1))) * d0;
    sG[2*lane + 1] = __expf(Ah*(cs127 - p)) * d1;
    if (lane == 0) Dcb[sci] = __expf(Ah*cs127);
  }
  __syncthreads();
  {
    const ushort* xsrc = xhT + (size_t)(b*2048 + h*64)*1024 + c*128;
    for (int q = tid; q < 1024; q += 256){
      int r = q >> 4, cc = q & 15;
      ushort8 v = *(const ushort8*)(xsrc + (size_t)r*1024 + cc*8);
      ushort8 o;
#pragma unroll
      for (int j = 0; j < 8; ++j) o[j] = f2bf(bf2f(v[j]) * sG[cc*8 + j]);
      *(ushort8*)&sXG[r*128 + ((cc ^ (r & 7))*8)] = o;
    }
  }
  __syncthreads();
  f32x4 acc[4][2];
#pragma unroll
  for (int m=0;m<4;m++)
#pragma unroll
    for (int nf=0;nf<2;nf++) acc[m][nf] = (f32x4){0.f,0.f,0.f,0.f};
  for (int ks = 0; ks < 4; ++ks){
    bf16x8 av[4], bv[2];
#pragma unroll
    for (int m = 0; m < 4; ++m){
      int rp = m*16 + l16;
      av[m] = *(const bf16x8*)&sXG[rp*128 + (((ks*4 + l4) ^ (rp & 7))*8)];
    }
#pragma unroll
    for (int nf = 0; nf < 2; ++nf){
      int rn = wave*32 + nf*16 + l16;
      bv[nf] = *(const bf16x8*)&sBT[rn*128 + (((ks*4 + l4) ^ (rn & 7))*8)];
    }
#pragma unroll
    for (int m = 0; m < 4; ++m)
#pragma unroll
      for (int nf = 0; nf < 2; ++nf)
        acc[m][nf] = __builtin_amdgcn_mfma_f32_16x16x32_bf16(av[m], bv[nf], acc[m][nf], 0, 0, 0);
  }
  const size_t base = (size_t)sci * 8192;
#pragma unroll
  for (int m = 0; m < 4; ++m)
#pragma unroll
    for (int nf = 0; nf < 2; ++nf)
#pragma unroll
      for (int r = 0; r < 4; ++r){
        int p = m*16 + l4*4 + r;
        int n = wave*32 + nf*16 + l16;
        Sc[base + p*128 + n] = f2bf(acc[m][nf][r]);
      }
}

// ---------------- chunk recurrence: h <- h*Dc + Sc ; writes h_in over Sc in place ----------------
__global__ __launch_bounds__(256) void k_chunkscan(ushort* __restrict__ Sc,
                                                   const float* __restrict__ Dcb){
  size_t idx = (size_t)blockIdx.x*256 + threadIdx.x;   // 2,097,152 total
  int bh = (int)(idx >> 13);
  int pn = (int)(idx & 8191);
  float hv = 0.f;
  for (int c = 0; c < 8; ++c){
    size_t o = (size_t)(bh*8 + c)*8192 + pn;
    float s = bf2f(Sc[o]);
    float dc = Dcb[bh*8 + c];
    Sc[o] = f2bf(hv);
    hv = hv*dc + s;
  }
}

// ---------------- main SSD chunk kernel: y = (mask.(C@B^T))@X + decay*(C@h^T), gated ----------------
__global__ __launch_bounds__(256) void k_ssd(
    const ushort* __restrict__ co, const ushort* __restrict__ zz,
    const ushort* __restrict__ dtc, const ushort* __restrict__ xhT,
    const ushort* __restrict__ Hin,
    const float* __restrict__ dt_bias, const float* __restrict__ A_log,
    const float* __restrict__ D_param,
    ushort* __restrict__ yv){
  __shared__ __align__(16) ushort sC [128*128];  // 32KB C tile (swizzled)
  __shared__ __align__(16) ushort sBP[128*128];  // 32KB B tile, then P (swizzled)
  __shared__ __align__(16) ushort sXT[64*128];   // 16KB x^T tile (swizzled)
  __shared__ __align__(16) ushort sH [64*128];   // 16KB h_in (swizzled)
  __shared__ float csv[128], dtv[128];
  const int bid = blockIdx.x;
  const int h = bid & 31, bc = bid >> 5, b = bc >> 3, c = bc & 7;
  const int tid = threadIdx.x, wave = tid >> 6, lane = tid & 63;
  const int l16 = lane & 15, l4 = lane >> 4;
  const int row0 = b*1024 + c*128;
  const ushort* cbase = co + (size_t)row0*CONVDIM;
  for (int i2 = 0; i2 < 8; ++i2){
    int itg = wave*8 + i2;
    int r = itg*4 + l4;
    int cc = l16 ^ (r & 7);
    gload16(cbase + (size_t)r*CONVDIM + 2176 + cc*8, &sC [itg*512]);
    gload16(cbase + (size_t)r*CONVDIM + 2048 + cc*8, &sBP[itg*512]);
  }
  {
    const ushort* xsrc = xhT + (size_t)(b*2048 + h*64)*1024 + c*128;
    const size_t hbase = (size_t)((b*32 + h)*8 + c)*8192;
    for (int i2 = 0; i2 < 4; ++i2){
      int itg = wave*4 + i2;
      int r = itg*4 + l4;
      int cc = l16 ^ (r & 7);
      gload16(xsrc + (size_t)r*1024 + cc*8, &sXT[itg*512]);
      gload16(Hin + hbase + r*128 + cc*8, &sH[itg*512]);
    }
  }
  const float Ah = -__expf(A_log[h]);
  if (wave == 0){
    float bi = dt_bias[h];
    float d0 = bf2f(dtc[(size_t)(row0 + 2*lane    )*32 + h]) + bi;
    float d1 = bf2f(dtc[(size_t)(row0 + 2*lane + 1)*32 + h]) + bi;
    d0 = (d0 > 20.f) ? d0 : log1pf(__expf(d0));
    d1 = (d1 > 20.f) ? d1 : log1pf(__expf(d1));
    float p = d0 + d1;
#pragma unroll
    for (int o = 1; o < 64; o <<= 1){
      float tp = __shfl_up(p, o);
      if (lane >= o) p += tp;
    }
    csv[2*lane    ] = p - d1;
    csv[2*lane + 1] = p;
    dtv[2*lane    ] = d0;
    dtv[2*lane + 1] = d1;
  }
  __syncthreads();
  const int wr = wave >> 1, wc = wave & 1;
  // GEMM1: S[i][s] = C[i].B[s]
  f32x4 acc[4][4];
#pragma unroll
  for (int m=0;m<4;m++)
#pragma unroll
    for (int n=0;n<4;n++) acc[m][n] = (f32x4){0.f,0.f,0.f,0.f};
  for (int ks = 0; ks < 4; ++ks){
    bf16x8 av[4], bv[4];
#pragma unroll
    for (int m = 0; m < 4; ++m){
      int ri = wr*64 + m*16 + l16;
      av[m] = *(const bf16x8*)&sC[ri*128 + (((ks*4 + l4) ^ (ri & 7))*8)];
    }
#pragma unroll
    for (int n = 0; n < 4; ++n){
      int rs = wc*64 + n*16 + l16;
      bv[n] = *(const bf16x8*)&sBP[rs*128 + (((ks*4 + l4) ^ (rs & 7))*8)];
    }
#pragma unroll
    for (int m = 0; m < 4; ++m)
#pragma unroll
      for (int n = 0; n < 4; ++n)
        acc[m][n] = __builtin_amdgcn_mfma_f32_16x16x32_bf16(av[m], bv[n], acc[m][n], 0, 0, 0);
  }
  __syncthreads();
  // mask + dt + D-diagonal -> P (bf16, over B tile)
  const float Dp = D_param[h];
#pragma unroll
  for (int m = 0; m < 4; ++m){
#pragma unroll
    for (int r = 0; r < 4; ++r){
      int i = wr*64 + m*16 + l4*4 + r;
      float ci = csv[i];
#pragma unroll
      for (int n = 0; n < 4; ++n){
        int s = wc*64 + n*16 + l16;
        float e = __expf(Ah*(ci - csv[s]));
        float v = (i >= s) ? acc[m][n][r]*e*dtv[s] : 0.f;
        if (i == s) v += Dp;
        sBP[i*128 + (s ^ ((i & 7)<<3))] = f2bf(v);
      }
    }
  }
  __syncthreads();
  // GEMM2: Y[i][p] = P@X^T + Ei*(C@h^T)
  f32x4 accY[4][2], accI[4][2];
#pragma unroll
  for (int m=0;m<4;m++)
#pragma unroll
    for (int n=0;n<2;n++){ accY[m][n] = (f32x4){0.f,0.f,0.f,0.f}; accI[m][n] = (f32x4){0.f,0.f,0.f,0.f}; }
  for (int ks = 0; ks < 4; ++ks){
    bf16x8 pa[4], ca[4], xb[2], hb[2];
#pragma unroll
    for (int m = 0; m < 4; ++m){
      int ri = wr*64 + m*16 + l16;
      int off = ((ks*4 + l4) ^ (ri & 7))*8;
      pa[m] = *(const bf16x8*)&sBP[ri*128 + off];
      ca[m] = *(const bf16x8*)&sC [ri*128 + off];
    }
#pragma unroll
    for (int n = 0; n < 2; ++n){
      int rp = wc*32 + n*16 + l16;
      int off = ((ks*4 + l4) ^ (rp & 7))*8;
      xb[n] = *(const bf16x8*)&sXT[rp*128 + off];
      hb[n] = *(const bf16x8*)&sH [rp*128 + off];
    }
#pragma unroll
    for (int m = 0; m < 4; ++m)
#pragma unroll
      for (int n = 0; n < 2; ++n){
        accY[m][n] = __builtin_amdgcn_mfma_f32_16x16x32_bf16(pa[m], xb[n], accY[m][n], 0, 0, 0);
        accI[m][n] = __builtin_amdgcn_mfma_f32_16x16x32_bf16(ca[m], hb[n], accI[m][n], 0, 0, 0);
      }
  }
#pragma unroll
  for (int m = 0; m < 4; ++m){
#pragma unroll
    for (int r = 0; r < 4; ++r){
      int i = wr*64 + m*16 + l4*4 + r;
      float Ei = __expf(Ah*csv[i]);
      int grow = row0 + i;
#pragma unroll
      for (int n = 0; n < 2; ++n){
        int p = wc*32 + n*16 + l16;
        float yvl = accY[m][n][r] + Ei*accI[m][n][r];
        float z = bf2f(zz[(size_t)grow*2048 + h*64 + p]);
        yv[(size_t)grow*DI + h*64 + p] = f2bf(yvl * siluf(z));
      }
    }
  }
}

extern "C" void kernel_launch(void* const* d_in, const int* in_sizes, int n_in,
                              void* d_out, int out_size, void* d_ws, size_t ws_size,
                              hipStream_t stream){
  const float* x       = (const float*)d_in[0];
  const float* t       = (const float*)d_in[1];
  const float* y       = (const float*)d_in[2];
  const float* w_ada   = (const float*)d_in[3];
  const float* b_ada   = (const float*)d_in[4];
  const float* w_in    = (const float*)d_in[5];
  const float* conv_w  = (const float*)d_in[6];
  const float* conv_b  = (const float*)d_in[7];
  const float* dt_bias = (const float*)d_in[8];
  const float* A_log   = (const float*)d_in[9];
  const float* D_param = (const float*)d_in[10];
  const float* w_out   = (const float*)d_in[11];

  char* w = (char*)d_ws;
  size_t off = 0;
  auto alloc = [&](size_t bytes)->char*{
    char* p = w + off; off += (bytes + 255) & ~(size_t)255; return p;
  };
  ushort* zz    = (ushort*)alloc((size_t)ROWS*2048*2);   // z part of in_proj
  ushort* xbc   = (ushort*)alloc((size_t)ROWS*CONVDIM*2);// conv input; xhT alias (33.6<=37.7MB)
  ushort* dtc   = (ushort*)alloc((size_t)ROWS*32*2);     // dt logits
  ushort* co    = (ushort*)alloc((size_t)ROWS*CONVDIM*2);
  ushort* Mss   = (ushort*)alloc((size_t)ROWS*2048*2);   // shift|scale -> Sc alias
  ushort* Mg    = (ushort*)alloc((size_t)ROWS*1024*2);   // gate
  ushort* yv    = (ushort*)alloc((size_t)ROWS*DI*2);
  ushort* woutT = (ushort*)alloc(1024ull*2048*2);
  ushort* waT   = (ushort*)alloc(3072ull*1024*2);
  ushort* winT  = (ushort*)alloc(4608ull*1024*2);
  float*  atb   = (float*) alloc(8ull*3072*4);
  ushort* Ya    = (ushort*)alloc((size_t)ROWS*1024*2);   // silu(y) -> mod
  ushort* BTg   = (ushort*)alloc((size_t)8*128*1024*2);
  float*  Dcb   = (float*) alloc(2048ull*4);
  ushort* xhT   = xbc;   // alias: xbc dead after k_conv; xhT needs 33.6MB <= 37.7MB
  ushort* Sc    = Mss;   // alias: Mss dead after k_lnmod; same size (33.6MB)

  // 1. Ya = bf16(silu(y))
  k_silu_cast<<<dim3(ROWS*1024/(256*4)), 256, 0, stream>>>(y, Ya, ROWS*1024);
  // 2. weight transposes (f32 -> bf16 [N][K])
  k_transpose_cast<<<dim3(96,32),  256, 0, stream>>>(w_ada, waT,  1024, 3072);
  k_transpose_cast<<<dim3(137,32), 256, 0, stream>>>(w_in,  winT, 1024, 4384);
  k_transpose_cast<<<dim3(32,64),  256, 0, stream>>>(w_out, woutT, 2048, 1024);
  // 3. at = silu(t)@w_ada + b_ada  (f32)
  k_at<<<dim3(12,8), 256, 0, stream>>>(t, w_ada, b_ada, atb);
  // 4. [shift|scale] -> Mss, gate -> Mg   (1D grid 64*24=1536, %8==0)
  k_gemm<1><<<dim3(1536), 256, 0, stream>>>(Ya, waT, Mss, Mg, nullptr, nullptr, ROWS, 3072, 1024, 24,
                                            b_ada, atb, nullptr, nullptr);
  // 5. mod = LN(x)*(1+scale)+shift  (into Ya)
  k_lnmod<<<dim3(ROWS), 256, 0, stream>>>(x, Mss, Ya);
  // 6. in_proj: zz | xbc | dtc   (1D grid 64*35=2240, %8==0)
  k_gemm<0><<<dim3(2240), 256, 0, stream>>>(Ya, winT, zz, xbc, dtc, nullptr, ROWS, DPROJ, 1024, 35,
                                            nullptr, nullptr, nullptr, nullptr);
  // 7. conv4 + silu
  k_conv<<<dim3(9,ROWS), 256, 0, stream>>>(xbc, conv_w, conv_b, co);
  // 8. transpose xh+B -> xhT (over xbc), BTg
  k_transT<<<dim3(34,16,8), 256, 0, stream>>>(co, xhT, BTg);
  // 9. per-chunk state contributions (Sc over Mss)
  k_chunkstate<<<dim3(2048), 256, 0, stream>>>(xhT, BTg, dtc, dt_bias, A_log, Sc, Dcb);
  // 10. chunk-state recurrence (in place: Sc -> h_in)
  k_chunkscan<<<dim3(8192), 256, 0, stream>>>(Sc, Dcb);
  // 11. SSD main: intra + inter + D + silu(z) gate -> yv
  k_ssd<<<dim3(2048), 256, 0, stream>>>(co, zz, dtc, xhT, Sc, dt_bias, A_log, D_param, yv);
  // 12. out = gate * (yv @ w_out) + x   (1D grid 64*8=512, %8==0)
  k_gemm<2><<<dim3(512), 256, 0, stream>>>(yv, woutT, nullptr, nullptr, nullptr, (float*)d_out,
                                           ROWS, 1024, 2048, 8, nullptr, nullptr, Mg, x);
}

// Round 9
// 486.920 us; speedup vs baseline: 1.2095x; 1.0791x over previous
//
#include <hip/hip_runtime.h>

typedef float f32x4 __attribute__((ext_vector_type(4)));
typedef __bf16 bf16x8 __attribute__((ext_vector_type(8)));
typedef unsigned short ushort;
typedef ushort ushort8 __attribute__((ext_vector_type(8)));
typedef ushort ushort4v __attribute__((ext_vector_type(4)));

#define DM 1024
#define DI 2048
#define DSTATE 128
#define NH 32
#define HD 64
#define CONVDIM 2304
#define DPROJ 4384
#define ROWS 8192

__device__ __forceinline__ float bf2f(ushort u){
  union { unsigned int i; float f; } v; v.i = ((unsigned int)u)<<16; return v.f;
}
__device__ __forceinline__ ushort f2bf(float f){
  union { float f; unsigned int i; } v; v.f = f;
  unsigned int r = v.i + 0x7FFFu + ((v.i>>16)&1u);
  return (ushort)(r>>16);
}
__device__ __forceinline__ float siluf(float x){ return x / (1.f + __expf(-x)); }

__device__ __forceinline__ void gload16(const ushort* g, ushort* l){
  __builtin_amdgcn_global_load_lds(
      (const __attribute__((address_space(1))) void*)g,
      (__attribute__((address_space(3))) void*)l, 16, 0, 0);
}

// ---------------- elementwise: Ya = bf16(silu(y)) ----------------
__global__ __launch_bounds__(256) void k_silu_cast(const float* __restrict__ in,
                                                   ushort* __restrict__ out, int n){
  int i = (blockIdx.x*256 + threadIdx.x)*4;
  if (i >= n) return;
  float4 v = *(const float4*)(in + i);
  ushort4v o;
  o.x = f2bf(siluf(v.x)); o.y = f2bf(siluf(v.y));
  o.z = f2bf(siluf(v.z)); o.w = f2bf(siluf(v.w));
  *(ushort4v*)(out + i) = o;
}

// ---------------- weight transpose+cast: in[K][N] f32 -> out[N][K] bf16 ----------------
__global__ __launch_bounds__(256) void k_transpose_cast(const float* __restrict__ in,
                                                        ushort* __restrict__ out,
                                                        int K, int N){
  __shared__ float tile[32][33];
  int n0 = blockIdx.x*32, k0 = blockIdx.y*32;
  int tx = threadIdx.x & 31, ty = threadIdx.x >> 5; // 32x8
  for (int r = ty; r < 32; r += 8) tile[r][tx] = in[(size_t)(k0+r)*N + n0+tx];
  __syncthreads();
  for (int r = ty; r < 32; r += 8) out[(size_t)(n0+r)*K + k0+tx] = f2bf(tile[tx][r]);
}

// ---------------- at[b][n] = silu(t[b]) @ w_ada + b_ada ----------------
__global__ __launch_bounds__(256) void k_at(const float* __restrict__ t,
                                            const float* __restrict__ w_ada,
                                            const float* __restrict__ b_ada,
                                            float* __restrict__ at){
  __shared__ float st[1024];
  int b = blockIdx.y;
  int col = blockIdx.x*256 + threadIdx.x;
  for (int i = threadIdx.x; i < 1024; i += 256) st[i] = siluf(t[b*1024 + i]);
  __syncthreads();
  float acc = 0.f;
  for (int k = 0; k < 1024; ++k) acc += st[k] * w_ada[(size_t)k*3072 + col];
  at[b*3072 + col] = acc + b_ada[col];
}

// ---------------- GEMM: 128x128 tile, BK=32, 4 waves, TRIPLE-buffer counted-vmcnt ----------------
// + XCD-chunked bijective swizzle composed with GROUP_M=8 supertiling.
// Tile T: compute from buf[T%3]; stage tile T+2 into buf[(T+2)%3]; vmcnt(4)+s_barrier.
#define STG(Q, KT) do{ \
  gload16(pA0 + (size_t)(KT)*32, &sm[(Q)*8192 + (wave*2+0)*512]); \
  gload16(pA1 + (size_t)(KT)*32, &sm[(Q)*8192 + (wave*2+1)*512]); \
  gload16(pB0 + (size_t)(KT)*32, &sm[(Q)*8192 + 4096 + (wave*2+0)*512]); \
  gload16(pB1 + (size_t)(KT)*32, &sm[(Q)*8192 + 4096 + (wave*2+1)*512]); }while(0)

#define CMP(BOFF) do{ \
  bf16x8 af[4], bfr[4]; \
  _Pragma("unroll") \
  for (int m=0;m<4;m++) af[m]  = *(const bf16x8*)&sm[(BOFF) + (wr*64 + m*16 + l16)*32 + kbs]; \
  _Pragma("unroll") \
  for (int n=0;n<4;n++) bfr[n] = *(const bf16x8*)&sm[(BOFF) + 4096 + (wc*64 + n*16 + l16)*32 + kbs]; \
  __builtin_amdgcn_s_setprio(1); \
  _Pragma("unroll") \
  for (int m=0;m<4;m++) \
    _Pragma("unroll") \
    for (int n=0;n<4;n++) \
      acc[m][n] = __builtin_amdgcn_mfma_f32_16x16x32_bf16(af[m], bfr[n], acc[m][n], 0, 0, 0); \
  __builtin_amdgcn_s_setprio(0); }while(0)

#define BODY(Q, T) do{ \
  STG(((Q)+2)%3, (T)+2); \
  CMP((Q)*8192); \
  asm volatile("s_waitcnt vmcnt(4)" ::: "memory"); \
  __builtin_amdgcn_s_barrier(); \
  __builtin_amdgcn_sched_barrier(0); }while(0)

template<int EPI>
__global__ __launch_bounds__(256)
void k_gemm(const ushort* __restrict__ Ag, const ushort* __restrict__ Bt,
            ushort* __restrict__ Cb, ushort* __restrict__ Cb2, ushort* __restrict__ Cb3,
            float* __restrict__ Cf,
            int M, int N, int K, int nbn,
            const float* __restrict__ bias, const float* __restrict__ at,
            const ushort* __restrict__ gateM, const float* __restrict__ xres){
  __shared__ __align__(16) ushort sm[3*8192];   // 3 bufs x (A 8KB + B 8KB) = 48KB
  const int tid  = threadIdx.x;
  const int wave = tid >> 6, lane = tid & 63;
  // XCD-chunked swizzle (nwg % 8 == 0 guaranteed) + GROUP_M=8 supertiling
  const int nwg = gridDim.x, bid0 = blockIdx.x;
  const int wg = (bid0 & 7)*(nwg >> 3) + (bid0 >> 3);
  const int pg = nbn << 3;
  const int g  = wg / pg;
  const int rem = wg - g*pg;
  const int bm = (g << 3) + (rem & 7);
  const int bn = rem >> 3;
  const int wr = wave >> 1, wc = wave & 1;
  const int l16 = lane & 15, kb = lane >> 4;
  const int arow0 = (wave*2+0)*16 + (lane>>2);
  const int arow1 = (wave*2+1)*16 + (lane>>2);
  const int kcs = (lane & 3) ^ ((lane>>3)&3);
  const int kbs = (kb ^ ((l16>>1)&3))*8;

  const ushort* pA0 = Ag + (size_t)(bm*128 + arow0)*K + kcs*8;
  const ushort* pA1 = Ag + (size_t)(bm*128 + arow1)*K + kcs*8;
  int br0 = bn*128 + arow0; if (br0 > N-1) br0 = N-1;
  int br1 = bn*128 + arow1; if (br1 > N-1) br1 = N-1;
  const ushort* pB0 = Bt + (size_t)br0*K + kcs*8;
  const ushort* pB1 = Bt + (size_t)br1*K + kcs*8;

  f32x4 acc[4][4];
#pragma unroll
  for (int m=0;m<4;m++)
#pragma unroll
    for (int n=0;n<4;n++) acc[m][n] = (f32x4){0.f,0.f,0.f,0.f};

  const int NT = K >> 5;
  const int NB = NT - 2;

  // prologue: stage tiles 0,1; wait tile0 landed
  STG(0, 0); STG(1, 1);
  asm volatile("s_waitcnt vmcnt(4)" ::: "memory");
  __builtin_amdgcn_s_barrier();
  __builtin_amdgcn_sched_barrier(0);

  int T = 0;
  for (; T + 3 <= NB; T += 3){
    BODY(0, T); BODY(1, T+1); BODY(2, T+2);
  }
  if (NB - T >= 1) BODY(0, T);
  if (NB - T >= 2) BODY(1, T+1);

  // tail: tiles NB, NB+1 already staged
  {
    const int qa = NB % 3, qb = (NB + 1) % 3;
    CMP(qa*8192);
    asm volatile("s_waitcnt vmcnt(0)" ::: "memory");
    __builtin_amdgcn_s_barrier();
    __builtin_amdgcn_sched_barrier(0);
    CMP(qb*8192);
  }

#pragma unroll
  for (int m=0;m<4;m++){
    int grow_base = bm*128 + wr*64 + m*16 + (lane>>4)*4;
#pragma unroll
    for (int n=0;n<4;n++){
      int gcol = bn*128 + wc*64 + n*16 + l16;
      if (EPI == 0){
        if (gcol < N){
#pragma unroll
          for (int r=0;r<4;r++){
            int row = grow_base + r;
            float v = acc[m][n][r];
            if (gcol < 2048)      Cb [(size_t)row*2048 + gcol] = f2bf(v);
            else if (gcol < 4352) Cb2[(size_t)row*2304 + (gcol-2048)] = f2bf(v);
            else                  Cb3[(size_t)row*32   + (gcol-4352)] = f2bf(v);
          }
        }
      } else if (EPI == 1){
        float bv = bias[gcol];
#pragma unroll
        for (int r=0;r<4;r++){
          int row = grow_base + r;
          float v = acc[m][n][r] + bv + at[(row>>10)*3072 + gcol];
          if (gcol < 2048) Cb [(size_t)row*2048 + gcol] = f2bf(v);
          else             Cb2[(size_t)row*1024 + (gcol - 2048)] = f2bf(v);
        }
      } else {
#pragma unroll
        for (int r=0;r<4;r++){
          int row = grow_base + r;
          float g2 = bf2f(gateM[(size_t)row*1024 + gcol]);
          Cf[(size_t)row*1024 + gcol] = g2*acc[m][n][r] + xres[(size_t)row*1024 + gcol];
        }
      }
    }
  }
}

// ---------------- LN + modulation: mod = LN(x)*(1+scale)+shift (bf16) ----------------
__global__ __launch_bounds__(256) void k_lnmod(const float* __restrict__ x,
                                               const ushort* __restrict__ Mss,
                                               ushort* __restrict__ mod){
  int row = blockIdx.x;
  const float* xr = x + (size_t)row*1024;
  float v[4]; float s = 0.f, s2 = 0.f;
#pragma unroll
  for (int j=0;j<4;j++){ v[j] = xr[threadIdx.x + j*256]; s += v[j]; s2 += v[j]*v[j]; }
#pragma unroll
  for (int o=32;o>0;o>>=1){ s += __shfl_down(s,o); s2 += __shfl_down(s2,o); }
  __shared__ float ls[4], ls2[4];
  int wv = threadIdx.x >> 6;
  if ((threadIdx.x & 63) == 0){ ls[wv] = s; ls2[wv] = s2; }
  __syncthreads();
  s  = ls[0]+ls[1]+ls[2]+ls[3];
  s2 = ls2[0]+ls2[1]+ls2[2]+ls2[3];
  float mu = s * (1.f/1024.f);
  float var = s2 * (1.f/1024.f) - mu*mu;
  float rstd = rsqrtf(var + 1e-6f);
  const ushort* Mr = Mss + (size_t)row*2048;
#pragma unroll
  for (int j=0;j<4;j++){
    int d = threadIdx.x + j*256;
    float sc = bf2f(Mr[1024 + d]);
    float sh = bf2f(Mr[d]);
    mod[(size_t)row*1024 + d] = f2bf((v[j]-mu)*rstd*(1.f+sc) + sh);
  }
}

// ---------------- causal conv4 + silu over xbc ----------------
__global__ __launch_bounds__(256) void k_conv(const ushort* __restrict__ xbc,
                                              const float* __restrict__ conv_w,
                                              const float* __restrict__ conv_b,
                                              ushort* __restrict__ co){
  int ch  = blockIdx.x*256 + threadIdx.x;   // < 2304
  int row = blockIdx.y;                      // < 8192
  int l = row & 1023, b = row >> 10;
  float acc = conv_b[ch];
#pragma unroll
  for (int k=0;k<4;k++){
    int ll = l - 3 + k;
    if (ll >= 0) acc += conv_w[ch*4 + k] * bf2f(xbc[(size_t)(b*1024 + ll)*CONVDIM + ch]);
  }
  co[(size_t)row*CONVDIM + ch] = f2bf(siluf(acc));
}

// ---------------- transpose co cols [0,2176) -> xhT [b*2048+c][l], BTg [b*128+n][l] ----------------
__global__ __launch_bounds__(256) void k_transT(const ushort* __restrict__ co,
                                                ushort* __restrict__ xhT,
                                                ushort* __restrict__ BTg){
  __shared__ ushort tile[64*72];
  const int c0 = blockIdx.x*64, l0 = blockIdx.y*64, b = blockIdx.z;
  const int tid = threadIdx.x;
  for (int q = tid; q < 512; q += 256){
    int r = q >> 3, cc = q & 7;
    ushort8 v = *(const ushort8*)(co + (size_t)(b*1024 + l0 + r)*CONVDIM + c0 + cc*8);
    *(ushort8*)&tile[r*72 + cc*8] = v;
  }
  __syncthreads();
  for (int q = tid; q < 1024; q += 256){
    int oc = q >> 4, lc = (q & 15)*4;
    ushort4v o;
#pragma unroll
    for (int j = 0; j < 4; ++j) o[j] = tile[(lc + j)*72 + oc];
    int ccol = c0 + oc;
    ushort* out = (ccol < 2048) ? (xhT + (size_t)(b*2048 + ccol)*1024)
                                : (BTg + (size_t)(b*128 + (ccol - 2048))*1024);
    *(ushort4v*)(out + l0 + lc) = o;
  }
}

// ---------------- chunk state contribution: Sc[p][n] = sum_s G[s]*x[s,p]*B[s,n] ----------------
__global__ __launch_bounds__(256) void k_chunkstate(
    const ushort* __restrict__ xhT, const ushort* __restrict__ BTg,
    const ushort* __restrict__ dtc,
    const float* __restrict__ dt_bias, const float* __restrict__ A_log,
    ushort* __restrict__ Sc, float* __restrict__ Dcb){
  __shared__ __align__(16) ushort sXG[64*128];   // 16KB (swizzled)
  __shared__ __align__(16) ushort sBT[128*128];  // 32KB (swizzled)
  __shared__ float sG[128];
  const int bid = blockIdx.x;
  const int h = bid & 31, bc = bid >> 5, b = bc >> 3, c = bc & 7;
  const int tid = threadIdx.x, wave = tid >> 6, lane = tid & 63;
  const int l16 = lane & 15, l4 = lane >> 4;
  const int sci = (b*32 + h)*8 + c;
  {
    const ushort* src = BTg + (size_t)(b*128)*1024 + c*128;
    for (int i2 = 0; i2 < 8; ++i2){
      int itg = wave*8 + i2;
      int r = itg*4 + l4;
      int cc = l16 ^ (r & 7);
      gload16(src + (size_t)r*1024 + cc*8, &sBT[itg*512]);
    }
  }
  const float Ah = -__expf(A_log[h]);
  if (wave == 0){
    const int row0 = b*1024 + c*128;
    float bi = dt_bias[h];
    float d0 = bf2f(dtc[(size_t)(row0 + 2*lane    )*32 + h]) + bi;
    float d1 = bf2f(dtc[(size_t)(row0 + 2*lane + 1)*32 + h]) + bi;
    d0 = (d0 > 20.f) ? d0 : log1pf(__expf(d0));
    d1 = (d1 > 20.f) ? d1 : log1pf(__expf(d1));
    float p = d0 + d1;
#pragma unroll
    for (int o = 1; o < 64; o <<= 1){
      float tp = __shfl_up(p, o);
      if (lane >= o) p += tp;
    }
    float cs127 = __shfl(p, 63);
    sG[2*lane    ] = __expf(Ah*(cs127 - (p - d1))) * d0;
    sG[2*lane + 1] = __expf(Ah*(cs127 - p)) * d1;
    if (lane == 0) Dcb[sci] = __expf(Ah*cs127);
  }
  __syncthreads();
  {
    const ushort* xsrc = xhT + (size_t)(b*2048 + h*64)*1024 + c*128;
    for (int q = tid; q < 1024; q += 256){
      int r = q >> 4, cc = q & 15;
      ushort8 v = *(const ushort8*)(xsrc + (size_t)r*1024 + cc*8);
      ushort8 o;
#pragma unroll
      for (int j = 0; j < 8; ++j) o[j] = f2bf(bf2f(v[j]) * sG[cc*8 + j]);
      *(ushort8*)&sXG[r*128 + ((cc ^ (r & 7))*8)] = o;
    }
  }
  __syncthreads();
  f32x4 acc[4][2];
#pragma unroll
  for (int m=0;m<4;m++)
#pragma unroll
    for (int nf=0;nf<2;nf++) acc[m][nf] = (f32x4){0.f,0.f,0.f,0.f};
  for (int ks = 0; ks < 4; ++ks){
    bf16x8 av[4], bv[2];
#pragma unroll
    for (int m = 0; m < 4; ++m){
      int rp = m*16 + l16;
      av[m] = *(const bf16x8*)&sXG[rp*128 + (((ks*4 + l4) ^ (rp & 7))*8)];
    }
#pragma unroll
    for (int nf = 0; nf < 2; ++nf){
      int rn = wave*32 + nf*16 + l16;
      bv[nf] = *(const bf16x8*)&sBT[rn*128 + (((ks*4 + l4) ^ (rn & 7))*8)];
    }
#pragma unroll
    for (int m = 0; m < 4; ++m)
#pragma unroll
      for (int nf = 0; nf < 2; ++nf)
        acc[m][nf] = __builtin_amdgcn_mfma_f32_16x16x32_bf16(av[m], bv[nf], acc[m][nf], 0, 0, 0);
  }
  const size_t base = (size_t)sci * 8192;
#pragma unroll
  for (int m = 0; m < 4; ++m)
#pragma unroll
    for (int nf = 0; nf < 2; ++nf)
#pragma unroll
      for (int r = 0; r < 4; ++r){
        int p = m*16 + l4*4 + r;
        int n = wave*32 + nf*16 + l16;
        Sc[base + p*128 + n] = f2bf(acc[m][nf][r]);
      }
}

// ---------------- chunk recurrence: h <- h*Dc + Sc ; writes h_in over Sc in place ----------------
__global__ __launch_bounds__(256) void k_chunkscan(ushort* __restrict__ Sc,
                                                   const float* __restrict__ Dcb){
  size_t idx = (size_t)blockIdx.x*256 + threadIdx.x;   // 2,097,152 total
  int bh = (int)(idx >> 13);
  int pn = (int)(idx & 8191);
  float hv = 0.f;
  for (int c = 0; c < 8; ++c){
    size_t o = (size_t)(bh*8 + c)*8192 + pn;
    float s = bf2f(Sc[o]);
    float dc = Dcb[bh*8 + c];
    Sc[o] = f2bf(hv);
    hv = hv*dc + s;
  }
}

// ---------------- main SSD chunk kernel: y = (mask.(C@B^T))@X + decay*(C@h^T), gated ----------------
// 65KB LDS (2 blocks/CU); X^T and h_in fragments loaded global->register up front.
__global__ __launch_bounds__(256, 2) void k_ssd(
    const ushort* __restrict__ co, const ushort* __restrict__ zz,
    const ushort* __restrict__ dtc, const ushort* __restrict__ xhT,
    const ushort* __restrict__ Hin,
    const float* __restrict__ dt_bias, const float* __restrict__ A_log,
    const float* __restrict__ D_param,
    ushort* __restrict__ yv){
  __shared__ __align__(16) ushort sC [128*128];  // 32KB C tile (swizzled)
  __shared__ __align__(16) ushort sBP[128*128];  // 32KB B tile, then P (swizzled)
  __shared__ float csv[128], dtv[128];
  const int bid = blockIdx.x;
  const int h = bid & 31, bc = bid >> 5, b = bc >> 3, c = bc & 7;
  const int tid = threadIdx.x, wave = tid >> 6, lane = tid & 63;
  const int l16 = lane & 15, l4 = lane >> 4;
  const int wr = wave >> 1, wc = wave & 1;
  const int row0 = b*1024 + c*128;
  const ushort* cbase = co + (size_t)row0*CONVDIM;
  for (int i2 = 0; i2 < 8; ++i2){
    int itg = wave*8 + i2;
    int r = itg*4 + l4;
    int cc = l16 ^ (r & 7);
    gload16(cbase + (size_t)r*CONVDIM + 2176 + cc*8, &sC [itg*512]);
    gload16(cbase + (size_t)r*CONVDIM + 2048 + cc*8, &sBP[itg*512]);
  }
  // prefetch GEMM2 B-operand fragments (X^T, h_in) directly to registers
  bf16x8 xbr[2][4], hbr[2][4];
  {
    const size_t hbase = (size_t)((b*32 + h)*8 + c)*8192;
#pragma unroll
    for (int n = 0; n < 2; ++n){
      const int rp = wc*32 + n*16 + l16;
      const ushort* xrow = xhT + (size_t)(b*2048 + h*64 + rp)*1024 + c*128;
      const ushort* hrow = Hin + hbase + (size_t)rp*128;
#pragma unroll
      for (int ks = 0; ks < 4; ++ks){
        xbr[n][ks] = *(const bf16x8*)(xrow + (ks*4 + l4)*8);
        hbr[n][ks] = *(const bf16x8*)(hrow + (ks*4 + l4)*8);
      }
    }
  }
  const float Ah = -__expf(A_log[h]);
  if (wave == 0){
    float bi = dt_bias[h];
    float d0 = bf2f(dtc[(size_t)(row0 + 2*lane    )*32 + h]) + bi;
    float d1 = bf2f(dtc[(size_t)(row0 + 2*lane + 1)*32 + h]) + bi;
    d0 = (d0 > 20.f) ? d0 : log1pf(__expf(d0));
    d1 = (d1 > 20.f) ? d1 : log1pf(__expf(d1));
    float p = d0 + d1;
#pragma unroll
    for (int o = 1; o < 64; o <<= 1){
      float tp = __shfl_up(p, o);
      if (lane >= o) p += tp;
    }
    csv[2*lane    ] = p - d1;
    csv[2*lane + 1] = p;
    dtv[2*lane    ] = d0;
    dtv[2*lane + 1] = d1;
  }
  __syncthreads();
  // GEMM1: S[i][s] = C[i].B[s]
  f32x4 acc[4][4];
#pragma unroll
  for (int m=0;m<4;m++)
#pragma unroll
    for (int n=0;n<4;n++) acc[m][n] = (f32x4){0.f,0.f,0.f,0.f};
  for (int ks = 0; ks < 4; ++ks){
    bf16x8 av[4], bv[4];
#pragma unroll
    for (int m = 0; m < 4; ++m){
      int ri = wr*64 + m*16 + l16;
      av[m] = *(const bf16x8*)&sC[ri*128 + (((ks*4 + l4) ^ (ri & 7))*8)];
    }
#pragma unroll
    for (int n = 0; n < 4; ++n){
      int rs = wc*64 + n*16 + l16;
      bv[n] = *(const bf16x8*)&sBP[rs*128 + (((ks*4 + l4) ^ (rs & 7))*8)];
    }
#pragma unroll
    for (int m = 0; m < 4; ++m)
#pragma unroll
      for (int n = 0; n < 4; ++n)
        acc[m][n] = __builtin_amdgcn_mfma_f32_16x16x32_bf16(av[m], bv[n], acc[m][n], 0, 0, 0);
  }
  __syncthreads();
  // mask + dt + D-diagonal -> P (bf16, over B tile)
  const float Dp = D_param[h];
#pragma unroll
  for (int m = 0; m < 4; ++m){
#pragma unroll
    for (int r = 0; r < 4; ++r){
      int i = wr*64 + m*16 + l4*4 + r;
      float ci = csv[i];
#pragma unroll
      for (int n = 0; n < 4; ++n){
        int s = wc*64 + n*16 + l16;
        float e = __expf(Ah*(ci - csv[s]));
        float v = (i >= s) ? acc[m][n][r]*e*dtv[s] : 0.f;
        if (i == s) v += Dp;
        sBP[i*128 + (s ^ ((i & 7)<<3))] = f2bf(v);
      }
    }
  }
  __syncthreads();
  // GEMM2: Y[i][p] = P@X^T + Ei*(C@h^T)   (X^T, h from registers)
  f32x4 accY[4][2], accI[4][2];
#pragma unroll
  for (int m=0;m<4;m++)
#pragma unroll
    for (int n=0;n<2;n++){ accY[m][n] = (f32x4){0.f,0.f,0.f,0.f}; accI[m][n] = (f32x4){0.f,0.f,0.f,0.f}; }
#pragma unroll
  for (int ks = 0; ks < 4; ++ks){
    bf16x8 pa[4], ca[4];
#pragma unroll
    for (int m = 0; m < 4; ++m){
      int ri = wr*64 + m*16 + l16;
      int off = ((ks*4 + l4) ^ (ri & 7))*8;
      pa[m] = *(const bf16x8*)&sBP[ri*128 + off];
      ca[m] = *(const bf16x8*)&sC [ri*128 + off];
    }
#pragma unroll
    for (int m = 0; m < 4; ++m)
#pragma unroll
      for (int n = 0; n < 2; ++n){
        accY[m][n] = __builtin_amdgcn_mfma_f32_16x16x32_bf16(pa[m], xbr[n][ks], accY[m][n], 0, 0, 0);
        accI[m][n] = __builtin_amdgcn_mfma_f32_16x16x32_bf16(ca[m], hbr[n][ks], accI[m][n], 0, 0, 0);
      }
  }
#pragma unroll
  for (int m = 0; m < 4; ++m){
#pragma unroll
    for (int r = 0; r < 4; ++r){
      int i = wr*64 + m*16 + l4*4 + r;
      float Ei = __expf(Ah*csv[i]);
      int grow = row0 + i;
#pragma unroll
      for (int n = 0; n < 2; ++n){
        int p = wc*32 + n*16 + l16;
        float yvl = accY[m][n][r] + Ei*accI[m][n][r];
        float z = bf2f(zz[(size_t)grow*2048 + h*64 + p]);
        yv[(size_t)grow*DI + h*64 + p] = f2bf(yvl * siluf(z));
      }
    }
  }
}

extern "C" void kernel_launch(void* const* d_in, const int* in_sizes, int n_in,
                              void* d_out, int out_size, void* d_ws, size_t ws_size,
                              hipStream_t stream){
  const float* x       = (const float*)d_in[0];
  const float* t       = (const float*)d_in[1];
  const float* y       = (const float*)d_in[2];
  const float* w_ada   = (const float*)d_in[3];
  const float* b_ada   = (const float*)d_in[4];
  const float* w_in    = (const float*)d_in[5];
  const float* conv_w  = (const float*)d_in[6];
  const float* conv_b  = (const float*)d_in[7];
  const float* dt_bias = (const float*)d_in[8];
  const float* A_log   = (const float*)d_in[9];
  const float* D_param = (const float*)d_in[10];
  const float* w_out   = (const float*)d_in[11];

  char* w = (char*)d_ws;
  size_t off = 0;
  auto alloc = [&](size_t bytes)->char*{
    char* p = w + off; off += (bytes + 255) & ~(size_t)255; return p;
  };
  ushort* zz    = (ushort*)alloc((size_t)ROWS*2048*2);   // z part of in_proj
  ushort* xbc   = (ushort*)alloc((size_t)ROWS*CONVDIM*2);// conv input; xhT alias (33.6<=37.7MB)
  ushort* dtc   = (ushort*)alloc((size_t)ROWS*32*2);     // dt logits
  ushort* co    = (ushort*)alloc((size_t)ROWS*CONVDIM*2);
  ushort* Mss   = (ushort*)alloc((size_t)ROWS*2048*2);   // shift|scale -> Sc alias
  ushort* Mg    = (ushort*)alloc((size_t)ROWS*1024*2);   // gate
  ushort* yv    = (ushort*)alloc((size_t)ROWS*DI*2);
  ushort* woutT = (ushort*)alloc(1024ull*2048*2);
  ushort* waT   = (ushort*)alloc(3072ull*1024*2);
  ushort* winT  = (ushort*)alloc(4608ull*1024*2);
  float*  atb   = (float*) alloc(8ull*3072*4);
  ushort* Ya    = (ushort*)alloc((size_t)ROWS*1024*2);   // silu(y) -> mod
  ushort* BTg   = (ushort*)alloc((size_t)8*128*1024*2);
  float*  Dcb   = (float*) alloc(2048ull*4);
  ushort* xhT   = xbc;   // alias: xbc dead after k_conv; xhT needs 33.6MB <= 37.7MB
  ushort* Sc    = Mss;   // alias: Mss dead after k_lnmod; same size (33.6MB)

  // 1. Ya = bf16(silu(y))
  k_silu_cast<<<dim3(ROWS*1024/(256*4)), 256, 0, stream>>>(y, Ya, ROWS*1024);
  // 2. weight transposes (f32 -> bf16 [N][K])
  k_transpose_cast<<<dim3(96,32),  256, 0, stream>>>(w_ada, waT,  1024, 3072);
  k_transpose_cast<<<dim3(137,32), 256, 0, stream>>>(w_in,  winT, 1024, 4384);
  k_transpose_cast<<<dim3(32,64),  256, 0, stream>>>(w_out, woutT, 2048, 1024);
  // 3. at = silu(t)@w_ada + b_ada  (f32)
  k_at<<<dim3(12,8), 256, 0, stream>>>(t, w_ada, b_ada, atb);
  // 4. [shift|scale] -> Mss, gate -> Mg   (1D grid 64*24=1536, %8==0)
  k_gemm<1><<<dim3(1536), 256, 0, stream>>>(Ya, waT, Mss, Mg, nullptr, nullptr, ROWS, 3072, 1024, 24,
                                            b_ada, atb, nullptr, nullptr);
  // 5. mod = LN(x)*(1+scale)+shift  (into Ya)
  k_lnmod<<<dim3(ROWS), 256, 0, stream>>>(x, Mss, Ya);
  // 6. in_proj: zz | xbc | dtc   (1D grid 64*35=2240, %8==0)
  k_gemm<0><<<dim3(2240), 256, 0, stream>>>(Ya, winT, zz, xbc, dtc, nullptr, ROWS, DPROJ, 1024, 35,
                                            nullptr, nullptr, nullptr, nullptr);
  // 7. conv4 + silu
  k_conv<<<dim3(9,ROWS), 256, 0, stream>>>(xbc, conv_w, conv_b, co);
  // 8. transpose xh+B -> xhT (over xbc), BTg
  k_transT<<<dim3(34,16,8), 256, 0, stream>>>(co, xhT, BTg);
  // 9. per-chunk state contributions (Sc over Mss)
  k_chunkstate<<<dim3(2048), 256, 0, stream>>>(xhT, BTg, dtc, dt_bias, A_log, Sc, Dcb);
  // 10. chunk-state recurrence (in place: Sc -> h_in)
  k_chunkscan<<<dim3(8192), 256, 0, stream>>>(Sc, Dcb);
  // 11. SSD main: intra + inter + D + silu(z) gate -> yv
  k_ssd<<<dim3(2048), 256, 0, stream>>>(co, zz, dtc, xhT, Sc, dt_bias, A_log, D_param, yv);
  // 12. out = gate * (yv @ w_out) + x   (1D grid 64*8=512, %8==0)
  k_gemm<2><<<dim3(512), 256, 0, stream>>>(yv, woutT, nullptr, nullptr, nullptr, (float*)d_out,
                                           ROWS, 1024, 2048, 8, nullptr, nullptr, Mg, x);
}

// Round 10
// 421.402 us; speedup vs baseline: 1.3975x; 1.1555x over previous
//
#include <hip/hip_runtime.h>

typedef float f32x4 __attribute__((ext_vector_type(4)));
typedef __bf16 bf16x8 __attribute__((ext_vector_type(8)));
typedef unsigned short ushort;
typedef ushort ushort8 __attribute__((ext_vector_type(8)));
typedef ushort ushort4v __attribute__((ext_vector_type(4)));

#define DM 1024
#define DI 2048
#define DSTATE 128
#define NH 32
#define HD 64
#define CONVDIM 2304
#define DPROJ 4384
#define ROWS 8192

__device__ __forceinline__ float bf2f(ushort u){
  union { unsigned int i; float f; } v; v.i = ((unsigned int)u)<<16; return v.f;
}
__device__ __forceinline__ ushort f2bf(float f){
  union { float f; unsigned int i; } v; v.f = f;
  unsigned int r = v.i + 0x7FFFu + ((v.i>>16)&1u);
  return (ushort)(r>>16);
}
__device__ __forceinline__ float siluf(float x){ return x / (1.f + __expf(-x)); }

__device__ __forceinline__ void gload16(const ushort* g, ushort* l){
  __builtin_amdgcn_global_load_lds(
      (const __attribute__((address_space(1))) void*)g,
      (__attribute__((address_space(3))) void*)l, 16, 0, 0);
}

// ---------------- elementwise: Ya = bf16(silu(y)) ----------------
__global__ __launch_bounds__(256) void k_silu_cast(const float* __restrict__ in,
                                                   ushort* __restrict__ out, int n){
  int i = (blockIdx.x*256 + threadIdx.x)*4;
  if (i >= n) return;
  float4 v = *(const float4*)(in + i);
  ushort4v o;
  o.x = f2bf(siluf(v.x)); o.y = f2bf(siluf(v.y));
  o.z = f2bf(siluf(v.z)); o.w = f2bf(siluf(v.w));
  *(ushort4v*)(out + i) = o;
}

// ---------------- weight transpose+cast: in[K][N] f32 -> out[N][K] bf16 ----------------
__global__ __launch_bounds__(256) void k_transpose_cast(const float* __restrict__ in,
                                                        ushort* __restrict__ out,
                                                        int K, int N){
  __shared__ float tile[32][33];
  int n0 = blockIdx.x*32, k0 = blockIdx.y*32;
  int tx = threadIdx.x & 31, ty = threadIdx.x >> 5; // 32x8
  for (int r = ty; r < 32; r += 8) tile[r][tx] = in[(size_t)(k0+r)*N + n0+tx];
  __syncthreads();
  for (int r = ty; r < 32; r += 8) out[(size_t)(n0+r)*K + k0+tx] = f2bf(tile[tx][r]);
}

// ---------------- at[b][n] = silu(t[b]) @ w_ada + b_ada ----------------
__global__ __launch_bounds__(256) void k_at(const float* __restrict__ t,
                                            const float* __restrict__ w_ada,
                                            const float* __restrict__ b_ada,
                                            float* __restrict__ at){
  __shared__ float st[1024];
  int b = blockIdx.y;
  int col = blockIdx.x*256 + threadIdx.x;
  for (int i = threadIdx.x; i < 1024; i += 256) st[i] = siluf(t[b*1024 + i]);
  __syncthreads();
  float acc = 0.f;
  for (int k = 0; k < 1024; ++k) acc += st[k] * w_ada[(size_t)k*3072 + col];
  at[b*3072 + col] = acc + b_ada[col];
}

// ---------------- GEMM: 256x128 tile, BK=32, 8 waves, TRIPLE-buffer counted-vmcnt ----------------
// Tile T: compute from buf[T%3]; stage tile T+2 into buf[(T+2)%3]; vmcnt(3)+s_barrier.
// buf stride 12288 ushorts: A 8192 (256x32), B 4096 (128x32). Swizzle as verified r4/r7.
#define STG(Q, KT) do{ \
  gload16(pA0 + (size_t)(KT)*32, &sm[(Q)*12288 + (wave*2+0)*512]); \
  gload16(pA1 + (size_t)(KT)*32, &sm[(Q)*12288 + (wave*2+1)*512]); \
  gload16(pB0 + (size_t)(KT)*32, &sm[(Q)*12288 + 8192 + wave*512]); }while(0)

#define CMP(BOFF) do{ \
  bf16x8 af[4], bfr[4]; \
  _Pragma("unroll") \
  for (int m=0;m<4;m++) af[m]  = *(const bf16x8*)&sm[(BOFF) + (wr*64 + m*16 + l16)*32 + kbs]; \
  _Pragma("unroll") \
  for (int n=0;n<4;n++) bfr[n] = *(const bf16x8*)&sm[(BOFF) + 8192 + (wc*64 + n*16 + l16)*32 + kbs]; \
  __builtin_amdgcn_s_setprio(1); \
  _Pragma("unroll") \
  for (int m=0;m<4;m++) \
    _Pragma("unroll") \
    for (int n=0;n<4;n++) \
      acc[m][n] = __builtin_amdgcn_mfma_f32_16x16x32_bf16(af[m], bfr[n], acc[m][n], 0, 0, 0); \
  __builtin_amdgcn_s_setprio(0); }while(0)

#define BODY(Q, T) do{ \
  STG(((Q)+2)%3, (T)+2); \
  CMP((Q)*12288); \
  asm volatile("s_waitcnt vmcnt(3)" ::: "memory"); \
  __builtin_amdgcn_s_barrier(); \
  __builtin_amdgcn_sched_barrier(0); }while(0)

template<int EPI>
__global__ __launch_bounds__(512)
void k_gemm(const ushort* __restrict__ Ag, const ushort* __restrict__ Bt,
            ushort* __restrict__ Cb, ushort* __restrict__ Cb2, ushort* __restrict__ Cb3,
            float* __restrict__ Cf,
            int M, int N, int K, int nbn,
            const float* __restrict__ bias, const float* __restrict__ at,
            const ushort* __restrict__ gateM, const float* __restrict__ xres){
  __shared__ __align__(16) ushort sm[3*12288];   // 3 bufs x (A 16KB + B 8KB) = 72KB
  const int tid  = threadIdx.x;
  const int wave = tid >> 6, lane = tid & 63;
  // XCD-chunked swizzle (nwg % 8 == 0) + GROUP_M=4 supertiling
  const int nwg = gridDim.x, bid0 = blockIdx.x;
  const int wg = (bid0 & 7)*(nwg >> 3) + (bid0 >> 3);
  const int pg = nbn << 2;
  const int g  = wg / pg;
  const int rem = wg - g*pg;
  const int bm = (g << 2) + (rem & 3);
  const int bn = rem >> 2;
  const int wr = wave >> 1, wc = wave & 1;
  const int l16 = lane & 15, kb = lane >> 4;
  const int arow0 = (wave*2+0)*16 + (lane>>2);   // A rows 0..255
  const int arow1 = (wave*2+1)*16 + (lane>>2);
  const int brow  = wave*16 + (lane>>2);          // B rows 0..127
  const int kcs = (lane & 3) ^ ((lane>>3)&3);
  const int kbs = (kb ^ ((l16>>1)&3))*8;

  const ushort* pA0 = Ag + (size_t)(bm*256 + arow0)*K + kcs*8;
  const ushort* pA1 = Ag + (size_t)(bm*256 + arow1)*K + kcs*8;
  int br0 = bn*128 + brow; if (br0 > N-1) br0 = N-1;
  const ushort* pB0 = Bt + (size_t)br0*K + kcs*8;

  f32x4 acc[4][4];
#pragma unroll
  for (int m=0;m<4;m++)
#pragma unroll
    for (int n=0;n<4;n++) acc[m][n] = (f32x4){0.f,0.f,0.f,0.f};

  const int NT = K >> 5;
  const int NB = NT - 2;

  // prologue: stage tiles 0,1; wait tile0 landed (6 outstanding -> 3)
  STG(0, 0); STG(1, 1);
  asm volatile("s_waitcnt vmcnt(3)" ::: "memory");
  __builtin_amdgcn_s_barrier();
  __builtin_amdgcn_sched_barrier(0);

  int T = 0;
  for (; T + 3 <= NB; T += 3){
    BODY(0, T); BODY(1, T+1); BODY(2, T+2);
  }
  if (NB - T >= 1) BODY(0, T);
  if (NB - T >= 2) BODY(1, T+1);

  // tail: tiles NB, NB+1 already staged
  {
    const int qa = NB % 3, qb = (NB + 1) % 3;
    CMP(qa*12288);
    asm volatile("s_waitcnt vmcnt(0)" ::: "memory");
    __builtin_amdgcn_s_barrier();
    __builtin_amdgcn_sched_barrier(0);
    CMP(qb*12288);
  }

#pragma unroll
  for (int m=0;m<4;m++){
    int grow_base = bm*256 + wr*64 + m*16 + (lane>>4)*4;
#pragma unroll
    for (int n=0;n<4;n++){
      int gcol = bn*128 + wc*64 + n*16 + l16;
      if (EPI == 0){
        if (gcol < N){
#pragma unroll
          for (int r=0;r<4;r++){
            int row = grow_base + r;
            float v = acc[m][n][r];
            if (gcol < 2048)      Cb [(size_t)row*2048 + gcol] = f2bf(v);
            else if (gcol < 4352) Cb2[(size_t)row*2304 + (gcol-2048)] = f2bf(v);
            else                  Cb3[(size_t)row*32   + (gcol-4352)] = f2bf(v);
          }
        }
      } else if (EPI == 1){
        float bv = bias[gcol];
#pragma unroll
        for (int r=0;r<4;r++){
          int row = grow_base + r;
          float v = acc[m][n][r] + bv + at[(row>>10)*3072 + gcol];
          if (gcol < 2048) Cb [(size_t)row*2048 + gcol] = f2bf(v);
          else             Cb2[(size_t)row*1024 + (gcol - 2048)] = f2bf(v);
        }
      } else {
#pragma unroll
        for (int r=0;r<4;r++){
          int row = grow_base + r;
          float g2 = bf2f(gateM[(size_t)row*1024 + gcol]);
          Cf[(size_t)row*1024 + gcol] = g2*acc[m][n][r] + xres[(size_t)row*1024 + gcol];
        }
      }
    }
  }
}

// ---------------- LN + modulation: mod = LN(x)*(1+scale)+shift (bf16) ----------------
__global__ __launch_bounds__(256) void k_lnmod(const float* __restrict__ x,
                                               const ushort* __restrict__ Mss,
                                               ushort* __restrict__ mod){
  int row = blockIdx.x;
  const float* xr = x + (size_t)row*1024;
  float v[4]; float s = 0.f, s2 = 0.f;
#pragma unroll
  for (int j=0;j<4;j++){ v[j] = xr[threadIdx.x + j*256]; s += v[j]; s2 += v[j]*v[j]; }
#pragma unroll
  for (int o=32;o>0;o>>=1){ s += __shfl_down(s,o); s2 += __shfl_down(s2,o); }
  __shared__ float ls[4], ls2[4];
  int wv = threadIdx.x >> 6;
  if ((threadIdx.x & 63) == 0){ ls[wv] = s; ls2[wv] = s2; }
  __syncthreads();
  s  = ls[0]+ls[1]+ls[2]+ls[3];
  s2 = ls2[0]+ls2[1]+ls2[2]+ls2[3];
  float mu = s * (1.f/1024.f);
  float var = s2 * (1.f/1024.f) - mu*mu;
  float rstd = rsqrtf(var + 1e-6f);
  const ushort* Mr = Mss + (size_t)row*2048;
#pragma unroll
  for (int j=0;j<4;j++){
    int d = threadIdx.x + j*256;
    float sc = bf2f(Mr[1024 + d]);
    float sh = bf2f(Mr[d]);
    mod[(size_t)row*1024 + d] = f2bf((v[j]-mu)*rstd*(1.f+sc) + sh);
  }
}

// ---------------- fused conv4+silu+transpose ----------------
// 64ch x 64L tile. ch<2048 -> xhT[ch][l]; 2048..2175 -> BTg[ch][l] AND co[l][ch];
// 2176..2303 -> co[l][ch].
__global__ __launch_bounds__(256) void k_convT(const ushort* __restrict__ xbc,
                                               const float* __restrict__ conv_w,
                                               const float* __restrict__ conv_b,
                                               ushort* __restrict__ co,
                                               ushort* __restrict__ xhT,
                                               ushort* __restrict__ BTg){
  __shared__ ushort lin[67*64];
  __shared__ __align__(16) ushort outb[64*76];
  const int cb = blockIdx.x, lb = blockIdx.y, b = blockIdx.z;
  const int ch0 = cb*64, l0 = lb*64;
  const int tid = threadIdx.x;
  for (int q = tid; q < 67*8; q += 256){
    int r = q >> 3, c8 = q & 7;
    int l = l0 - 3 + r;
    ushort8 v = {0,0,0,0,0,0,0,0};
    if (l >= 0) v = *(const ushort8*)(xbc + (size_t)(b*1024 + l)*CONVDIM + ch0 + c8*8);
    *(ushort8*)&lin[r*64 + c8*8] = v;
  }
  __syncthreads();
  const int ch = tid & 63, lg = tid >> 6;
  const int chg = ch0 + ch;
  const float w0 = conv_w[chg*4+0], w1 = conv_w[chg*4+1];
  const float w2 = conv_w[chg*4+2], w3 = conv_w[chg*4+3];
  const float cbv = conv_b[chg];
  __align__(16) ushort o[16];
#pragma unroll
  for (int j = 0; j < 16; ++j){
    int r = lg*16 + j;
    float a = cbv + w0*bf2f(lin[r*64+ch])     + w1*bf2f(lin[(r+1)*64+ch])
                  + w2*bf2f(lin[(r+2)*64+ch]) + w3*bf2f(lin[(r+3)*64+ch]);
    o[j] = f2bf(siluf(a));
  }
  if (cb < 34){   // transposed output (xh or B)
    *(ushort8*)&outb[ch*76 + lg*16]     = *(ushort8*)&o[0];
    *(ushort8*)&outb[ch*76 + lg*16 + 8] = *(ushort8*)&o[8];
    __syncthreads();
    int row = tid >> 2, seg = tid & 3;
    ushort8 v0 = *(ushort8*)&outb[row*76 + seg*16];
    ushort8 v1 = *(ushort8*)&outb[row*76 + seg*16 + 8];
    ushort* dst = (cb < 32)
      ? (xhT + (size_t)(b*2048 + ch0 + row)*1024 + l0 + seg*16)
      : (BTg + (size_t)(b*128 + (ch0 - 2048) + row)*1024 + l0 + seg*16);
    *(ushort8*)dst = v0; *(ushort8*)(dst+8) = v1;
  }
  if (cb >= 32){  // row-major output (B or C) into co
    __syncthreads();
#pragma unroll
    for (int j = 0; j < 16; ++j) outb[(lg*16+j)*76 + ch] = o[j];
    __syncthreads();
    int l = tid >> 2, seg = tid & 3;
    ushort8 v0 = *(ushort8*)&outb[l*76 + seg*16];
    ushort8 v1 = *(ushort8*)&outb[l*76 + seg*16 + 8];
    ushort* dst = co + (size_t)(b*1024 + l0 + l)*CONVDIM + ch0 + seg*16;
    *(ushort8*)dst = v0; *(ushort8*)(dst+8) = v1;
  }
}

// ---------------- chunk state contribution: Sc[p][n] = sum_s G[s]*x[s,p]*B[s,n] ----------------
__global__ __launch_bounds__(256) void k_chunkstate(
    const ushort* __restrict__ xhT, const ushort* __restrict__ BTg,
    const ushort* __restrict__ dtc,
    const float* __restrict__ dt_bias, const float* __restrict__ A_log,
    ushort* __restrict__ Sc, float* __restrict__ Dcb){
  __shared__ __align__(16) ushort sXG[64*128];   // 16KB (swizzled)
  __shared__ __align__(16) ushort sBT[128*128];  // 32KB (swizzled)
  __shared__ float sG[128];
  const int bid = blockIdx.x;
  const int h = bid & 31, bc = bid >> 5, b = bc >> 3, c = bc & 7;
  const int tid = threadIdx.x, wave = tid >> 6, lane = tid & 63;
  const int l16 = lane & 15, l4 = lane >> 4;
  const int sci = (b*32 + h)*8 + c;
  {
    const ushort* src = BTg + (size_t)(b*128)*1024 + c*128;
    for (int i2 = 0; i2 < 8; ++i2){
      int itg = wave*8 + i2;
      int r = itg*4 + l4;
      int cc = l16 ^ (r & 7);
      gload16(src + (size_t)r*1024 + cc*8, &sBT[itg*512]);
    }
  }
  const float Ah = -__expf(A_log[h]);
  if (wave == 0){
    const int row0 = b*1024 + c*128;
    float bi = dt_bias[h];
    float d0 = bf2f(dtc[(size_t)(row0 + 2*lane    )*32 + h]) + bi;
    float d1 = bf2f(dtc[(size_t)(row0 + 2*lane + 1)*32 + h]) + bi;
    d0 = (d0 > 20.f) ? d0 : log1pf(__expf(d0));
    d1 = (d1 > 20.f) ? d1 : log1pf(__expf(d1));
    float p = d0 + d1;
#pragma unroll
    for (int o = 1; o < 64; o <<= 1){
      float tp = __shfl_up(p, o);
      if (lane >= o) p += tp;
    }
    float cs127 = __shfl(p, 63);
    sG[2*lane    ] = __expf(Ah*(cs127 - (p - d1))) * d0;
    sG[2*lane + 1] = __expf(Ah*(cs127 - p)) * d1;
    if (lane == 0) Dcb[sci] = __expf(Ah*cs127);
  }
  __syncthreads();
  {
    const ushort* xsrc = xhT + (size_t)(b*2048 + h*64)*1024 + c*128;
    for (int q = tid; q < 1024; q += 256){
      int r = q >> 4, cc = q & 15;
      ushort8 v = *(const ushort8*)(xsrc + (size_t)r*1024 + cc*8);
      ushort8 o;
#pragma unroll
      for (int j = 0; j < 8; ++j) o[j] = f2bf(bf2f(v[j]) * sG[cc*8 + j]);
      *(ushort8*)&sXG[r*128 + ((cc ^ (r & 7))*8)] = o;
    }
  }
  __syncthreads();
  f32x4 acc[4][2];
#pragma unroll
  for (int m=0;m<4;m++)
#pragma unroll
    for (int nf=0;nf<2;nf++) acc[m][nf] = (f32x4){0.f,0.f,0.f,0.f};
  for (int ks = 0; ks < 4; ++ks){
    bf16x8 av[4], bv[2];
#pragma unroll
    for (int m = 0; m < 4; ++m){
      int rp = m*16 + l16;
      av[m] = *(const bf16x8*)&sXG[rp*128 + (((ks*4 + l4) ^ (rp & 7))*8)];
    }
#pragma unroll
    for (int nf = 0; nf < 2; ++nf){
      int rn = wave*32 + nf*16 + l16;
      bv[nf] = *(const bf16x8*)&sBT[rn*128 + (((ks*4 + l4) ^ (rn & 7))*8)];
    }
#pragma unroll
    for (int m = 0; m < 4; ++m)
#pragma unroll
      for (int nf = 0; nf < 2; ++nf)
        acc[m][nf] = __builtin_amdgcn_mfma_f32_16x16x32_bf16(av[m], bv[nf], acc[m][nf], 0, 0, 0);
  }
  const size_t base = (size_t)sci * 8192;
#pragma unroll
  for (int m = 0; m < 4; ++m)
#pragma unroll
    for (int nf = 0; nf < 2; ++nf)
#pragma unroll
      for (int r = 0; r < 4; ++r){
        int p = m*16 + l4*4 + r;
        int n = wave*32 + nf*16 + l16;
        Sc[base + p*128 + n] = f2bf(acc[m][nf][r]);
      }
}

// ---------------- chunk recurrence: h <- h*Dc + Sc ; writes h_in over Sc in place ----------------
__global__ __launch_bounds__(256) void k_chunkscan(ushort* __restrict__ Sc,
                                                   const float* __restrict__ Dcb){
  size_t idx = (size_t)blockIdx.x*256 + threadIdx.x;   // 2,097,152 total
  int bh = (int)(idx >> 13);
  int pn = (int)(idx & 8191);
  float hv = 0.f;
  for (int c = 0; c < 8; ++c){
    size_t o = (size_t)(bh*8 + c)*8192 + pn;
    float s = bf2f(Sc[o]);
    float dc = Dcb[bh*8 + c];
    Sc[o] = f2bf(hv);
    hv = hv*dc + s;
  }
}

// ---------------- main SSD chunk kernel ----------------
__global__ __launch_bounds__(256, 2) void k_ssd(
    const ushort* __restrict__ co, const ushort* __restrict__ zz,
    const ushort* __restrict__ dtc, const ushort* __restrict__ xhT,
    const ushort* __restrict__ Hin,
    const float* __restrict__ dt_bias, const float* __restrict__ A_log,
    const float* __restrict__ D_param,
    ushort* __restrict__ yv){
  __shared__ __align__(16) ushort sC [128*128];
  __shared__ __align__(16) ushort sBP[128*128];
  __shared__ float csv[128], dtv[128];
  const int bid = blockIdx.x;
  const int h = bid & 31, bc = bid >> 5, b = bc >> 3, c = bc & 7;
  const int tid = threadIdx.x, wave = tid >> 6, lane = tid & 63;
  const int l16 = lane & 15, l4 = lane >> 4;
  const int wr = wave >> 1, wc = wave & 1;
  const int row0 = b*1024 + c*128;
  const ushort* cbase = co + (size_t)row0*CONVDIM;
  for (int i2 = 0; i2 < 8; ++i2){
    int itg = wave*8 + i2;
    int r = itg*4 + l4;
    int cc = l16 ^ (r & 7);
    gload16(cbase + (size_t)r*CONVDIM + 2176 + cc*8, &sC [itg*512]);
    gload16(cbase + (size_t)r*CONVDIM + 2048 + cc*8, &sBP[itg*512]);
  }
  bf16x8 xbr[2][4], hbr[2][4];
  {
    const size_t hbase = (size_t)((b*32 + h)*8 + c)*8192;
#pragma unroll
    for (int n = 0; n < 2; ++n){
      const int rp = wc*32 + n*16 + l16;
      const ushort* xrow = xhT + (size_t)(b*2048 + h*64 + rp)*1024 + c*128;
      const ushort* hrow = Hin + hbase + (size_t)rp*128;
#pragma unroll
      for (int ks = 0; ks < 4; ++ks){
        xbr[n][ks] = *(const bf16x8*)(xrow + (ks*4 + l4)*8);
        hbr[n][ks] = *(const bf16x8*)(hrow + (ks*4 + l4)*8);
      }
    }
  }
  const float Ah = -__expf(A_log[h]);
  if (wave == 0){
    float bi = dt_bias[h];
    float d0 = bf2f(dtc[(size_t)(row0 + 2*lane    )*32 + h]) + bi;
    float d1 = bf2f(dtc[(size_t)(row0 + 2*lane + 1)*32 + h]) + bi;
    d0 = (d0 > 20.f) ? d0 : log1pf(__expf(d0));
    d1 = (d1 > 20.f) ? d1 : log1pf(__expf(d1));
    float p = d0 + d1;
#pragma unroll
    for (int o = 1; o < 64; o <<= 1){
      float tp = __shfl_up(p, o);
      if (lane >= o) p += tp;
    }
    csv[2*lane    ] = p - d1;
    csv[2*lane + 1] = p;
    dtv[2*lane    ] = d0;
    dtv[2*lane + 1] = d1;
  }
  __syncthreads();
  f32x4 acc[4][4];
#pragma unroll
  for (int m=0;m<4;m++)
#pragma unroll
    for (int n=0;n<4;n++) acc[m][n] = (f32x4){0.f,0.f,0.f,0.f};
  for (int ks = 0; ks < 4; ++ks){
    bf16x8 av[4], bv[4];
#pragma unroll
    for (int m = 0; m < 4; ++m){
      int ri = wr*64 + m*16 + l16;
      av[m] = *(const bf16x8*)&sC[ri*128 + (((ks*4 + l4) ^ (ri & 7))*8)];
    }
#pragma unroll
    for (int n = 0; n < 4; ++n){
      int rs = wc*64 + n*16 + l16;
      bv[n] = *(const bf16x8*)&sBP[rs*128 + (((ks*4 + l4) ^ (rs & 7))*8)];
    }
#pragma unroll
    for (int m = 0; m < 4; ++m)
#pragma unroll
      for (int n = 0; n < 4; ++n)
        acc[m][n] = __builtin_amdgcn_mfma_f32_16x16x32_bf16(av[m], bv[n], acc[m][n], 0, 0, 0);
  }
  __syncthreads();
  const float Dp = D_param[h];
#pragma unroll
  for (int m = 0; m < 4; ++m){
#pragma unroll
    for (int r = 0; r < 4; ++r){
      int i = wr*64 + m*16 + l4*4 + r;
      float ci = csv[i];
#pragma unroll
      for (int n = 0; n < 4; ++n){
        int s = wc*64 + n*16 + l16;
        float e = __expf(Ah*(ci - csv[s]));
        float v = (i >= s) ? acc[m][n][r]*e*dtv[s] : 0.f;
        if (i == s) v += Dp;
        sBP[i*128 + (s ^ ((i & 7)<<3))] = f2bf(v);
      }
    }
  }
  __syncthreads();
  f32x4 accY[4][2], accI[4][2];
#pragma unroll
  for (int m=0;m<4;m++)
#pragma unroll
    for (int n=0;n<2;n++){ accY[m][n] = (f32x4){0.f,0.f,0.f,0.f}; accI[m][n] = (f32x4){0.f,0.f,0.f,0.f}; }
#pragma unroll
  for (int ks = 0; ks < 4; ++ks){
    bf16x8 pa[4], ca[4];
#pragma unroll
    for (int m = 0; m < 4; ++m){
      int ri = wr*64 + m*16 + l16;
      int off = ((ks*4 + l4) ^ (ri & 7))*8;
      pa[m] = *(const bf16x8*)&sBP[ri*128 + off];
      ca[m] = *(const bf16x8*)&sC [ri*128 + off];
    }
#pragma unroll
    for (int m = 0; m < 4; ++m)
#pragma unroll
      for (int n = 0; n < 2; ++n){
        accY[m][n] = __builtin_amdgcn_mfma_f32_16x16x32_bf16(pa[m], xbr[n][ks], accY[m][n], 0, 0, 0);
        accI[m][n] = __builtin_amdgcn_mfma_f32_16x16x32_bf16(ca[m], hbr[n][ks], accI[m][n], 0, 0, 0);
      }
  }
#pragma unroll
  for (int m = 0; m < 4; ++m){
#pragma unroll
    for (int r = 0; r < 4; ++r){
      int i = wr*64 + m*16 + l4*4 + r;
      float Ei = __expf(Ah*csv[i]);
      int grow = row0 + i;
#pragma unroll
      for (int n = 0; n < 2; ++n){
        int p = wc*32 + n*16 + l16;
        float yvl = accY[m][n][r] + Ei*accI[m][n][r];
        float z = bf2f(zz[(size_t)grow*2048 + h*64 + p]);
        yv[(size_t)grow*DI + h*64 + p] = f2bf(yvl * siluf(z));
      }
    }
  }
}

extern "C" void kernel_launch(void* const* d_in, const int* in_sizes, int n_in,
                              void* d_out, int out_size, void* d_ws, size_t ws_size,
                              hipStream_t stream){
  const float* x       = (const float*)d_in[0];
  const float* t       = (const float*)d_in[1];
  const float* y       = (const float*)d_in[2];
  const float* w_ada   = (const float*)d_in[3];
  const float* b_ada   = (const float*)d_in[4];
  const float* w_in    = (const float*)d_in[5];
  const float* conv_w  = (const float*)d_in[6];
  const float* conv_b  = (const float*)d_in[7];
  const float* dt_bias = (const float*)d_in[8];
  const float* A_log   = (const float*)d_in[9];
  const float* D_param = (const float*)d_in[10];
  const float* w_out   = (const float*)d_in[11];

  char* w = (char*)d_ws;
  size_t off = 0;
  auto alloc = [&](size_t bytes)->char*{
    char* p = w + off; off += (bytes + 255) & ~(size_t)255; return p;
  };
  ushort* zz    = (ushort*)alloc((size_t)ROWS*2048*2);   // z part of in_proj
  ushort* xbc   = (ushort*)alloc((size_t)ROWS*CONVDIM*2);// conv input; Sc alias after convT
  ushort* dtc   = (ushort*)alloc((size_t)ROWS*32*2);     // dt logits
  ushort* co    = (ushort*)alloc((size_t)ROWS*CONVDIM*2);// conv out (only cols 2048..4352 used)
  ushort* Mss   = (ushort*)alloc((size_t)ROWS*2048*2);   // shift|scale -> xhT alias
  ushort* Mg    = (ushort*)alloc((size_t)ROWS*1024*2);   // gate
  ushort* yv    = (ushort*)alloc((size_t)ROWS*DI*2);
  ushort* woutT = (ushort*)alloc(1024ull*2048*2);
  ushort* waT   = (ushort*)alloc(3072ull*1024*2);
  ushort* winT  = (ushort*)alloc(4608ull*1024*2);
  float*  atb   = (float*) alloc(8ull*3072*4);
  ushort* Ya    = (ushort*)alloc((size_t)ROWS*1024*2);   // silu(y) -> mod
  ushort* BTg   = (ushort*)alloc((size_t)8*128*1024*2);
  float*  Dcb   = (float*) alloc(2048ull*4);
  ushort* xhT   = Mss;   // alias: Mss dead after k_lnmod; exact size (33.6MB)
  ushort* Sc    = xbc;   // alias: xbc dead after k_convT; 33.6 <= 37.7MB

  // 1. Ya = bf16(silu(y))
  k_silu_cast<<<dim3(ROWS*1024/(256*4)), 256, 0, stream>>>(y, Ya, ROWS*1024);
  // 2. weight transposes (f32 -> bf16 [N][K])
  k_transpose_cast<<<dim3(96,32),  256, 0, stream>>>(w_ada, waT,  1024, 3072);
  k_transpose_cast<<<dim3(137,32), 256, 0, stream>>>(w_in,  winT, 1024, 4384);
  k_transpose_cast<<<dim3(32,64),  256, 0, stream>>>(w_out, woutT, 2048, 1024);
  // 3. at = silu(t)@w_ada + b_ada  (f32)
  k_at<<<dim3(12,8), 256, 0, stream>>>(t, w_ada, b_ada, atb);
  // 4. [shift|scale] -> Mss, gate -> Mg   (256x128 tiles: 32x24=768 blocks)
  k_gemm<1><<<dim3(768), 512, 0, stream>>>(Ya, waT, Mss, Mg, nullptr, nullptr, ROWS, 3072, 1024, 24,
                                           b_ada, atb, nullptr, nullptr);
  // 5. mod = LN(x)*(1+scale)+shift  (into Ya)
  k_lnmod<<<dim3(ROWS), 256, 0, stream>>>(x, Mss, Ya);
  // 6. in_proj: zz | xbc | dtc   (32x35=1120 blocks)
  k_gemm<0><<<dim3(1120), 512, 0, stream>>>(Ya, winT, zz, xbc, dtc, nullptr, ROWS, DPROJ, 1024, 35,
                                            nullptr, nullptr, nullptr, nullptr);
  // 7. fused conv4+silu+transpose: xhT (over Mss), BTg, co[B|C]
  k_convT<<<dim3(36,16,8), 256, 0, stream>>>(xbc, conv_w, conv_b, co, xhT, BTg);
  // 8. per-chunk state contributions (Sc over xbc)
  k_chunkstate<<<dim3(2048), 256, 0, stream>>>(xhT, BTg, dtc, dt_bias, A_log, Sc, Dcb);
  // 9. chunk-state recurrence (in place: Sc -> h_in)
  k_chunkscan<<<dim3(8192), 256, 0, stream>>>(Sc, Dcb);
  // 10. SSD main: intra + inter + D + silu(z) gate -> yv
  k_ssd<<<dim3(2048), 256, 0, stream>>>(co, zz, dtc, xhT, Sc, dt_bias, A_log, D_param, yv);
  // 11. out = gate * (yv @ w_out) + x   (32x8=256 blocks)
  k_gemm<2><<<dim3(256), 512, 0, stream>>>(yv, woutT, nullptr, nullptr, nullptr, (float*)d_out,
                                           ROWS, 1024, 2048, 8, nullptr, nullptr, Mg, x);
}

// Round 11
// 416.933 us; speedup vs baseline: 1.4125x; 1.0107x over previous
//
#include <hip/hip_runtime.h>

typedef float f32x4 __attribute__((ext_vector_type(4)));
typedef __bf16 bf16x8 __attribute__((ext_vector_type(8)));
typedef unsigned short ushort;
typedef ushort ushort8 __attribute__((ext_vector_type(8)));
typedef ushort ushort4v __attribute__((ext_vector_type(4)));

#define DM 1024
#define DI 2048
#define DSTATE 128
#define NH 32
#define HD 64
#define CONVDIM 2304
#define DPROJ 4384
#define ROWS 8192

__device__ __forceinline__ float bf2f(ushort u){
  union { unsigned int i; float f; } v; v.i = ((unsigned int)u)<<16; return v.f;
}
__device__ __forceinline__ ushort f2bf(float f){
  union { float f; unsigned int i; } v; v.f = f;
  unsigned int r = v.i + 0x7FFFu + ((v.i>>16)&1u);
  return (ushort)(r>>16);
}
__device__ __forceinline__ float siluf(float x){ return x / (1.f + __expf(-x)); }

__device__ __forceinline__ void gload16(const ushort* g, ushort* l){
  __builtin_amdgcn_global_load_lds(
      (const __attribute__((address_space(1))) void*)g,
      (__attribute__((address_space(3))) void*)l, 16, 0, 0);
}

// ---------------- elementwise: Ya = bf16(silu(y)) ----------------
__global__ __launch_bounds__(256) void k_silu_cast(const float* __restrict__ in,
                                                   ushort* __restrict__ out, int n){
  int i = (blockIdx.x*256 + threadIdx.x)*4;
  if (i >= n) return;
  float4 v = *(const float4*)(in + i);
  ushort4v o;
  o.x = f2bf(siluf(v.x)); o.y = f2bf(siluf(v.y));
  o.z = f2bf(siluf(v.z)); o.w = f2bf(siluf(v.w));
  *(ushort4v*)(out + i) = o;
}

// ---------------- weight transpose+cast: in[K][N] f32 -> out[N][K] bf16 ----------------
__global__ __launch_bounds__(256) void k_transpose_cast(const float* __restrict__ in,
                                                        ushort* __restrict__ out,
                                                        int K, int N){
  __shared__ float tile[32][33];
  int n0 = blockIdx.x*32, k0 = blockIdx.y*32;
  int tx = threadIdx.x & 31, ty = threadIdx.x >> 5; // 32x8
  for (int r = ty; r < 32; r += 8) tile[r][tx] = in[(size_t)(k0+r)*N + n0+tx];
  __syncthreads();
  for (int r = ty; r < 32; r += 8) out[(size_t)(n0+r)*K + k0+tx] = f2bf(tile[tx][r]);
}

// ---------------- at[b][n] = silu(t[b]) @ w_ada + b_ada ----------------
__global__ __launch_bounds__(256) void k_at(const float* __restrict__ t,
                                            const float* __restrict__ w_ada,
                                            const float* __restrict__ b_ada,
                                            float* __restrict__ at){
  __shared__ float st[1024];
  int b = blockIdx.y;
  int col = blockIdx.x*256 + threadIdx.x;
  for (int i = threadIdx.x; i < 1024; i += 256) st[i] = siluf(t[b*1024 + i]);
  __syncthreads();
  float acc = 0.f;
  for (int k = 0; k < 1024; ++k) acc += st[k] * w_ada[(size_t)k*3072 + col];
  at[b*3072 + col] = acc + b_ada[col];
}

// ---------------- GEMM: 256x128 tile, BK=32, 8 waves, TRIPLE-buffer counted-vmcnt ----------------
#define STG(Q, KT) do{ \
  gload16(pA0 + (size_t)(KT)*32, &sm[(Q)*12288 + (wave*2+0)*512]); \
  gload16(pA1 + (size_t)(KT)*32, &sm[(Q)*12288 + (wave*2+1)*512]); \
  gload16(pB0 + (size_t)(KT)*32, &sm[(Q)*12288 + 8192 + wave*512]); }while(0)

#define CMP(BOFF) do{ \
  bf16x8 af[4], bfr[4]; \
  _Pragma("unroll") \
  for (int m=0;m<4;m++) af[m]  = *(const bf16x8*)&sm[(BOFF) + (wr*64 + m*16 + l16)*32 + kbs]; \
  _Pragma("unroll") \
  for (int n=0;n<4;n++) bfr[n] = *(const bf16x8*)&sm[(BOFF) + 8192 + (wc*64 + n*16 + l16)*32 + kbs]; \
  __builtin_amdgcn_s_setprio(1); \
  _Pragma("unroll") \
  for (int m=0;m<4;m++) \
    _Pragma("unroll") \
    for (int n=0;n<4;n++) \
      acc[m][n] = __builtin_amdgcn_mfma_f32_16x16x32_bf16(af[m], bfr[n], acc[m][n], 0, 0, 0); \
  __builtin_amdgcn_s_setprio(0); }while(0)

#define BODY(Q, T) do{ \
  STG(((Q)+2)%3, (T)+2); \
  CMP((Q)*12288); \
  asm volatile("s_waitcnt vmcnt(3)" ::: "memory"); \
  __builtin_amdgcn_s_barrier(); \
  __builtin_amdgcn_sched_barrier(0); }while(0)

template<int EPI>
__global__ __launch_bounds__(512)
void k_gemm(const ushort* __restrict__ Ag, const ushort* __restrict__ Bt,
            ushort* __restrict__ Cb, ushort* __restrict__ Cb2, ushort* __restrict__ Cb3,
            float* __restrict__ Cf,
            int M, int N, int K, int nbn,
            const float* __restrict__ bias, const float* __restrict__ at,
            const ushort* __restrict__ gateM, const float* __restrict__ xres){
  __shared__ __align__(16) ushort sm[3*12288];   // 72KB
  const int tid  = threadIdx.x;
  const int wave = tid >> 6, lane = tid & 63;
  const int nwg = gridDim.x, bid0 = blockIdx.x;
  const int wg = (bid0 & 7)*(nwg >> 3) + (bid0 >> 3);
  const int pg = nbn << 2;
  const int g  = wg / pg;
  const int rem = wg - g*pg;
  const int bm = (g << 2) + (rem & 3);
  const int bn = rem >> 2;
  const int wr = wave >> 1, wc = wave & 1;
  const int l16 = lane & 15, kb = lane >> 4;
  const int arow0 = (wave*2+0)*16 + (lane>>2);
  const int arow1 = (wave*2+1)*16 + (lane>>2);
  const int brow  = wave*16 + (lane>>2);
  const int kcs = (lane & 3) ^ ((lane>>3)&3);
  const int kbs = (kb ^ ((l16>>1)&3))*8;

  const ushort* pA0 = Ag + (size_t)(bm*256 + arow0)*K + kcs*8;
  const ushort* pA1 = Ag + (size_t)(bm*256 + arow1)*K + kcs*8;
  int br0 = bn*128 + brow; if (br0 > N-1) br0 = N-1;
  const ushort* pB0 = Bt + (size_t)br0*K + kcs*8;

  f32x4 acc[4][4];
#pragma unroll
  for (int m=0;m<4;m++)
#pragma unroll
    for (int n=0;n<4;n++) acc[m][n] = (f32x4){0.f,0.f,0.f,0.f};

  const int NT = K >> 5;
  const int NB = NT - 2;

  STG(0, 0); STG(1, 1);
  asm volatile("s_waitcnt vmcnt(3)" ::: "memory");
  __builtin_amdgcn_s_barrier();
  __builtin_amdgcn_sched_barrier(0);

  int T = 0;
  for (; T + 3 <= NB; T += 3){
    BODY(0, T); BODY(1, T+1); BODY(2, T+2);
  }
  if (NB - T >= 1) BODY(0, T);
  if (NB - T >= 2) BODY(1, T+1);

  {
    const int qa = NB % 3, qb = (NB + 1) % 3;
    CMP(qa*12288);
    asm volatile("s_waitcnt vmcnt(0)" ::: "memory");
    __builtin_amdgcn_s_barrier();
    __builtin_amdgcn_sched_barrier(0);
    CMP(qb*12288);
  }

#pragma unroll
  for (int m=0;m<4;m++){
    int grow_base = bm*256 + wr*64 + m*16 + (lane>>4)*4;
#pragma unroll
    for (int n=0;n<4;n++){
      int gcol = bn*128 + wc*64 + n*16 + l16;
      if (EPI == 0){
        if (gcol < N){
#pragma unroll
          for (int r=0;r<4;r++){
            int row = grow_base + r;
            float v = acc[m][n][r];
            if (gcol < 2048)      Cb [(size_t)row*2048 + gcol] = f2bf(v);
            else if (gcol < 4352) Cb2[(size_t)row*2304 + (gcol-2048)] = f2bf(v);
            else                  Cb3[(size_t)row*32   + (gcol-4352)] = f2bf(v);
          }
        }
      } else if (EPI == 1){
        float bv = bias[gcol];
#pragma unroll
        for (int r=0;r<4;r++){
          int row = grow_base + r;
          float v = acc[m][n][r] + bv + at[(row>>10)*3072 + gcol];
          if (gcol < 2048) Cb [(size_t)row*2048 + gcol] = f2bf(v);
          else             Cb2[(size_t)row*1024 + (gcol - 2048)] = f2bf(v);
        }
      } else {
#pragma unroll
        for (int r=0;r<4;r++){
          int row = grow_base + r;
          float g2 = bf2f(gateM[(size_t)row*1024 + gcol]);
          Cf[(size_t)row*1024 + gcol] = g2*acc[m][n][r] + xres[(size_t)row*1024 + gcol];
        }
      }
    }
  }
}

// ---------------- LN + modulation ----------------
__global__ __launch_bounds__(256) void k_lnmod(const float* __restrict__ x,
                                               const ushort* __restrict__ Mss,
                                               ushort* __restrict__ mod){
  int row = blockIdx.x;
  const float* xr = x + (size_t)row*1024;
  float v[4]; float s = 0.f, s2 = 0.f;
#pragma unroll
  for (int j=0;j<4;j++){ v[j] = xr[threadIdx.x + j*256]; s += v[j]; s2 += v[j]*v[j]; }
#pragma unroll
  for (int o=32;o>0;o>>=1){ s += __shfl_down(s,o); s2 += __shfl_down(s2,o); }
  __shared__ float ls[4], ls2[4];
  int wv = threadIdx.x >> 6;
  if ((threadIdx.x & 63) == 0){ ls[wv] = s; ls2[wv] = s2; }
  __syncthreads();
  s  = ls[0]+ls[1]+ls[2]+ls[3];
  s2 = ls2[0]+ls2[1]+ls2[2]+ls2[3];
  float mu = s * (1.f/1024.f);
  float var = s2 * (1.f/1024.f) - mu*mu;
  float rstd = rsqrtf(var + 1e-6f);
  const ushort* Mr = Mss + (size_t)row*2048;
#pragma unroll
  for (int j=0;j<4;j++){
    int d = threadIdx.x + j*256;
    float sc = bf2f(Mr[1024 + d]);
    float sh = bf2f(Mr[d]);
    mod[(size_t)row*1024 + d] = f2bf((v[j]-mu)*rstd*(1.f+sc) + sh);
  }
}

// ---------------- fused conv4+silu+transpose ----------------
// ch<2048 -> xhT[ch][l]; 2048..2175 -> BTg[ch][l] AND BC[l][ch-2048];
// 2176..2303 -> BC[l][ch-2048].
__global__ __launch_bounds__(256) void k_convT(const ushort* __restrict__ xbc,
                                               const float* __restrict__ conv_w,
                                               const float* __restrict__ conv_b,
                                               ushort* __restrict__ BC,
                                               ushort* __restrict__ xhT,
                                               ushort* __restrict__ BTg){
  __shared__ ushort lin[67*64];
  __shared__ __align__(16) ushort outb[64*76];
  const int cb = blockIdx.x, lb = blockIdx.y, b = blockIdx.z;
  const int ch0 = cb*64, l0 = lb*64;
  const int tid = threadIdx.x;
  for (int q = tid; q < 67*8; q += 256){
    int r = q >> 3, c8 = q & 7;
    int l = l0 - 3 + r;
    ushort8 v = {0,0,0,0,0,0,0,0};
    if (l >= 0) v = *(const ushort8*)(xbc + (size_t)(b*1024 + l)*CONVDIM + ch0 + c8*8);
    *(ushort8*)&lin[r*64 + c8*8] = v;
  }
  __syncthreads();
  const int ch = tid & 63, lg = tid >> 6;
  const int chg = ch0 + ch;
  const float w0 = conv_w[chg*4+0], w1 = conv_w[chg*4+1];
  const float w2 = conv_w[chg*4+2], w3 = conv_w[chg*4+3];
  const float cbv = conv_b[chg];
  __align__(16) ushort o[16];
#pragma unroll
  for (int j = 0; j < 16; ++j){
    int r = lg*16 + j;
    float a = cbv + w0*bf2f(lin[r*64+ch])     + w1*bf2f(lin[(r+1)*64+ch])
                  + w2*bf2f(lin[(r+2)*64+ch]) + w3*bf2f(lin[(r+3)*64+ch]);
    o[j] = f2bf(siluf(a));
  }
  if (cb < 34){   // transposed output (xh or B)
    *(ushort8*)&outb[ch*76 + lg*16]     = *(ushort8*)&o[0];
    *(ushort8*)&outb[ch*76 + lg*16 + 8] = *(ushort8*)&o[8];
    __syncthreads();
    int row = tid >> 2, seg = tid & 3;
    ushort8 v0 = *(ushort8*)&outb[row*76 + seg*16];
    ushort8 v1 = *(ushort8*)&outb[row*76 + seg*16 + 8];
    ushort* dst = (cb < 32)
      ? (xhT + (size_t)(b*2048 + ch0 + row)*1024 + l0 + seg*16)
      : (BTg + (size_t)(b*128 + (ch0 - 2048) + row)*1024 + l0 + seg*16);
    *(ushort8*)dst = v0; *(ushort8*)(dst+8) = v1;
  }
  if (cb >= 32){  // row-major output (B or C) into compact BC
    __syncthreads();
#pragma unroll
    for (int j = 0; j < 16; ++j) outb[(lg*16+j)*76 + ch] = o[j];
    __syncthreads();
    int l = tid >> 2, seg = tid & 3;
    ushort8 v0 = *(ushort8*)&outb[l*76 + seg*16];
    ushort8 v1 = *(ushort8*)&outb[l*76 + seg*16 + 8];
    ushort* dst = BC + (size_t)(b*1024 + l0 + l)*256 + (ch0 - 2048) + seg*16;
    *(ushort8*)dst = v0; *(ushort8*)(dst+8) = v1;
  }
}

// ---------------- fused chunk-state + recurrence ----------------
// grid 1024 = (b,h,ph,nh). Per block: 8 sequential chunks; h (32p x 64n) in f32 acc;
// per chunk: Hin = h; h = h*dc + sum_s G_s x[s,p] B[s,n] (MFMA accumulates into h).
__global__ __launch_bounds__(256) void k_chscan(
    const ushort* __restrict__ xhT, const ushort* __restrict__ BTg,
    const ushort* __restrict__ dtc,
    const float* __restrict__ dt_bias, const float* __restrict__ A_log,
    ushort* __restrict__ Hin){
  __shared__ __align__(16) ushort sX[32*128];   // 8KB
  __shared__ __align__(16) ushort sB[64*128];   // 16KB
  __shared__ float sG[128];
  __shared__ float sDc;
  const int bid = blockIdx.x;
  const int nh = bid & 1, ph = (bid >> 1) & 1, h = (bid >> 2) & 31, b = bid >> 7;
  const int tid = threadIdx.x, wave = tid >> 6, lane = tid & 63;
  const int l16 = lane & 15, l4 = lane >> 4;
  const float Ah = -__expf(A_log[h]);
  const size_t hinBase0 = (size_t)((b*32 + h)*8)*8192;

  f32x4 acc[2];
  acc[0] = (f32x4){0.f,0.f,0.f,0.f};
  acc[1] = (f32x4){0.f,0.f,0.f,0.f};

  for (int c = 0; c < 8; ++c){
    // stage B-half (64 rows x 128 k), swizzled source -> linear LDS
    {
      const ushort* src = BTg + (size_t)(b*128 + nh*64)*1024 + c*128;
#pragma unroll
      for (int i2 = 0; i2 < 4; ++i2){
        int itg = wave*4 + i2;
        int r = itg*4 + l4;
        int cc = l16 ^ (r & 7);
        gload16(src + (size_t)r*1024 + cc*8, &sB[itg*512]);
      }
    }
    if (wave == 0){
      const int row0 = b*1024 + c*128;
      float bi = dt_bias[h];
      float d0 = bf2f(dtc[(size_t)(row0 + 2*lane    )*32 + h]) + bi;
      float d1 = bf2f(dtc[(size_t)(row0 + 2*lane + 1)*32 + h]) + bi;
      d0 = (d0 > 20.f) ? d0 : log1pf(__expf(d0));
      d1 = (d1 > 20.f) ? d1 : log1pf(__expf(d1));
      float p = d0 + d1;
#pragma unroll
      for (int o = 1; o < 64; o <<= 1){
        float tp = __shfl_up(p, o);
        if (lane >= o) p += tp;
      }
      float cs127 = __shfl(p, 63);
      sG[2*lane    ] = __expf(Ah*(cs127 - (p - d1))) * d0;
      sG[2*lane + 1] = __expf(Ah*(cs127 - p)) * d1;
      if (lane == 0) sDc = __expf(Ah*cs127);
    }
    __syncthreads();
    float dcv = sDc;
    // write Hin = h_old (chunk c sees state before this chunk)
    {
      size_t base = hinBase0 + (size_t)c*8192;
#pragma unroll
      for (int m = 0; m < 2; ++m)
#pragma unroll
        for (int r = 0; r < 4; ++r){
          int p = ph*32 + m*16 + l4*4 + r;
          int n = nh*64 + wave*16 + l16;
          Hin[base + p*128 + n] = f2bf(acc[m][r]);
        }
    }
    // stage X (32 rows x 128 k), scaled by G, swizzled ds_write
    {
      const ushort* xsrc = xhT + (size_t)(b*2048 + h*64 + ph*32)*1024 + c*128;
#pragma unroll
      for (int q0 = 0; q0 < 2; ++q0){
        int q = tid + q0*256;
        int r = q >> 4, cc = q & 15;
        ushort8 v = *(const ushort8*)(xsrc + (size_t)r*1024 + cc*8);
        ushort8 o;
#pragma unroll
        for (int j = 0; j < 8; ++j) o[j] = f2bf(bf2f(v[j]) * sG[cc*8 + j]);
        *(ushort8*)&sX[r*128 + ((cc ^ (r & 7))*8)] = o;
      }
    }
    asm volatile("s_waitcnt vmcnt(0)" ::: "memory");
    __syncthreads();
    acc[0] = acc[0]*dcv;
    acc[1] = acc[1]*dcv;
#pragma unroll
    for (int ks = 0; ks < 4; ++ks){
      bf16x8 av[2], bv;
#pragma unroll
      for (int m = 0; m < 2; ++m){
        int rp = m*16 + l16;
        av[m] = *(const bf16x8*)&sX[rp*128 + (((ks*4 + l4) ^ (rp & 7))*8)];
      }
      int rn = wave*16 + l16;
      bv = *(const bf16x8*)&sB[rn*128 + (((ks*4 + l4) ^ (rn & 7))*8)];
#pragma unroll
      for (int m = 0; m < 2; ++m)
        acc[m] = __builtin_amdgcn_mfma_f32_16x16x32_bf16(av[m], bv, acc[m], 0, 0, 0);
    }
    __syncthreads();
  }
}

// ---------------- main SSD chunk kernel ----------------
__global__ __launch_bounds__(256, 2) void k_ssd(
    const ushort* __restrict__ BC, const ushort* __restrict__ zz,
    const ushort* __restrict__ dtc, const ushort* __restrict__ xhT,
    const ushort* __restrict__ Hin,
    const float* __restrict__ dt_bias, const float* __restrict__ A_log,
    const float* __restrict__ D_param,
    ushort* __restrict__ yv){
  __shared__ __align__(16) ushort sC [128*128];
  __shared__ __align__(16) ushort sBP[128*128];
  __shared__ float csv[128], dtv[128];
  const int bid = blockIdx.x;
  const int h = bid & 31, bc = bid >> 5, b = bc >> 3, c = bc & 7;
  const int tid = threadIdx.x, wave = tid >> 6, lane = tid & 63;
  const int l16 = lane & 15, l4 = lane >> 4;
  const int wr = wave >> 1, wc = wave & 1;
  const int row0 = b*1024 + c*128;
  const ushort* cbase = BC + (size_t)row0*256;
  for (int i2 = 0; i2 < 8; ++i2){
    int itg = wave*8 + i2;
    int r = itg*4 + l4;
    int cc = l16 ^ (r & 7);
    gload16(cbase + (size_t)r*256 + 128 + cc*8, &sC [itg*512]);
    gload16(cbase + (size_t)r*256 +       cc*8, &sBP[itg*512]);
  }
  bf16x8 xbr[2][4], hbr[2][4];
  {
    const size_t hbase = (size_t)((b*32 + h)*8 + c)*8192;
#pragma unroll
    for (int n = 0; n < 2; ++n){
      const int rp = wc*32 + n*16 + l16;
      const ushort* xrow = xhT + (size_t)(b*2048 + h*64 + rp)*1024 + c*128;
      const ushort* hrow = Hin + hbase + (size_t)rp*128;
#pragma unroll
      for (int ks = 0; ks < 4; ++ks){
        xbr[n][ks] = *(const bf16x8*)(xrow + (ks*4 + l4)*8);
        hbr[n][ks] = *(const bf16x8*)(hrow + (ks*4 + l4)*8);
      }
    }
  }
  const float Ah = -__expf(A_log[h]);
  if (wave == 0){
    float bi = dt_bias[h];
    float d0 = bf2f(dtc[(size_t)(row0 + 2*lane    )*32 + h]) + bi;
    float d1 = bf2f(dtc[(size_t)(row0 + 2*lane + 1)*32 + h]) + bi;
    d0 = (d0 > 20.f) ? d0 : log1pf(__expf(d0));
    d1 = (d1 > 20.f) ? d1 : log1pf(__expf(d1));
    float p = d0 + d1;
#pragma unroll
    for (int o = 1; o < 64; o <<= 1){
      float tp = __shfl_up(p, o);
      if (lane >= o) p += tp;
    }
    csv[2*lane    ] = p - d1;
    csv[2*lane + 1] = p;
    dtv[2*lane    ] = d0;
    dtv[2*lane + 1] = d1;
  }
  __syncthreads();
  f32x4 acc[4][4];
#pragma unroll
  for (int m=0;m<4;m++)
#pragma unroll
    for (int n=0;n<4;n++) acc[m][n] = (f32x4){0.f,0.f,0.f,0.f};
  for (int ks = 0; ks < 4; ++ks){
    bf16x8 av[4], bv[4];
#pragma unroll
    for (int m = 0; m < 4; ++m){
      int ri = wr*64 + m*16 + l16;
      av[m] = *(const bf16x8*)&sC[ri*128 + (((ks*4 + l4) ^ (ri & 7))*8)];
    }
#pragma unroll
    for (int n = 0; n < 4; ++n){
      int rs = wc*64 + n*16 + l16;
      bv[n] = *(const bf16x8*)&sBP[rs*128 + (((ks*4 + l4) ^ (rs & 7))*8)];
    }
#pragma unroll
    for (int m = 0; m < 4; ++m)
#pragma unroll
      for (int n = 0; n < 4; ++n)
        acc[m][n] = __builtin_amdgcn_mfma_f32_16x16x32_bf16(av[m], bv[n], acc[m][n], 0, 0, 0);
  }
  __syncthreads();
  const float Dp = D_param[h];
#pragma unroll
  for (int m = 0; m < 4; ++m){
#pragma unroll
    for (int r = 0; r < 4; ++r){
      int i = wr*64 + m*16 + l4*4 + r;
      float ci = csv[i];
#pragma unroll
      for (int n = 0; n < 4; ++n){
        int s = wc*64 + n*16 + l16;
        float e = __expf(Ah*(ci - csv[s]));
        float v = (i >= s) ? acc[m][n][r]*e*dtv[s] : 0.f;
        if (i == s) v += Dp;
        sBP[i*128 + (s ^ ((i & 7)<<3))] = f2bf(v);
      }
    }
  }
  __syncthreads();
  f32x4 accY[4][2], accI[4][2];
#pragma unroll
  for (int m=0;m<4;m++)
#pragma unroll
    for (int n=0;n<2;n++){ accY[m][n] = (f32x4){0.f,0.f,0.f,0.f}; accI[m][n] = (f32x4){0.f,0.f,0.f,0.f}; }
#pragma unroll
  for (int ks = 0; ks < 4; ++ks){
    bf16x8 pa[4], ca[4];
#pragma unroll
    for (int m = 0; m < 4; ++m){
      int ri = wr*64 + m*16 + l16;
      int off = ((ks*4 + l4) ^ (ri & 7))*8;
      pa[m] = *(const bf16x8*)&sBP[ri*128 + off];
      ca[m] = *(const bf16x8*)&sC [ri*128 + off];
    }
#pragma unroll
    for (int m = 0; m < 4; ++m)
#pragma unroll
      for (int n = 0; n < 2; ++n){
        accY[m][n] = __builtin_amdgcn_mfma_f32_16x16x32_bf16(pa[m], xbr[n][ks], accY[m][n], 0, 0, 0);
        accI[m][n] = __builtin_amdgcn_mfma_f32_16x16x32_bf16(ca[m], hbr[n][ks], accI[m][n], 0, 0, 0);
      }
  }
#pragma unroll
  for (int m = 0; m < 4; ++m){
#pragma unroll
    for (int r = 0; r < 4; ++r){
      int i = wr*64 + m*16 + l4*4 + r;
      float Ei = __expf(Ah*csv[i]);
      int grow = row0 + i;
#pragma unroll
      for (int n = 0; n < 2; ++n){
        int p = wc*32 + n*16 + l16;
        float yvl = accY[m][n][r] + Ei*accI[m][n][r];
        float z = bf2f(zz[(size_t)grow*2048 + h*64 + p]);
        yv[(size_t)grow*DI + h*64 + p] = f2bf(yvl * siluf(z));
      }
    }
  }
}

extern "C" void kernel_launch(void* const* d_in, const int* in_sizes, int n_in,
                              void* d_out, int out_size, void* d_ws, size_t ws_size,
                              hipStream_t stream){
  const float* x       = (const float*)d_in[0];
  const float* t       = (const float*)d_in[1];
  const float* y       = (const float*)d_in[2];
  const float* w_ada   = (const float*)d_in[3];
  const float* b_ada   = (const float*)d_in[4];
  const float* w_in    = (const float*)d_in[5];
  const float* conv_w  = (const float*)d_in[6];
  const float* conv_b  = (const float*)d_in[7];
  const float* dt_bias = (const float*)d_in[8];
  const float* A_log   = (const float*)d_in[9];
  const float* D_param = (const float*)d_in[10];
  const float* w_out   = (const float*)d_in[11];

  char* w = (char*)d_ws;
  size_t off = 0;
  auto alloc = [&](size_t bytes)->char*{
    char* p = w + off; off += (bytes + 255) & ~(size_t)255; return p;
  };
  ushort* zz    = (ushort*)alloc((size_t)ROWS*2048*2);   // z part of in_proj
  ushort* xbc   = (ushort*)alloc((size_t)ROWS*CONVDIM*2);// conv input; Hin alias after convT
  ushort* dtc   = (ushort*)alloc((size_t)ROWS*32*2);     // dt logits
  ushort* BCb   = (ushort*)alloc((size_t)ROWS*256*2);    // compact B|C (4.2MB)
  ushort* Mss   = (ushort*)alloc((size_t)ROWS*2048*2);   // shift|scale -> xhT alias
  ushort* Mg    = (ushort*)alloc((size_t)ROWS*1024*2);   // gate
  ushort* yv    = (ushort*)alloc((size_t)ROWS*DI*2);
  ushort* woutT = (ushort*)alloc(1024ull*2048*2);
  ushort* waT   = (ushort*)alloc(3072ull*1024*2);
  ushort* winT  = (ushort*)alloc(4608ull*1024*2);
  float*  atb   = (float*) alloc(8ull*3072*4);
  ushort* Ya    = (ushort*)alloc((size_t)ROWS*1024*2);   // silu(y) -> mod
  ushort* BTg   = (ushort*)alloc((size_t)8*128*1024*2);
  ushort* xhT   = Mss;   // alias: Mss dead after k_lnmod (33.6MB exact)
  ushort* Hin   = xbc;   // alias: xbc dead after k_convT (33.6 <= 37.7MB)

  // 1. Ya = bf16(silu(y))
  k_silu_cast<<<dim3(ROWS*1024/(256*4)), 256, 0, stream>>>(y, Ya, ROWS*1024);
  // 2. weight transposes (f32 -> bf16 [N][K])
  k_transpose_cast<<<dim3(96,32),  256, 0, stream>>>(w_ada, waT,  1024, 3072);
  k_transpose_cast<<<dim3(137,32), 256, 0, stream>>>(w_in,  winT, 1024, 4384);
  k_transpose_cast<<<dim3(32,64),  256, 0, stream>>>(w_out, woutT, 2048, 1024);
  // 3. at = silu(t)@w_ada + b_ada  (f32)
  k_at<<<dim3(12,8), 256, 0, stream>>>(t, w_ada, b_ada, atb);
  // 4. [shift|scale] -> Mss, gate -> Mg
  k_gemm<1><<<dim3(768), 512, 0, stream>>>(Ya, waT, Mss, Mg, nullptr, nullptr, ROWS, 3072, 1024, 24,
                                           b_ada, atb, nullptr, nullptr);
  // 5. mod = LN(x)*(1+scale)+shift  (into Ya)
  k_lnmod<<<dim3(ROWS), 256, 0, stream>>>(x, Mss, Ya);
  // 6. in_proj: zz | xbc | dtc
  k_gemm<0><<<dim3(1120), 512, 0, stream>>>(Ya, winT, zz, xbc, dtc, nullptr, ROWS, DPROJ, 1024, 35,
                                            nullptr, nullptr, nullptr, nullptr);
  // 7. fused conv4+silu+transpose: xhT (over Mss), BTg, BC (compact)
  k_convT<<<dim3(36,16,8), 256, 0, stream>>>(xbc, conv_w, conv_b, BCb, xhT, BTg);
  // 8. fused chunk-state + recurrence -> Hin (over xbc)
  k_chscan<<<dim3(1024), 256, 0, stream>>>(xhT, BTg, dtc, dt_bias, A_log, Hin);
  // 9. SSD main: intra + inter + D + silu(z) gate -> yv
  k_ssd<<<dim3(2048), 256, 0, stream>>>(BCb, zz, dtc, xhT, Hin, dt_bias, A_log, D_param, yv);
  // 10. out = gate * (yv @ w_out) + x
  k_gemm<2><<<dim3(256), 512, 0, stream>>>(yv, woutT, nullptr, nullptr, nullptr, (float*)d_out,
                                           ROWS, 1024, 2048, 8, nullptr, nullptr, Mg, x);
}

// Round 12
// 401.547 us; speedup vs baseline: 1.4666x; 1.0383x over previous
//
#include <hip/hip_runtime.h>

typedef float f32x4 __attribute__((ext_vector_type(4)));
typedef __bf16 bf16x8 __attribute__((ext_vector_type(8)));
typedef unsigned short ushort;
typedef ushort ushort8 __attribute__((ext_vector_type(8)));
typedef ushort ushort4v __attribute__((ext_vector_type(4)));

#define DM 1024
#define DI 2048
#define DSTATE 128
#define NH 32
#define HD 64
#define CONVDIM 2304
#define DPROJ 4384
#define ROWS 8192

__device__ __forceinline__ float bf2f(ushort u){
  union { unsigned int i; float f; } v; v.i = ((unsigned int)u)<<16; return v.f;
}
__device__ __forceinline__ ushort f2bf(float f){
  union { float f; unsigned int i; } v; v.f = f;
  unsigned int r = v.i + 0x7FFFu + ((v.i>>16)&1u);
  return (ushort)(r>>16);
}
__device__ __forceinline__ float siluf(float x){ return x / (1.f + __expf(-x)); }

__device__ __forceinline__ void gload16(const ushort* g, ushort* l){
  __builtin_amdgcn_global_load_lds(
      (const __attribute__((address_space(1))) void*)g,
      (__attribute__((address_space(3))) void*)l, 16, 0, 0);
}

// ---------------- elementwise: Ya = bf16(silu(y)) ----------------
__global__ __launch_bounds__(256) void k_silu_cast(const float* __restrict__ in,
                                                   ushort* __restrict__ out, int n){
  int i = (blockIdx.x*256 + threadIdx.x)*4;
  if (i >= n) return;
  float4 v = *(const float4*)(in + i);
  ushort4v o;
  o.x = f2bf(siluf(v.x)); o.y = f2bf(siluf(v.y));
  o.z = f2bf(siluf(v.z)); o.w = f2bf(siluf(v.w));
  *(ushort4v*)(out + i) = o;
}

// ---------------- weight transpose+cast: in[K][N] f32 -> out[N][K] bf16 ----------------
__global__ __launch_bounds__(256) void k_transpose_cast(const float* __restrict__ in,
                                                        ushort* __restrict__ out,
                                                        int K, int N){
  __shared__ float tile[32][33];
  int n0 = blockIdx.x*32, k0 = blockIdx.y*32;
  int tx = threadIdx.x & 31, ty = threadIdx.x >> 5; // 32x8
  for (int r = ty; r < 32; r += 8) tile[r][tx] = in[(size_t)(k0+r)*N + n0+tx];
  __syncthreads();
  for (int r = ty; r < 32; r += 8) out[(size_t)(n0+r)*K + k0+tx] = f2bf(tile[tx][r]);
}

// ---------------- at[b][n] = silu(t[b]) @ w_ada + b_ada ----------------
__global__ __launch_bounds__(256) void k_at(const float* __restrict__ t,
                                            const float* __restrict__ w_ada,
                                            const float* __restrict__ b_ada,
                                            float* __restrict__ at){
  __shared__ float st[1024];
  int b = blockIdx.y;
  int col = blockIdx.x*256 + threadIdx.x;
  for (int i = threadIdx.x; i < 1024; i += 256) st[i] = siluf(t[b*1024 + i]);
  __syncthreads();
  float acc = 0.f;
  for (int k = 0; k < 1024; ++k) acc += st[k] * w_ada[(size_t)k*3072 + col];
  at[b*3072 + col] = acc + b_ada[col];
}

// ---------------- GEMM: 128x128 tile, BK=32, 4 waves, QUAD-buffer depth-3 prefetch ----------------
// Tile T: compute buf[T%4]; stage tile T+3 into buf[(T+3)%4]; vmcnt(8)+s_barrier.
// Requires K % 128 == 0 (NT%4==0 -> NB=NT-3 == 1 mod 4: one leftover BODY, tail bufs 1,2,3).
// + XCD-chunked bijective swizzle + GROUP_M=8 supertiling (round-8 verified).
#define STG(Q, KT) do{ \
  gload16(pA0 + (size_t)(KT)*32, &sm[(Q)*8192 + (wave*2+0)*512]); \
  gload16(pA1 + (size_t)(KT)*32, &sm[(Q)*8192 + (wave*2+1)*512]); \
  gload16(pB0 + (size_t)(KT)*32, &sm[(Q)*8192 + 4096 + (wave*2+0)*512]); \
  gload16(pB1 + (size_t)(KT)*32, &sm[(Q)*8192 + 4096 + (wave*2+1)*512]); }while(0)

#define CMP(BOFF) do{ \
  bf16x8 af[4], bfr[4]; \
  _Pragma("unroll") \
  for (int m=0;m<4;m++) af[m]  = *(const bf16x8*)&sm[(BOFF) + (wr*64 + m*16 + l16)*32 + kbs]; \
  _Pragma("unroll") \
  for (int n=0;n<4;n++) bfr[n] = *(const bf16x8*)&sm[(BOFF) + 4096 + (wc*64 + n*16 + l16)*32 + kbs]; \
  __builtin_amdgcn_s_setprio(1); \
  _Pragma("unroll") \
  for (int m=0;m<4;m++) \
    _Pragma("unroll") \
    for (int n=0;n<4;n++) \
      acc[m][n] = __builtin_amdgcn_mfma_f32_16x16x32_bf16(af[m], bfr[n], acc[m][n], 0, 0, 0); \
  __builtin_amdgcn_s_setprio(0); }while(0)

#define BODY(Q, T) do{ \
  STG(((Q)+3)&3, (T)+3); \
  CMP((Q)*8192); \
  asm volatile("s_waitcnt vmcnt(8)" ::: "memory"); \
  __builtin_amdgcn_s_barrier(); \
  __builtin_amdgcn_sched_barrier(0); }while(0)

template<int EPI>
__global__ __launch_bounds__(256)
void k_gemm(const ushort* __restrict__ Ag, const ushort* __restrict__ Bt,
            ushort* __restrict__ Cb, ushort* __restrict__ Cb2, ushort* __restrict__ Cb3,
            float* __restrict__ Cf,
            int M, int N, int K, int nbn,
            const float* __restrict__ bias, const float* __restrict__ at,
            const ushort* __restrict__ gateM, const float* __restrict__ xres){
  __shared__ __align__(16) ushort sm[4*8192];   // 4 bufs x (A 8KB + B 8KB) = 64KB
  const int tid  = threadIdx.x;
  const int wave = tid >> 6, lane = tid & 63;
  // XCD-chunked swizzle (nwg % 8 == 0 guaranteed) + GROUP_M=8 supertiling
  const int nwg = gridDim.x, bid0 = blockIdx.x;
  const int wg = (bid0 & 7)*(nwg >> 3) + (bid0 >> 3);
  const int pg = nbn << 3;
  const int g  = wg / pg;
  const int rem = wg - g*pg;
  const int bm = (g << 3) + (rem & 7);
  const int bn = rem >> 3;
  const int wr = wave >> 1, wc = wave & 1;
  const int l16 = lane & 15, kb = lane >> 4;
  const int arow0 = (wave*2+0)*16 + (lane>>2);
  const int arow1 = (wave*2+1)*16 + (lane>>2);
  const int kcs = (lane & 3) ^ ((lane>>3)&3);
  const int kbs = (kb ^ ((l16>>1)&3))*8;

  const ushort* pA0 = Ag + (size_t)(bm*128 + arow0)*K + kcs*8;
  const ushort* pA1 = Ag + (size_t)(bm*128 + arow1)*K + kcs*8;
  int br0 = bn*128 + arow0; if (br0 > N-1) br0 = N-1;
  int br1 = bn*128 + arow1; if (br1 > N-1) br1 = N-1;
  const ushort* pB0 = Bt + (size_t)br0*K + kcs*8;
  const ushort* pB1 = Bt + (size_t)br1*K + kcs*8;

  f32x4 acc[4][4];
#pragma unroll
  for (int m=0;m<4;m++)
#pragma unroll
    for (int n=0;n<4;n++) acc[m][n] = (f32x4){0.f,0.f,0.f,0.f};

  const int NT = K >> 5;       // K%128==0 -> NT%4==0
  const int NB = NT - 3;       // NB % 4 == 1

  // prologue: stage tiles 0,1,2; wait tile0 landed (12 outstanding -> 8)
  STG(0, 0); STG(1, 1); STG(2, 2);
  asm volatile("s_waitcnt vmcnt(8)" ::: "memory");
  __builtin_amdgcn_s_barrier();
  __builtin_amdgcn_sched_barrier(0);

  int T = 0;
  for (; T + 4 <= NB; T += 4){
    BODY(0, T); BODY(1, T+1); BODY(2, T+2); BODY(3, T+3);
  }
  // NB % 4 == 1 -> exactly one leftover, Q = 0
  BODY(0, T);

  // tail: tiles NB, NB+1, NB+2 in bufs 1, 2, 3 (NB%4==1)
  CMP(1*8192);
  asm volatile("s_waitcnt vmcnt(4)" ::: "memory");
  __builtin_amdgcn_s_barrier();
  __builtin_amdgcn_sched_barrier(0);
  CMP(2*8192);
  asm volatile("s_waitcnt vmcnt(0)" ::: "memory");
  __builtin_amdgcn_s_barrier();
  __builtin_amdgcn_sched_barrier(0);
  CMP(3*8192);

#pragma unroll
  for (int m=0;m<4;m++){
    int grow_base = bm*128 + wr*64 + m*16 + (lane>>4)*4;
#pragma unroll
    for (int n=0;n<4;n++){
      int gcol = bn*128 + wc*64 + n*16 + l16;
      if (EPI == 0){
        if (gcol < N){
#pragma unroll
          for (int r=0;r<4;r++){
            int row = grow_base + r;
            float v = acc[m][n][r];
            if (gcol < 2048)      Cb [(size_t)row*2048 + gcol] = f2bf(v);
            else if (gcol < 4352) Cb2[(size_t)row*2304 + (gcol-2048)] = f2bf(v);
            else                  Cb3[(size_t)row*32   + (gcol-4352)] = f2bf(v);
          }
        }
      } else if (EPI == 1){
        float bv = bias[gcol];
#pragma unroll
        for (int r=0;r<4;r++){
          int row = grow_base + r;
          float v = acc[m][n][r] + bv + at[(row>>10)*3072 + gcol];
          if (gcol < 2048) Cb [(size_t)row*2048 + gcol] = f2bf(v);
          else             Cb2[(size_t)row*1024 + (gcol - 2048)] = f2bf(v);
        }
      } else {
#pragma unroll
        for (int r=0;r<4;r++){
          int row = grow_base + r;
          float g2 = bf2f(gateM[(size_t)row*1024 + gcol]);
          Cf[(size_t)row*1024 + gcol] = g2*acc[m][n][r] + xres[(size_t)row*1024 + gcol];
        }
      }
    }
  }
}

// ---------------- LN + modulation ----------------
__global__ __launch_bounds__(256) void k_lnmod(const float* __restrict__ x,
                                               const ushort* __restrict__ Mss,
                                               ushort* __restrict__ mod){
  int row = blockIdx.x;
  const float* xr = x + (size_t)row*1024;
  float v[4]; float s = 0.f, s2 = 0.f;
#pragma unroll
  for (int j=0;j<4;j++){ v[j] = xr[threadIdx.x + j*256]; s += v[j]; s2 += v[j]*v[j]; }
#pragma unroll
  for (int o=32;o>0;o>>=1){ s += __shfl_down(s,o); s2 += __shfl_down(s2,o); }
  __shared__ float ls[4], ls2[4];
  int wv = threadIdx.x >> 6;
  if ((threadIdx.x & 63) == 0){ ls[wv] = s; ls2[wv] = s2; }
  __syncthreads();
  s  = ls[0]+ls[1]+ls[2]+ls[3];
  s2 = ls2[0]+ls2[1]+ls2[2]+ls2[3];
  float mu = s * (1.f/1024.f);
  float var = s2 * (1.f/1024.f) - mu*mu;
  float rstd = rsqrtf(var + 1e-6f);
  const ushort* Mr = Mss + (size_t)row*2048;
#pragma unroll
  for (int j=0;j<4;j++){
    int d = threadIdx.x + j*256;
    float sc = bf2f(Mr[1024 + d]);
    float sh = bf2f(Mr[d]);
    mod[(size_t)row*1024 + d] = f2bf((v[j]-mu)*rstd*(1.f+sc) + sh);
  }
}

// ---------------- fused conv4+silu+transpose ----------------
__global__ __launch_bounds__(256) void k_convT(const ushort* __restrict__ xbc,
                                               const float* __restrict__ conv_w,
                                               const float* __restrict__ conv_b,
                                               ushort* __restrict__ BC,
                                               ushort* __restrict__ xhT,
                                               ushort* __restrict__ BTg){
  __shared__ ushort lin[67*64];
  __shared__ __align__(16) ushort outb[64*76];
  const int cb = blockIdx.x, lb = blockIdx.y, b = blockIdx.z;
  const int ch0 = cb*64, l0 = lb*64;
  const int tid = threadIdx.x;
  for (int q = tid; q < 67*8; q += 256){
    int r = q >> 3, c8 = q & 7;
    int l = l0 - 3 + r;
    ushort8 v = {0,0,0,0,0,0,0,0};
    if (l >= 0) v = *(const ushort8*)(xbc + (size_t)(b*1024 + l)*CONVDIM + ch0 + c8*8);
    *(ushort8*)&lin[r*64 + c8*8] = v;
  }
  __syncthreads();
  const int ch = tid & 63, lg = tid >> 6;
  const int chg = ch0 + ch;
  const float w0 = conv_w[chg*4+0], w1 = conv_w[chg*4+1];
  const float w2 = conv_w[chg*4+2], w3 = conv_w[chg*4+3];
  const float cbv = conv_b[chg];
  __align__(16) ushort o[16];
#pragma unroll
  for (int j = 0; j < 16; ++j){
    int r = lg*16 + j;
    float a = cbv + w0*bf2f(lin[r*64+ch])     + w1*bf2f(lin[(r+1)*64+ch])
                  + w2*bf2f(lin[(r+2)*64+ch]) + w3*bf2f(lin[(r+3)*64+ch]);
    o[j] = f2bf(siluf(a));
  }
  if (cb < 34){   // transposed output (xh or B)
    *(ushort8*)&outb[ch*76 + lg*16]     = *(ushort8*)&o[0];
    *(ushort8*)&outb[ch*76 + lg*16 + 8] = *(ushort8*)&o[8];
    __syncthreads();
    int row = tid >> 2, seg = tid & 3;
    ushort8 v0 = *(ushort8*)&outb[row*76 + seg*16];
    ushort8 v1 = *(ushort8*)&outb[row*76 + seg*16 + 8];
    ushort* dst = (cb < 32)
      ? (xhT + (size_t)(b*2048 + ch0 + row)*1024 + l0 + seg*16)
      : (BTg + (size_t)(b*128 + (ch0 - 2048) + row)*1024 + l0 + seg*16);
    *(ushort8*)dst = v0; *(ushort8*)(dst+8) = v1;
  }
  if (cb >= 32){  // row-major output (B or C) into compact BC
    __syncthreads();
#pragma unroll
    for (int j = 0; j < 16; ++j) outb[(lg*16+j)*76 + ch] = o[j];
    __syncthreads();
    int l = tid >> 2, seg = tid & 3;
    ushort8 v0 = *(ushort8*)&outb[l*76 + seg*16];
    ushort8 v1 = *(ushort8*)&outb[l*76 + seg*16 + 8];
    ushort* dst = BC + (size_t)(b*1024 + l0 + l)*256 + (ch0 - 2048) + seg*16;
    *(ushort8*)dst = v0; *(ushort8*)(dst+8) = v1;
  }
}

// ---------------- fused chunk-state + recurrence ----------------
__global__ __launch_bounds__(256) void k_chscan(
    const ushort* __restrict__ xhT, const ushort* __restrict__ BTg,
    const ushort* __restrict__ dtc,
    const float* __restrict__ dt_bias, const float* __restrict__ A_log,
    ushort* __restrict__ Hin){
  __shared__ __align__(16) ushort sX[32*128];   // 8KB
  __shared__ __align__(16) ushort sB[64*128];   // 16KB
  __shared__ float sG[128];
  __shared__ float sDc;
  const int bid = blockIdx.x;
  const int nh = bid & 1, ph = (bid >> 1) & 1, h = (bid >> 2) & 31, b = bid >> 7;
  const int tid = threadIdx.x, wave = tid >> 6, lane = tid & 63;
  const int l16 = lane & 15, l4 = lane >> 4;
  const float Ah = -__expf(A_log[h]);
  const size_t hinBase0 = (size_t)((b*32 + h)*8)*8192;

  f32x4 acc[2];
  acc[0] = (f32x4){0.f,0.f,0.f,0.f};
  acc[1] = (f32x4){0.f,0.f,0.f,0.f};

  for (int c = 0; c < 8; ++c){
    {
      const ushort* src = BTg + (size_t)(b*128 + nh*64)*1024 + c*128;
#pragma unroll
      for (int i2 = 0; i2 < 4; ++i2){
        int itg = wave*4 + i2;
        int r = itg*4 + l4;
        int cc = l16 ^ (r & 7);
        gload16(src + (size_t)r*1024 + cc*8, &sB[itg*512]);
      }
    }
    if (wave == 0){
      const int row0 = b*1024 + c*128;
      float bi = dt_bias[h];
      float d0 = bf2f(dtc[(size_t)(row0 + 2*lane    )*32 + h]) + bi;
      float d1 = bf2f(dtc[(size_t)(row0 + 2*lane + 1)*32 + h]) + bi;
      d0 = (d0 > 20.f) ? d0 : log1pf(__expf(d0));
      d1 = (d1 > 20.f) ? d1 : log1pf(__expf(d1));
      float p = d0 + d1;
#pragma unroll
      for (int o = 1; o < 64; o <<= 1){
        float tp = __shfl_up(p, o);
        if (lane >= o) p += tp;
      }
      float cs127 = __shfl(p, 63);
      sG[2*lane    ] = __expf(Ah*(cs127 - (p - d1))) * d0;
      sG[2*lane + 1] = __expf(Ah*(cs127 - p)) * d1;
      if (lane == 0) sDc = __expf(Ah*cs127);
    }
    __syncthreads();
    float dcv = sDc;
    {
      size_t base = hinBase0 + (size_t)c*8192;
#pragma unroll
      for (int m = 0; m < 2; ++m)
#pragma unroll
        for (int r = 0; r < 4; ++r){
          int p = ph*32 + m*16 + l4*4 + r;
          int n = nh*64 + wave*16 + l16;
          Hin[base + p*128 + n] = f2bf(acc[m][r]);
        }
    }
    {
      const ushort* xsrc = xhT + (size_t)(b*2048 + h*64 + ph*32)*1024 + c*128;
#pragma unroll
      for (int q0 = 0; q0 < 2; ++q0){
        int q = tid + q0*256;
        int r = q >> 4, cc = q & 15;
        ushort8 v = *(const ushort8*)(xsrc + (size_t)r*1024 + cc*8);
        ushort8 o;
#pragma unroll
        for (int j = 0; j < 8; ++j) o[j] = f2bf(bf2f(v[j]) * sG[cc*8 + j]);
        *(ushort8*)&sX[r*128 + ((cc ^ (r & 7))*8)] = o;
      }
    }
    asm volatile("s_waitcnt vmcnt(0)" ::: "memory");
    __syncthreads();
    acc[0] = acc[0]*dcv;
    acc[1] = acc[1]*dcv;
#pragma unroll
    for (int ks = 0; ks < 4; ++ks){
      bf16x8 av[2], bv;
#pragma unroll
      for (int m = 0; m < 2; ++m){
        int rp = m*16 + l16;
        av[m] = *(const bf16x8*)&sX[rp*128 + (((ks*4 + l4) ^ (rp & 7))*8)];
      }
      int rn = wave*16 + l16;
      bv = *(const bf16x8*)&sB[rn*128 + (((ks*4 + l4) ^ (rn & 7))*8)];
#pragma unroll
      for (int m = 0; m < 2; ++m)
        acc[m] = __builtin_amdgcn_mfma_f32_16x16x32_bf16(av[m], bv, acc[m], 0, 0, 0);
    }
    __syncthreads();
  }
}

// ---------------- main SSD chunk kernel ----------------
__global__ __launch_bounds__(256, 2) void k_ssd(
    const ushort* __restrict__ BC, const ushort* __restrict__ zz,
    const ushort* __restrict__ dtc, const ushort* __restrict__ xhT,
    const ushort* __restrict__ Hin,
    const float* __restrict__ dt_bias, const float* __restrict__ A_log,
    const float* __restrict__ D_param,
    ushort* __restrict__ yv){
  __shared__ __align__(16) ushort sC [128*128];
  __shared__ __align__(16) ushort sBP[128*128];
  __shared__ float csv[128], dtv[128];
  const int bid = blockIdx.x;
  const int h = bid & 31, bc = bid >> 5, b = bc >> 3, c = bc & 7;
  const int tid = threadIdx.x, wave = tid >> 6, lane = tid & 63;
  const int l16 = lane & 15, l4 = lane >> 4;
  const int wr = wave >> 1, wc = wave & 1;
  const int row0 = b*1024 + c*128;
  const ushort* cbase = BC + (size_t)row0*256;
  for (int i2 = 0; i2 < 8; ++i2){
    int itg = wave*8 + i2;
    int r = itg*4 + l4;
    int cc = l16 ^ (r & 7);
    gload16(cbase + (size_t)r*256 + 128 + cc*8, &sC [itg*512]);
    gload16(cbase + (size_t)r*256 +       cc*8, &sBP[itg*512]);
  }
  bf16x8 xbr[2][4], hbr[2][4];
  {
    const size_t hbase = (size_t)((b*32 + h)*8 + c)*8192;
#pragma unroll
    for (int n = 0; n < 2; ++n){
      const int rp = wc*32 + n*16 + l16;
      const ushort* xrow = xhT + (size_t)(b*2048 + h*64 + rp)*1024 + c*128;
      const ushort* hrow = Hin + hbase + (size_t)rp*128;
#pragma unroll
      for (int ks = 0; ks < 4; ++ks){
        xbr[n][ks] = *(const bf16x8*)(xrow + (ks*4 + l4)*8);
        hbr[n][ks] = *(const bf16x8*)(hrow + (ks*4 + l4)*8);
      }
    }
  }
  const float Ah = -__expf(A_log[h]);
  if (wave == 0){
    float bi = dt_bias[h];
    float d0 = bf2f(dtc[(size_t)(row0 + 2*lane    )*32 + h]) + bi;
    float d1 = bf2f(dtc[(size_t)(row0 + 2*lane + 1)*32 + h]) + bi;
    d0 = (d0 > 20.f) ? d0 : log1pf(__expf(d0));
    d1 = (d1 > 20.f) ? d1 : log1pf(__expf(d1));
    float p = d0 + d1;
#pragma unroll
    for (int o = 1; o < 64; o <<= 1){
      float tp = __shfl_up(p, o);
      if (lane >= o) p += tp;
    }
    csv[2*lane    ] = p - d1;
    csv[2*lane + 1] = p;
    dtv[2*lane    ] = d0;
    dtv[2*lane + 1] = d1;
  }
  __syncthreads();
  f32x4 acc[4][4];
#pragma unroll
  for (int m=0;m<4;m++)
#pragma unroll
    for (int n=0;n<4;n++) acc[m][n] = (f32x4){0.f,0.f,0.f,0.f};
  for (int ks = 0; ks < 4; ++ks){
    bf16x8 av[4], bv[4];
#pragma unroll
    for (int m = 0; m < 4; ++m){
      int ri = wr*64 + m*16 + l16;
      av[m] = *(const bf16x8*)&sC[ri*128 + (((ks*4 + l4) ^ (ri & 7))*8)];
    }
#pragma unroll
    for (int n = 0; n < 4; ++n){
      int rs = wc*64 + n*16 + l16;
      bv[n] = *(const bf16x8*)&sBP[rs*128 + (((ks*4 + l4) ^ (rs & 7))*8)];
    }
#pragma unroll
    for (int m = 0; m < 4; ++m)
#pragma unroll
      for (int n = 0; n < 4; ++n)
        acc[m][n] = __builtin_amdgcn_mfma_f32_16x16x32_bf16(av[m], bv[n], acc[m][n], 0, 0, 0);
  }
  __syncthreads();
  const float Dp = D_param[h];
#pragma unroll
  for (int m = 0; m < 4; ++m){
#pragma unroll
    for (int r = 0; r < 4; ++r){
      int i = wr*64 + m*16 + l4*4 + r;
      float ci = csv[i];
#pragma unroll
      for (int n = 0; n < 4; ++n){
        int s = wc*64 + n*16 + l16;
        float e = __expf(Ah*(ci - csv[s]));
        float v = (i >= s) ? acc[m][n][r]*e*dtv[s] : 0.f;
        if (i == s) v += Dp;
        sBP[i*128 + (s ^ ((i & 7)<<3))] = f2bf(v);
      }
    }
  }
  __syncthreads();
  f32x4 accY[4][2], accI[4][2];
#pragma unroll
  for (int m=0;m<4;m++)
#pragma unroll
    for (int n=0;n<2;n++){ accY[m][n] = (f32x4){0.f,0.f,0.f,0.f}; accI[m][n] = (f32x4){0.f,0.f,0.f,0.f}; }
#pragma unroll
  for (int ks = 0; ks < 4; ++ks){
    bf16x8 pa[4], ca[4];
#pragma unroll
    for (int m = 0; m < 4; ++m){
      int ri = wr*64 + m*16 + l16;
      int off = ((ks*4 + l4) ^ (ri & 7))*8;
      pa[m] = *(const bf16x8*)&sBP[ri*128 + off];
      ca[m] = *(const bf16x8*)&sC [ri*128 + off];
    }
#pragma unroll
    for (int m = 0; m < 4; ++m)
#pragma unroll
      for (int n = 0; n < 2; ++n){
        accY[m][n] = __builtin_amdgcn_mfma_f32_16x16x32_bf16(pa[m], xbr[n][ks], accY[m][n], 0, 0, 0);
        accI[m][n] = __builtin_amdgcn_mfma_f32_16x16x32_bf16(ca[m], hbr[n][ks], accI[m][n], 0, 0, 0);
      }
  }
#pragma unroll
  for (int m = 0; m < 4; ++m){
#pragma unroll
    for (int r = 0; r < 4; ++r){
      int i = wr*64 + m*16 + l4*4 + r;
      float Ei = __expf(Ah*csv[i]);
      int grow = row0 + i;
#pragma unroll
      for (int n = 0; n < 2; ++n){
        int p = wc*32 + n*16 + l16;
        float yvl = accY[m][n][r] + Ei*accI[m][n][r];
        float z = bf2f(zz[(size_t)grow*2048 + h*64 + p]);
        yv[(size_t)grow*DI + h*64 + p] = f2bf(yvl * siluf(z));
      }
    }
  }
}

extern "C" void kernel_launch(void* const* d_in, const int* in_sizes, int n_in,
                              void* d_out, int out_size, void* d_ws, size_t ws_size,
                              hipStream_t stream){
  const float* x       = (const float*)d_in[0];
  const float* t       = (const float*)d_in[1];
  const float* y       = (const float*)d_in[2];
  const float* w_ada   = (const float*)d_in[3];
  const float* b_ada   = (const float*)d_in[4];
  const float* w_in    = (const float*)d_in[5];
  const float* conv_w  = (const float*)d_in[6];
  const float* conv_b  = (const float*)d_in[7];
  const float* dt_bias = (const float*)d_in[8];
  const float* A_log   = (const float*)d_in[9];
  const float* D_param = (const float*)d_in[10];
  const float* w_out   = (const float*)d_in[11];

  char* w = (char*)d_ws;
  size_t off = 0;
  auto alloc = [&](size_t bytes)->char*{
    char* p = w + off; off += (bytes + 255) & ~(size_t)255; return p;
  };
  ushort* zz    = (ushort*)alloc((size_t)ROWS*2048*2);   // z part of in_proj
  ushort* xbc   = (ushort*)alloc((size_t)ROWS*CONVDIM*2);// conv input; Hin alias after convT
  ushort* dtc   = (ushort*)alloc((size_t)ROWS*32*2);     // dt logits
  ushort* BCb   = (ushort*)alloc((size_t)ROWS*256*2);    // compact B|C (4.2MB)
  ushort* Mss   = (ushort*)alloc((size_t)ROWS*2048*2);   // shift|scale -> xhT alias
  ushort* Mg    = (ushort*)alloc((size_t)ROWS*1024*2);   // gate
  ushort* yv    = (ushort*)alloc((size_t)ROWS*DI*2);
  ushort* woutT = (ushort*)alloc(1024ull*2048*2);
  ushort* waT   = (ushort*)alloc(3072ull*1024*2);
  ushort* winT  = (ushort*)alloc(4608ull*1024*2);
  float*  atb   = (float*) alloc(8ull*3072*4);
  ushort* Ya    = (ushort*)alloc((size_t)ROWS*1024*2);   // silu(y) -> mod
  ushort* BTg   = (ushort*)alloc((size_t)8*128*1024*2);
  ushort* xhT   = Mss;   // alias: Mss dead after k_lnmod (33.6MB exact)
  ushort* Hin   = xbc;   // alias: xbc dead after k_convT (33.6 <= 37.7MB)

  // 1. Ya = bf16(silu(y))
  k_silu_cast<<<dim3(ROWS*1024/(256*4)), 256, 0, stream>>>(y, Ya, ROWS*1024);
  // 2. weight transposes (f32 -> bf16 [N][K])
  k_transpose_cast<<<dim3(96,32),  256, 0, stream>>>(w_ada, waT,  1024, 3072);
  k_transpose_cast<<<dim3(137,32), 256, 0, stream>>>(w_in,  winT, 1024, 4384);
  k_transpose_cast<<<dim3(32,64),  256, 0, stream>>>(w_out, woutT, 2048, 1024);
  // 3. at = silu(t)@w_ada + b_ada  (f32)
  k_at<<<dim3(12,8), 256, 0, stream>>>(t, w_ada, b_ada, atb);
  // 4. [shift|scale] -> Mss, gate -> Mg   (1D grid 64*24=1536, %8==0)
  k_gemm<1><<<dim3(1536), 256, 0, stream>>>(Ya, waT, Mss, Mg, nullptr, nullptr, ROWS, 3072, 1024, 24,
                                            b_ada, atb, nullptr, nullptr);
  // 5. mod = LN(x)*(1+scale)+shift  (into Ya)
  k_lnmod<<<dim3(ROWS), 256, 0, stream>>>(x, Mss, Ya);
  // 6. in_proj: zz | xbc | dtc   (1D grid 64*35=2240, %8==0)
  k_gemm<0><<<dim3(2240), 256, 0, stream>>>(Ya, winT, zz, xbc, dtc, nullptr, ROWS, DPROJ, 1024, 35,
                                            nullptr, nullptr, nullptr, nullptr);
  // 7. fused conv4+silu+transpose: xhT (over Mss), BTg, BC (compact)
  k_convT<<<dim3(36,16,8), 256, 0, stream>>>(xbc, conv_w, conv_b, BCb, xhT, BTg);
  // 8. fused chunk-state + recurrence -> Hin (over xbc)
  k_chscan<<<dim3(1024), 256, 0, stream>>>(xhT, BTg, dtc, dt_bias, A_log, Hin);
  // 9. SSD main: intra + inter + D + silu(z) gate -> yv
  k_ssd<<<dim3(2048), 256, 0, stream>>>(BCb, zz, dtc, xhT, Hin, dt_bias, A_log, D_param, yv);
  // 10. out = gate * (yv @ w_out) + x   (1D grid 64*8=512, %8==0)
  k_gemm<2><<<dim3(512), 256, 0, stream>>>(yv, woutT, nullptr, nullptr, nullptr, (float*)d_out,
                                           ROWS, 1024, 2048, 8, nullptr, nullptr, Mg, x);
}